// Round 24
// baseline (485.838 us; speedup 1.0000x reference)
//
#include <hip/hip_runtime.h>
#include <hip/hip_bf16.h>
#include <math.h>

typedef __hip_bfloat16 bf16;
typedef __attribute__((ext_vector_type(8))) short bf16x8;
typedef __attribute__((ext_vector_type(4))) float f32x4;
typedef __attribute__((ext_vector_type(2))) float f32x2;

#define LRELU(v) ((v) > 0.f ? (v) : 0.2f*(v))

__device__ __forceinline__ float sig_f(float x){ return 1.f/(1.f + __expf(-x)); }
__device__ __forceinline__ float tanh_f(float x){
  float ax = fabsf(x);
  float e = __expf(-2.f*ax);
  float t = (1.f - e)/(1.f + e);
  return x >= 0.f ? t : -t;
}
__device__ __forceinline__ ushort bfbits(float v){
  bf16 b = __float2bfloat16(v);
  return *(ushort*)&b;
}
__device__ __forceinline__ uint bfpack(float a, float b){
  return (uint)bfbits(a) | ((uint)bfbits(b) << 16);
}
__device__ __forceinline__ float bflo(uint u){ return __uint_as_float(u << 16); }
__device__ __forceinline__ float bfhi(uint u){ return __uint_as_float(u & 0xffff0000u); }

__global__ void k_tobf16(const float* __restrict__ src, ushort* __restrict__ dst, int n){
  int i = blockIdx.x*256 + threadIdx.x;
  if (i < n) dst[i] = bfbits(src[i]);
}

// ---------------- generic tiled transpose
__global__ void k_transpose(const float* __restrict__ src, float* __restrict__ dst, int R, int C){
  __shared__ float t[32][33];
  int c0 = blockIdx.x*32, r0 = blockIdx.y*32;
  int tx = threadIdx.x, ty = threadIdx.y;
  #pragma unroll
  for (int i = 0; i < 4; ++i)
    t[ty+8*i][tx] = src[(size_t)(r0+ty+8*i)*C + c0+tx];
  __syncthreads();
  #pragma unroll
  for (int i = 0; i < 4; ++i)
    dst[(size_t)(c0+ty+8*i)*R + r0+tx] = t[tx][ty+8*i];
}

// ---------------- LSTM weight pack: fp8 e4m3, uint per k: bytes {i,f,g,o}
__global__ void k_w4prep(const float* __restrict__ Wih, const float* __restrict__ Whh,
                         uint4* __restrict__ Whq8, uint4* __restrict__ Wsq8,
                         float* __restrict__ stats){
  int k4 = blockIdx.x, j = threadIdx.x;
  if (k4 < 2) { int i = k4*256 + j; if (i < 448) stats[i] = 0.f; }
  uint h4[4], s4[4];
  #pragma unroll
  for (int d = 0; d < 4; ++d) {
    int k = 4*k4 + d;
    float hi = Whh[j*256+k],       hf = Whh[(256+j)*256+k];
    float hg = Whh[(512+j)*256+k], ho = Whh[(768+j)*256+k];
    float ii = Wih[j*256+k],       iff = Wih[(256+j)*256+k];
    float ig = Wih[(512+j)*256+k], io = Wih[(768+j)*256+k];
    int lo = __builtin_amdgcn_cvt_pk_fp8_f32(hi, hf, 0, false);
    h4[d] = (uint)__builtin_amdgcn_cvt_pk_fp8_f32(hg, ho, lo, true);
    lo = __builtin_amdgcn_cvt_pk_fp8_f32(hi+ii, hf+iff, 0, false);
    s4[d] = (uint)__builtin_amdgcn_cvt_pk_fp8_f32(hg+ig, ho+io, lo, true);
  }
  Whq8[k4*256+j] = make_uint4(h4[0], h4[1], h4[2], h4[3]);
  Wsq8[k4*256+j] = make_uint4(s4[0], s4[1], s4[2], s4[3]);
}

__global__ void k_xgbias(const float* __restrict__ Wih, const float* __restrict__ b_ih,
                         const float* __restrict__ b_hh, const float* __restrict__ init_in,
                         float4* __restrict__ xg4, float4* __restrict__ bias4){
  int b = blockIdx.x, t = threadIdx.x;
  float v = init_in[t];
  float p0 = v * Wih[b*256 + t];
  float p1 = v * Wih[(256+b)*256 + t];
  float p2 = v * Wih[(512+b)*256 + t];
  float p3 = v * Wih[(768+b)*256 + t];
  #pragma unroll
  for (int o = 32; o; o >>= 1) {
    p0 += __shfl_xor(p0, o); p1 += __shfl_xor(p1, o);
    p2 += __shfl_xor(p2, o); p3 += __shfl_xor(p3, o);
  }
  __shared__ float4 red[4];
  int lane = t & 63, wid = t >> 6;
  if (lane == 0) red[wid] = make_float4(p0,p1,p2,p3);
  __syncthreads();
  if (t == 0) {
    float4 bi = make_float4(b_ih[b]+b_hh[b], b_ih[256+b]+b_hh[256+b],
                            b_ih[512+b]+b_hh[512+b], b_ih[768+b]+b_hh[768+b]);
    bias4[b] = bi;
    float4 a = bi;
    #pragma unroll
    for (int w = 0; w < 4; ++w) { a.x += red[w].x; a.y += red[w].y; a.z += red[w].z; a.w += red[w].w; }
    xg4[b] = a;
  }
}

__global__ __launch_bounds__(256) void k_h0c0(const float* __restrict__ zc, const float* __restrict__ zm,
                      const float* __restrict__ WhT, const float* __restrict__ WcT,
                      const float* __restrict__ b_h, const float* __restrict__ b_c,
                      float* __restrict__ h, float* __restrict__ c){
  __shared__ float zs[256];
  int b = blockIdx.x, j = threadIdx.x;
  zs[j] = (j < 128) ? zc[b*128 + j] : zm[b*128 + (j-128)];
  __syncthreads();
  float ah = b_h[j], ac = b_c[j];
  #pragma unroll 4
  for (int k = 0; k < 256; ++k) {
    float zv = zs[k];
    ah = fmaf(zv, WhT[k*256 + j], ah);
    ac = fmaf(zv, WcT[k*256 + j], ac);
  }
  h[b*256+j] = ah; c[b*256+j] = ac;
}

// ---------------- entire 20-step LSTM; fp8 uint4 weight loads
__global__ __launch_bounds__(1024) void k_lstm_all(
    const uint4* __restrict__ Whq8, const uint4* __restrict__ Wsq8,
    const float4* __restrict__ xg4, const float4* __restrict__ bias4,
    const float* __restrict__ h0, const float* __restrict__ c0,
    ushort* __restrict__ outsb){
  __shared__ float hs[256];
  __shared__ float4 part[3][256];
  const int b = blockIdx.x, tid = threadIdx.x;
  const int j = tid & 255, kq = tid >> 8;
  float cj = 0.f;
  if (kq == 0) { hs[j] = h0[b*256 + j]; cj = c0[b*256 + j]; }
  __syncthreads();
  for (int t = 0; t < 20; ++t) {
    const uint4* __restrict__ Wp = ((t == 0) ? Whq8 : Wsq8) + (size_t)(kq*16)*256 + j;
    float4 a = make_float4(0.f, 0.f, 0.f, 0.f);
    #pragma unroll 8
    for (int kk = 0; kk < 16; ++kk) {
      uint4 wv = Wp[(size_t)kk*256];
      const float* __restrict__ hb = &hs[kq*64 + 4*kk];
      {
        f32x2 pif = __builtin_amdgcn_cvt_pk_f32_fp8((int)wv.x, false);
        f32x2 pgo = __builtin_amdgcn_cvt_pk_f32_fp8((int)wv.x, true);
        float hv = hb[0];
        a.x = fmaf(hv, pif[0], a.x); a.y = fmaf(hv, pif[1], a.y);
        a.z = fmaf(hv, pgo[0], a.z); a.w = fmaf(hv, pgo[1], a.w);
      }
      {
        f32x2 pif = __builtin_amdgcn_cvt_pk_f32_fp8((int)wv.y, false);
        f32x2 pgo = __builtin_amdgcn_cvt_pk_f32_fp8((int)wv.y, true);
        float hv = hb[1];
        a.x = fmaf(hv, pif[0], a.x); a.y = fmaf(hv, pif[1], a.y);
        a.z = fmaf(hv, pgo[0], a.z); a.w = fmaf(hv, pgo[1], a.w);
      }
      {
        f32x2 pif = __builtin_amdgcn_cvt_pk_f32_fp8((int)wv.z, false);
        f32x2 pgo = __builtin_amdgcn_cvt_pk_f32_fp8((int)wv.z, true);
        float hv = hb[2];
        a.x = fmaf(hv, pif[0], a.x); a.y = fmaf(hv, pif[1], a.y);
        a.z = fmaf(hv, pgo[0], a.z); a.w = fmaf(hv, pgo[1], a.w);
      }
      {
        f32x2 pif = __builtin_amdgcn_cvt_pk_f32_fp8((int)wv.w, false);
        f32x2 pgo = __builtin_amdgcn_cvt_pk_f32_fp8((int)wv.w, true);
        float hv = hb[3];
        a.x = fmaf(hv, pif[0], a.x); a.y = fmaf(hv, pif[1], a.y);
        a.z = fmaf(hv, pgo[0], a.z); a.w = fmaf(hv, pgo[1], a.w);
      }
    }
    if (kq) part[kq-1][j] = a;
    __syncthreads();
    if (kq == 0) {
      float4 p1 = part[0][j], p2 = part[1][j], p3 = part[2][j];
      float4 bb = (t == 0) ? xg4[j] : bias4[j];
      a.x += p1.x + p2.x + p3.x + bb.x;
      a.y += p1.y + p2.y + p3.y + bb.y;
      a.z += p1.z + p2.z + p3.z + bb.z;
      a.w += p1.w + p2.w + p3.w + bb.w;
      float ig = sig_f(a.x), fg = sig_f(a.y), gg = tanh_f(a.z), og = sig_f(a.w);
      cj = fmaf(fg, cj, ig*gg);
      float hj = og * tanh_f(cj);
      outsb[(b*20 + t)*256 + j] = bfbits(hj);
      hs[j] = hj;
    }
    __syncthreads();
  }
}

__global__ void k_zc(const float* __restrict__ zc, ushort* __restrict__ featb){
  int e = blockIdx.x*256 + threadIdx.x;
  int r = e >> 7, c = e & 127;
  featb[r*640 + 512 + c] = bfbits(zc[(r/20)*128 + c]);
}

// ---------------- MFMA ff GEMM
__global__ __launch_bounds__(256) void k_ff_m(
    const ushort* __restrict__ A, const ushort* __restrict__ W,
    const float* __restrict__ bias, ushort* __restrict__ C)
{
  constexpr int K = 256, BK = 64, NK = K/BK, BM = 128, BN = 64;
  constexpr int RS = 72;
  constexpr int NCF = BN/16;
  constexpr int AC = 4, WC = 2;

  __shared__ __align__(16) ushort Al[2][BM*RS];
  __shared__ __align__(16) ushort Wl[2][BN*RS];

  const int tid = threadIdx.x;
  const int col0 = blockIdx.x * BN, row0 = blockIdx.y * BM;
  const int w = tid >> 6, l = tid & 63, lm = l & 15, lk = l >> 4;

  f32x4 acc[NCF][2];
  #pragma unroll
  for (int m = 0; m < NCF; ++m)
    #pragma unroll
    for (int s = 0; s < 2; ++s)
      acc[m][s] = (f32x4){0.f,0.f,0.f,0.f};

  uint4 ar[AC], wr[WC];

  #define LOADG(kt) { \
    _Pragma("unroll") \
    for (int i = 0; i < AC; ++i) { \
      int chunk = tid + i*256; \
      int rl = chunk >> 3, kc = chunk & 7; \
      ar[i] = *(const uint4*)&A[(size_t)(row0+rl)*K + (kt)*BK + kc*8]; \
    } \
    _Pragma("unroll") \
    for (int i = 0; i < WC; ++i) { \
      int chunk = tid + i*256; \
      int co = chunk >> 3, kc = chunk & 7; \
      wr[i] = *(const uint4*)&W[(size_t)(col0+co)*K + (kt)*BK + kc*8]; \
    } }

  #define STOREL(buf) { \
    _Pragma("unroll") \
    for (int i = 0; i < AC; ++i) { \
      int chunk = tid + i*256; \
      int rl = chunk >> 3, kc = chunk & 7; \
      *(uint4*)&Al[buf][rl*RS + kc*8] = ar[i]; \
    } \
    _Pragma("unroll") \
    for (int i = 0; i < WC; ++i) { \
      int chunk = tid + i*256; \
      int co = chunk >> 3, kc = chunk & 7; \
      *(uint4*)&Wl[buf][co*RS + kc*8] = wr[i]; \
    } }

  LOADG(0);
  STOREL(0);
  int cur = 0;
  for (int kt = 0; kt < NK; ++kt) {
    if (kt + 1 < NK) LOADG(kt + 1);
    __syncthreads();
    #pragma unroll
    for (int kf = 0; kf < 2; ++kf) {
      bf16x8 bfr[2];
      #pragma unroll
      for (int s = 0; s < 2; ++s)
        bfr[s] = *(bf16x8*)&Al[cur][(w*32 + s*16 + lm)*RS + kf*32 + lk*8];
      #pragma unroll
      for (int m = 0; m < NCF; ++m) {
        bf16x8 afr = *(bf16x8*)&Wl[cur][(m*16 + lm)*RS + kf*32 + lk*8];
        acc[m][0] = __builtin_amdgcn_mfma_f32_16x16x32_bf16(afr, bfr[0], acc[m][0], 0, 0, 0);
        acc[m][1] = __builtin_amdgcn_mfma_f32_16x16x32_bf16(afr, bfr[1], acc[m][1], 0, 0, 0);
      }
    }
    if (kt + 1 < NK) STOREL(cur ^ 1);
    cur ^= 1;
  }

  #pragma unroll
  for (int m = 0; m < NCF; ++m) {
    #pragma unroll
    for (int s = 0; s < 2; ++s) {
      int row = row0 + w*32 + s*16 + lm;
      f32x4 v = acc[m][s];
      int u0 = col0 + m*16 + lk*4;
      union { ushort u[4]; uint2 q; } pk;
      #pragma unroll
      for (int j = 0; j < 4; ++j)
        pk.u[j] = bfbits(LRELU(v[j] + bias[u0+j]));
      *(uint2*)&C[(size_t)row*640 + u0] = pk.q;
    }
  }
  #undef LOADG
  #undef STOREL
}

// ---------------- MFMA FC GEMM: C[1280][4096] = lrelu(A@W^T + bias), NHWC bf16 out
__global__ __launch_bounds__(256) void k_gemm_fc_m(
    const ushort* __restrict__ A, const ushort* __restrict__ W,
    const float* __restrict__ bias, ushort* __restrict__ C)
{
  constexpr int K = 640, BK = 64, NK = K/BK, BM = 128, BN = 64;
  constexpr int RS = 72;
  constexpr int NCF = BN/16;
  constexpr int AC = 4, WC = 2;

  __shared__ __align__(16) ushort Al[2][BM*RS];
  __shared__ __align__(16) ushort Wl[2][BN*RS];

  const int tid = threadIdx.x;
  const int col0 = blockIdx.x * BN, row0 = blockIdx.y * BM;
  const int w = tid >> 6, l = tid & 63, lm = l & 15, lk = l >> 4;

  f32x4 acc[NCF][2];
  #pragma unroll
  for (int m = 0; m < NCF; ++m)
    #pragma unroll
    for (int s = 0; s < 2; ++s)
      acc[m][s] = (f32x4){0.f,0.f,0.f,0.f};

  uint4 ar[AC], wr[WC];

  #define LOADG(kt) { \
    _Pragma("unroll") \
    for (int i = 0; i < AC; ++i) { \
      int chunk = tid + i*256; \
      int rl = chunk >> 3, kc = chunk & 7; \
      ar[i] = *(const uint4*)&A[(size_t)(row0+rl)*K + (kt)*BK + kc*8]; \
    } \
    _Pragma("unroll") \
    for (int i = 0; i < WC; ++i) { \
      int chunk = tid + i*256; \
      int co = chunk >> 3, kc = chunk & 7; \
      wr[i] = *(const uint4*)&W[(size_t)(col0+co)*K + (kt)*BK + kc*8]; \
    } }

  #define STOREL(buf) { \
    _Pragma("unroll") \
    for (int i = 0; i < AC; ++i) { \
      int chunk = tid + i*256; \
      int rl = chunk >> 3, kc = chunk & 7; \
      *(uint4*)&Al[buf][rl*RS + kc*8] = ar[i]; \
    } \
    _Pragma("unroll") \
    for (int i = 0; i < WC; ++i) { \
      int chunk = tid + i*256; \
      int co = chunk >> 3, kc = chunk & 7; \
      *(uint4*)&Wl[buf][co*RS + kc*8] = wr[i]; \
    } }

  LOADG(0);
  STOREL(0);
  int cur = 0;
  for (int kt = 0; kt < NK; ++kt) {
    if (kt + 1 < NK) LOADG(kt + 1);
    __syncthreads();
    #pragma unroll
    for (int kf = 0; kf < 2; ++kf) {
      bf16x8 bfr[2];
      #pragma unroll
      for (int s = 0; s < 2; ++s)
        bfr[s] = *(bf16x8*)&Al[cur][(w*32 + s*16 + lm)*RS + kf*32 + lk*8];
      #pragma unroll
      for (int m = 0; m < NCF; ++m) {
        bf16x8 afr = *(bf16x8*)&Wl[cur][(m*16 + lm)*RS + kf*32 + lk*8];
        acc[m][0] = __builtin_amdgcn_mfma_f32_16x16x32_bf16(afr, bfr[0], acc[m][0], 0, 0, 0);
        acc[m][1] = __builtin_amdgcn_mfma_f32_16x16x32_bf16(afr, bfr[1], acc[m][1], 0, 0, 0);
      }
    }
    if (kt + 1 < NK) STOREL(cur ^ 1);
    cur ^= 1;
  }

  #pragma unroll
  for (int m = 0; m < NCF; ++m) {
    #pragma unroll
    for (int s = 0; s < 2; ++s) {
      int row = row0 + w*32 + s*16 + lm;
      f32x4 v = acc[m][s];
      #pragma unroll
      for (int j = 0; j < 4; ++j) {
        int u = col0 + m*16 + lk*4 + j;
        float val = LRELU(v[j] + bias[u]);
        C[((size_t)row << 12) + ((size_t)(u & 15) << 8) + (u >> 4)] = bfbits(val);
      }
    }
  }
  #undef LOADG
  #undef STOREL
}

// ---------------- dcv/dcvw weight prep: wave-coalesced slabs per (p, m), co = m*16+lm
template<int CI, int CO>
__global__ void k_wprep_im(const float* __restrict__ w, ushort* __restrict__ wpn){
  constexpr int K = 4*CI, KF = K/32, MMW2 = CO/16;
  int e = blockIdx.x*256 + threadIdx.x;
  if (e >= 16*CI*CO) return;
  int j  = e & 7;
  int lk = (e >> 3) & 3;
  int lm = (e >> 5) & 15;
  int r3 = e >> 9;
  int kf = r3 % KF; int r4 = r3 / KF;
  int m  = r4 % MMW2; int p = r4 / MMW2;
  int k  = kf*32 + lk*8 + j;
  int t  = k / CI, ci = k % CI;
  int co = m*16 + lm;
  int py = p >> 1, px = p & 1, dy = t >> 1, dx = t & 1;
  int ky = (py ? 0 : 1) + 2*dy;
  int kx = (px ? 0 : 1) + 2*dx;
  wpn[e] = bfbits(w[((ci*CO + co)*4 + ky)*4 + kx]);
}

// wfb[t][ci] bf16 for the final tap-dot MFMA (t = ky*4+kx)
__global__ void k_wfprep(const float* __restrict__ wf, ushort* __restrict__ wfb){
  int e = blockIdx.x*256 + threadIdx.x;
  if (e < 512) {
    int t = e >> 5, ci = e & 31;
    wfb[t*32 + ci] = bfbits(wf[ci*16 + t]);
  }
}

// ---------------- MFMA parity-GEMM deconv (stage 0): A in LDS dbuf, weights
// direct-from-global in slab layout; CO-split via blockIdx.z (coz half)
template<int CI, int CO, int HI>
__global__ __launch_bounds__(256) void k_dcv(
    const ushort* __restrict__ in, const ushort* __restrict__ wp,
    ushort* __restrict__ out, float* __restrict__ gsum, float* __restrict__ gsq)
{
  constexpr int WI = HI, HO = 2*HI, WO = 2*WI;
  constexpr int K = 4*CI, BK = 64, NK = K/BK, KFT = K/32;
  constexpr int BSP = 128;
  constexpr int RS = 72;
  constexpr int NCF = CO/32;       // per-block co-frags (half of CO/16)
  constexpr int COH = CO/2;
  constexpr int AC = BSP/32;

  __shared__ __align__(16) ushort Al[2][BSP*RS];
  __shared__ float s_sum[COH], s_sq[COH];

  const int tid = threadIdx.x;
  const int sp0 = blockIdx.x * BSP;
  const int p  = blockIdx.y;
  const int coz = blockIdx.z;
  const int py = p >> 1, px = p & 1;
  const int w  = tid >> 6, l = tid & 63;
  const int lm = l & 15, lk = l >> 4;

  if (tid < COH) { s_sum[tid] = 0.f; s_sq[tid] = 0.f; }

  f32x4 acc[NCF][2];
  #pragma unroll
  for (int m = 0; m < NCF; ++m)
    #pragma unroll
    for (int s = 0; s < 2; ++s)
      acc[m][s] = (f32x4){0.f,0.f,0.f,0.f};

  uint4 ar[AC];
  const ushort* wpb = wp + (size_t)(p*(CO/16) + coz*NCF)*KFT*512;

  #define LOADT(kt) { \
    int t = ((kt)*BK)/CI, ci0 = ((kt)*BK)%CI; \
    int dy = t >> 1, dx = t & 1; \
    _Pragma("unroll") \
    for (int i = 0; i < AC; ++i) { \
      int chunk = tid + i*256; \
      int rl = chunk >> 3, kc = chunk & 7; \
      int r = sp0 + rl; \
      int n = r / (HI*WI), rem = r % (HI*WI); \
      int oy = rem / WI, ox = rem % WI; \
      int iy = oy + py - dy, ix = ox + px - dx; \
      if ((unsigned)iy < (unsigned)HI && (unsigned)ix < (unsigned)WI) \
        ar[i] = *(const uint4*)&in[((((size_t)n*HI + iy)*WI + ix)*CI) + ci0 + kc*8]; \
      else ar[i] = make_uint4(0,0,0,0); \
    } }

  #define STORET(buf) { \
    _Pragma("unroll") \
    for (int i = 0; i < AC; ++i) { \
      int chunk = tid + i*256; \
      int rl = chunk >> 3, kc = chunk & 7; \
      *(uint4*)&Al[buf][rl*RS + kc*8] = ar[i]; \
    } }

  LOADT(0);
  STORET(0);
  int cur = 0;
  for (int kt = 0; kt < NK; ++kt) {
    if (kt + 1 < NK) LOADT(kt + 1);
    __syncthreads();
    #pragma unroll
    for (int kf = 0; kf < 2; ++kf) {
      const int ktg = kt*2 + kf;
      bf16x8 bfr[2];
      #pragma unroll
      for (int s = 0; s < 2; ++s)
        bfr[s] = *(bf16x8*)&Al[cur][(w*32 + s*16 + lm)*RS + kf*32 + lk*8];
      #pragma unroll
      for (int m = 0; m < NCF; ++m) {
        bf16x8 afr = *(const bf16x8*)&wpb[((size_t)m*KFT + ktg)*512 + lm*32 + lk*8];
        acc[m][0] = __builtin_amdgcn_mfma_f32_16x16x32_bf16(afr, bfr[0], acc[m][0], 0, 0, 0);
        acc[m][1] = __builtin_amdgcn_mfma_f32_16x16x32_bf16(afr, bfr[1], acc[m][1], 0, 0, 0);
      }
    }
    if (kt + 1 < NK) STORET(cur ^ 1);
    cur ^= 1;
  }

  // pass 1: batch stats only (this CO half)
  #pragma unroll
  for (int m = 0; m < NCF; ++m) {
    float s1[4] = {0,0,0,0}, s2[4] = {0,0,0,0};
    #pragma unroll
    for (int s = 0; s < 2; ++s) {
      f32x4 v = acc[m][s];
      #pragma unroll
      for (int j = 0; j < 4; ++j) { s1[j] += v[j]; s2[j] += v[j]*v[j]; }
    }
    #pragma unroll
    for (int j = 0; j < 4; ++j) {
      float a = s1[j], b = s2[j];
      #pragma unroll
      for (int o = 1; o < 16; o <<= 1) { a += __shfl_xor(a, o); b += __shfl_xor(b, o); }
      if (lm == 0) {
        atomicAdd(&s_sum[m*16 + lk*4 + j], a);
        atomicAdd(&s_sq [m*16 + lk*4 + j], b);
      }
    }
  }
  // pass 2: stores, s-outer / m-inner (contiguous 128B half-line per pixel)
  #pragma unroll
  for (int s = 0; s < 2; ++s) {
    int sp = sp0 + w*32 + s*16 + lm;
    int n = sp / (HI*WI), rem = sp % (HI*WI);
    int y = 2*(rem / WI) + py, x = 2*(rem % WI) + px;
    size_t ob = (((size_t)n*HO + y)*WO + x)*CO + coz*COH + lk*4;
    #pragma unroll
    for (int m = 0; m < NCF; ++m) {
      f32x4 v = acc[m][s];
      union { ushort u[4]; uint2 q; } pk;
      pk.u[0] = bfbits(v[0]); pk.u[1] = bfbits(v[1]);
      pk.u[2] = bfbits(v[2]); pk.u[3] = bfbits(v[3]);
      *(uint2*)&out[ob + m*16] = pk.q;
    }
  }
  __syncthreads();
  for (int cc = tid; cc < COH; cc += 256) {
    atomicAdd(&gsum[coz*COH + cc], s_sum[cc]);
    atomicAdd(&gsq[coz*COH + cc],  s_sq[cc]);
  }
  #undef LOADT
  #undef STORET
}

// ---------------- deconv stages 1&2: LDS-resident WEIGHTS (one parity per
// block), G images looped with LDS-staged input; kf loop is pure LDS+MFMA.
// Kills the per-wave global weight re-read stream (was ~670MB L2 traffic).
template<int CI, int CO, int HI, int G, int MINW>
__global__ __launch_bounds__(512, MINW) void k_dcvw(
    const ushort* __restrict__ in, const ushort* __restrict__ wp,
    const float* __restrict__ gsumP, const float* __restrict__ gsqP,
    const float* __restrict__ gP, const float* __restrict__ beP, float invNP,
    ushort* __restrict__ out, float* __restrict__ gsum, float* __restrict__ gsq)
{
  constexpr int WI = HI, HO = 2*HI, WO = 2*WI;
  constexpr int KF = 4*CI/32;
  constexpr int PAD = HI + 2;
  constexpr int CICH = CI/8;
  constexpr int MMW2 = CO/16;
  constexpr int NPX = HI*WI;          // output px per parity per image
  constexpr int TILES = NPX/16;
  constexpr int PPW = TILES*MMW2/8;   // (tile,m) pairs per wave

  __shared__ __align__(16) ushort Wl[MMW2*KF*512];
  __shared__ __align__(16) ushort Ain[PAD*PAD*CI];
  __shared__ float s_scale[CI], s_shift[CI];
  __shared__ float s_sum[CO], s_sq[CO];

  const int tid = threadIdx.x;
  const int g0 = blockIdx.x * G;
  const int p = blockIdx.y, py = p >> 1, px = p & 1;
  const int w = tid >> 6, l = tid & 63, lm = l & 15, lk = l >> 4;

  if (tid < CO) { s_sum[tid] = 0.f; s_sq[tid] = 0.f; }
  if (tid >= 512-CI) {
    int c = tid - (512-CI);
    float m = gsumP[c]*invNP;
    float v = gsqP[c]*invNP - m*m;
    float sc = gP[c]*rsqrtf(v + 1e-5f);
    s_scale[c] = sc;
    s_shift[c] = beP[c] - m*sc;
  }
  // stage this parity's weight slab once
  {
    const uint4* wpb4 = (const uint4*)(wp + (size_t)(p*MMW2)*KF*512);
    constexpr int WCH = MMW2*KF*64;   // uint4 chunks
    for (int e = tid; e < WCH; e += 512)
      ((uint4*)Wl)[e] = wpb4[e];
  }
  __syncthreads();

  float st1[PPW][4], st2[PPW][4];
  #pragma unroll
  for (int i = 0; i < PPW; ++i)
    #pragma unroll
    for (int j = 0; j < 4; ++j) { st1[i][j] = 0.f; st2[i][j] = 0.f; }

  for (int gi = 0; gi < G; ++gi) {
    const int n = g0 + gi;
    // stage input image (BN+LReLU of previous stage), swizzled
    const ushort* inb = in + (size_t)n * HI * WI * CI;
    constexpr int NPCH = PAD*PAD*CICH;
    for (int e = tid; e < NPCH; e += 512) {
      int ci8 = e % CICH; int sp = e / CICH;
      int c = sp % PAD, r = sp / PAD;
      int chS = ci8 ^ (c & 7);
      if (r >= 1 && r <= HI && c >= 1 && c <= WI) {
        uint4 u = *(const uint4*)&inb[(((size_t)(r-1)*WI + (c-1))*CI) + ci8*8];
        int ci0 = ci8*8;
        float4 sc0 = *(const float4*)&s_scale[ci0];
        float4 sc1 = *(const float4*)&s_scale[ci0+4];
        float4 sh0 = *(const float4*)&s_shift[ci0];
        float4 sh1 = *(const float4*)&s_shift[ci0+4];
        float v0 = LRELU(fmaf(bflo(u.x), sc0.x, sh0.x));
        float v1 = LRELU(fmaf(bfhi(u.x), sc0.y, sh0.y));
        float v2 = LRELU(fmaf(bflo(u.y), sc0.z, sh0.z));
        float v3 = LRELU(fmaf(bfhi(u.y), sc0.w, sh0.w));
        float v4 = LRELU(fmaf(bflo(u.z), sc1.x, sh1.x));
        float v5 = LRELU(fmaf(bfhi(u.z), sc1.y, sh1.y));
        float v6 = LRELU(fmaf(bflo(u.w), sc1.z, sh1.z));
        float v7 = LRELU(fmaf(bfhi(u.w), sc1.w, sh1.w));
        uint4 o;
        o.x = (uint)bfpack(v0, v1);
        o.y = (uint)bfpack(v2, v3);
        o.z = (uint)bfpack(v4, v5);
        o.w = (uint)bfpack(v6, v7);
        ((uint4*)Ain)[(r*PAD + c)*CICH + chS] = o;
      } else {
        ((uint4*)Ain)[(r*PAD + c)*CICH + chS] = make_uint4(0,0,0,0);
      }
    }
    __syncthreads();

    f32x4 acc[PPW];
    #pragma unroll
    for (int i = 0; i < PPW; ++i) acc[i] = (f32x4){0.f,0.f,0.f,0.f};

    #pragma unroll
    for (int kf = 0; kf < KF; ++kf) {
      const int t = (kf*32)/CI, cib = (kf*32)%CI;
      const int dy = t >> 1, dx = t & 1;
      const int ch = (cib >> 3) + lk;
      #pragma unroll
      for (int i = 0; i < PPW; ++i) {
        const int q = w*PPW + i;
        const int tl = q / MMW2, m = q % MMW2;
        int s = tl*16 + lm;
        int y = s / WI, x = s % WI;
        int r = y + py - dy + 1, c = x + px - dx + 1;
        bf16x8 bfr = *(const bf16x8*)&Ain[((r*PAD + c)*CICH + (ch ^ (c & 7)))*8];
        bf16x8 afr = *(const bf16x8*)&Wl[((size_t)m*KF + kf)*512 + lm*32 + lk*8];
        acc[i] = __builtin_amdgcn_mfma_f32_16x16x32_bf16(afr, bfr, acc[i], 0, 0, 0);
      }
    }

    // stores + register stats
    #pragma unroll
    for (int i = 0; i < PPW; ++i) {
      const int q = w*PPW + i;
      const int tl = q / MMW2, m = q % MMW2;
      int s = tl*16 + lm;
      int y = 2*(s / WI) + py, x = 2*(s % WI) + px;
      size_t ob = (((size_t)n*HO + y)*WO + x)*CO + m*16 + lk*4;
      f32x4 v = acc[i];
      union { ushort u[4]; uint2 qq; } pk;
      #pragma unroll
      for (int j = 0; j < 4; ++j) {
        pk.u[j] = bfbits(v[j]);
        st1[i][j] += v[j];
        st2[i][j] += v[j]*v[j];
      }
      *(uint2*)&out[ob] = pk.qq;
    }
    __syncthreads();   // Ain reuse for next image
  }

  // stats: reduce over lm within wave, then LDS atomics, then global
  #pragma unroll
  for (int i = 0; i < PPW; ++i) {
    const int m = (w*PPW + i) % MMW2;
    #pragma unroll
    for (int j = 0; j < 4; ++j) {
      float a = st1[i][j], b = st2[i][j];
      #pragma unroll
      for (int o = 1; o < 16; o <<= 1) { a += __shfl_xor(a, o); b += __shfl_xor(b, o); }
      if (lm == 0) {
        atomicAdd(&s_sum[m*16 + lk*4 + j], a);
        atomicAdd(&s_sq [m*16 + lk*4 + j], b);
      }
    }
  }
  __syncthreads();
  for (int cc = tid; cc < CO; cc += 512) {
    atomicAdd(&gsum[cc], s_sum[cc]);
    atomicAdd(&gsq[cc],  s_sq[cc]);
  }
}

// ---------------- final deconv 32->1 + sigmoid via tap-dot MFMA
__global__ __launch_bounds__(256) void k_final(
    const ushort* __restrict__ in, const ushort* __restrict__ wfb,
    const float* __restrict__ gsumP, const float* __restrict__ gsqP,
    const float* __restrict__ gP, const float* __restrict__ beP, float invNP,
    const float* __restrict__ bfb, float* __restrict__ outp)
{
  constexpr int CI=32, HI=32, WI=32, HO=64, WO=64, SPLIT=4, HOq=HO/SPLIT;
  constexpr int RMAX = 10;
  constexpr int DP = 20;
  __shared__ float Dl[RMAX*32*DP];
  __shared__ float s_scale[CI], s_shift[CI];

  const int tid = threadIdx.x, bid = blockIdx.x;
  const int n = bid % 1280, q = bid / 1280;
  const int y0 = q * HOq;
  const int rows_lo = max(0, y0/2 - 1);
  const int rows_hi = min(HI-1, (y0 + HOq)/2);
  const int nrows = rows_hi - rows_lo + 1;

  if (tid < CI) {
    float m = gsumP[tid]*invNP;
    float v = gsqP[tid]*invNP - m*m;
    float sc = gP[tid]*rsqrtf(v + 1e-5f);
    s_scale[tid] = sc;
    s_shift[tid] = beP[tid] - m*sc;
  }
  __syncthreads();

  const int w = tid >> 6, l = tid & 63, lm = l & 15, lk = l >> 4;
  const bf16x8 afr = *(const bf16x8*)&wfb[lm*32 + lk*8];
  const float4 sc0 = *(const float4*)&s_scale[lk*8];
  const float4 sc1 = *(const float4*)&s_scale[lk*8+4];
  const float4 sh0 = *(const float4*)&s_shift[lk*8];
  const float4 sh1 = *(const float4*)&s_shift[lk*8+4];

  const ushort* inb = in + (size_t)n * HI * WI * CI;
  const int ngrp = nrows * 2;
  for (int g = w; g < ngrp; g += 4) {
    int px = g*16 + lm;
    int rl = px >> 5, ix = px & 31;
    uint4 u = *(const uint4*)&inb[(((size_t)(rows_lo+rl)*WI + ix)*CI) + lk*8];
    float v0 = LRELU(fmaf(bflo(u.x), sc0.x, sh0.x));
    float v1 = LRELU(fmaf(bfhi(u.x), sc0.y, sh0.y));
    float v2 = LRELU(fmaf(bflo(u.y), sc0.z, sh0.z));
    float v3 = LRELU(fmaf(bfhi(u.y), sc0.w, sh0.w));
    float v4 = LRELU(fmaf(bflo(u.z), sc1.x, sh1.x));
    float v5 = LRELU(fmaf(bfhi(u.z), sc1.y, sh1.y));
    float v6 = LRELU(fmaf(bflo(u.w), sc1.z, sh1.z));
    float v7 = LRELU(fmaf(bfhi(u.w), sc1.w, sh1.w));
    union { uint uu[4]; bf16x8 v; } pk;
    pk.uu[0] = bfpack(v0, v1);
    pk.uu[1] = bfpack(v2, v3);
    pk.uu[2] = bfpack(v4, v5);
    pk.uu[3] = bfpack(v6, v7);
    f32x4 d = __builtin_amdgcn_mfma_f32_16x16x32_bf16(afr, pk.v, (f32x4){0.f,0.f,0.f,0.f}, 0, 0, 0);
    *(f32x4*)&Dl[px*DP + lk*4] = d;
  }
  __syncthreads();

  const float b0 = bfb[0];
  #pragma unroll
  for (int i = 0; i < (HOq*WO)/256; ++i) {
    int e = tid + i*256;
    int oy = e >> 6, x = e & 63;
    int y = y0 + oy;
    int kya = (y + 1) & 1, iya = (y + 1) >> 1;
    int kxa = (x + 1) & 1, ixa = (x + 1) >> 1;
    float acc = b0;
    #pragma unroll
    for (int dy = 0; dy < 2; ++dy) {
      int iy = iya - dy, ky = kya + 2*dy;
      if (iy < 0 || iy >= HI) continue;
      #pragma unroll
      for (int dx = 0; dx < 2; ++dx) {
        int ix = ixa - dx, kx = kxa + 2*dx;
        if (ix < 0 || ix >= WI) continue;
        acc += Dl[((iy - rows_lo)*WI + ix)*DP + (ky*4 + kx)];
      }
    }
    outp[(size_t)n*HO*WO + y*WO + x] = 1.f/(1.f + __expf(-acc));
  }
}

extern "C" void kernel_launch(void* const* d_in, const int* in_sizes, int n_in,
                              void* d_out, int out_size, void* d_ws, size_t ws_size,
                              hipStream_t stream) {
  const float* z_content = (const float*)d_in[0];
  const float* z_motion  = (const float*)d_in[1];
  const float* W_h  = (const float*)d_in[2];
  const float* b_h  = (const float*)d_in[3];
  const float* W_c  = (const float*)d_in[4];
  const float* b_c  = (const float*)d_in[5];
  const float* W_ih = (const float*)d_in[6];
  const float* W_hh = (const float*)d_in[7];
  const float* b_ih = (const float*)d_in[8];
  const float* b_hh = (const float*)d_in[9];
  const float* W_f  = (const float*)d_in[10];
  const float* b_f  = (const float*)d_in[11];
  const float* init_in = (const float*)d_in[12];
  const float* fc_W = (const float*)d_in[13];
  const float* fc_b = (const float*)d_in[14];
  const float* w0 = (const float*)d_in[15];
  const float* g0 = (const float*)d_in[16];
  const float* be0 = (const float*)d_in[17];
  const float* w1 = (const float*)d_in[18];
  const float* g1 = (const float*)d_in[19];
  const float* be1 = (const float*)d_in[20];
  const float* w2 = (const float*)d_in[21];
  const float* g2 = (const float*)d_in[22];
  const float* be2 = (const float*)d_in[23];
  const float* wf = (const float*)d_in[24];
  const float* bf_ = (const float*)d_in[25];

  const size_t P_BYTES = 10631168;
  const size_t X_OFF   = P_BYTES;
  const size_t X_BYTES = 83886080;
  const size_t Y_OFF   = X_OFF + X_BYTES;
  const size_t NEED    = Y_OFF + 41943040;
  if (ws_size < NEED) return;

  float* ws = (float*)d_ws;
  char*  wsb = (char*)d_ws;
  float* sum0 = ws + 0;        float* sq0 = ws + 128;
  float* sum1 = ws + 256;      float* sq1 = ws + 320;
  float* sum2 = ws + 384;      float* sq2 = ws + 416;
  float4* xg4   = (float4*)(ws + 1024);
  float4* bias4 = (float4*)(ws + 2048);
  float* h    = ws + 3072;
  float* c    = ws + 19456;
  ushort* outsb = (ushort*)(ws + 35840);
  float* WhT  = ws + 199680;
  float* WcT  = ws + 265216;
  uint4* Whq8 = (uint4*)(ws + 330752);
  uint4* Wsq8 = (uint4*)(ws + 592896);
  ushort* wp0 = (ushort*)(ws + 855040);
  ushort* wp1 = (ushort*)(ws + 1117184);
  ushort* wp2 = (ushort*)(ws + 1182720);
  ushort* wfb = (ushort*)(ws + 1199104);
  ushort* wpff = (ushort*)(ws + 1199616);
  ushort* featb = (ushort*)(ws + 1265152);

  ushort* wpfc = (ushort*)(wsb + X_OFF);
  ushort* out0 = (ushort*)(wsb + X_OFF);
  ushort* out2 = (ushort*)(wsb + X_OFF);
  ushort* h1   = (ushort*)(wsb + Y_OFF);
  ushort* out1 = (ushort*)(wsb + Y_OFF);

  dim3 tb(32,8);
  k_transpose<<<dim3(8,8),   tb, 0, stream>>>(W_h,  WhT, 256, 256);
  k_transpose<<<dim3(8,8),   tb, 0, stream>>>(W_c,  WcT, 256, 256);
  k_tobf16<<<10240, 256, 0, stream>>>(fc_W, wpfc, 2621440);
  k_tobf16<<<512, 256, 0, stream>>>(W_f, wpff, 131072);
  k_w4prep<<<64, 256, 0, stream>>>(W_ih, W_hh, Whq8, Wsq8, ws);
  k_xgbias<<<256, 256, 0, stream>>>(W_ih, b_ih, b_hh, init_in, xg4, bias4);
  k_h0c0<<<64, 256, 0, stream>>>(z_content, z_motion, WhT, WcT, b_h, b_c, h, c);
  k_wprep_im<256,128><<<2048, 256, 0, stream>>>(w0, wp0);
  k_wprep_im<128,64><<<512, 256, 0, stream>>>(w1, wp1);
  k_wprep_im<64,32><<<128, 256, 0, stream>>>(w2, wp2);
  k_wfprep<<<2, 256, 0, stream>>>(wf, wfb);

  // ---- whole LSTM in one launch (fp8 weights)
  k_lstm_all<<<64, 1024, 0, stream>>>(Whq8, Wsq8, xg4, bias4, h, c, outsb);

  // ---- ff (MFMA) + concat + fc (MFMA)
  k_ff_m<<<dim3(8, 10), 256, 0, stream>>>(outsb, wpff, b_f, featb);
  k_zc<<<640, 256, 0, stream>>>(z_content, featb);
  k_gemm_fc_m<<<dim3(64, 10), 256, 0, stream>>>(featb, wpfc, fc_b, h1);

  // ---- deconv pipeline (stage0 CO-split; stages 1&2 weight-in-LDS)
  k_dcv<256,128,4><<<dim3(160,4,2), 256, 0, stream>>>(h1, wp0, out0, sum0, sq0);
  k_dcvw<128,64,8,8,2><<<dim3(160,4), 512, 0, stream>>>(out0, wp1, sum0, sq0, g0, be0, 1.f/81920.f, out1, sum1, sq1);
  k_dcvw<64,32,16,8,4><<<dim3(160,4), 512, 0, stream>>>(out1, wp2, sum1, sq1, g1, be1, 1.f/327680.f, out2, sum2, sq2);
  k_final<<<5120, 256, 0, stream>>>(out2, wfb, sum2, sq2, g2, be2, 1.f/1310720.f, bf_, (float*)d_out);
}

// Round 25
// 444.967 us; speedup vs baseline: 1.0919x; 1.0919x over previous
//
#include <hip/hip_runtime.h>
#include <hip/hip_bf16.h>
#include <math.h>

typedef __hip_bfloat16 bf16;
typedef __attribute__((ext_vector_type(8))) short bf16x8;
typedef __attribute__((ext_vector_type(4))) float f32x4;
typedef __attribute__((ext_vector_type(2))) float f32x2;

#define LRELU(v) ((v) > 0.f ? (v) : 0.2f*(v))

__device__ __forceinline__ float sig_f(float x){ return 1.f/(1.f + __expf(-x)); }
__device__ __forceinline__ float tanh_f(float x){
  float ax = fabsf(x);
  float e = __expf(-2.f*ax);
  float t = (1.f - e)/(1.f + e);
  return x >= 0.f ? t : -t;
}
__device__ __forceinline__ ushort bfbits(float v){
  bf16 b = __float2bfloat16(v);
  return *(ushort*)&b;
}
__device__ __forceinline__ uint bfpack(float a, float b){
  return (uint)bfbits(a) | ((uint)bfbits(b) << 16);
}
__device__ __forceinline__ float bflo(uint u){ return __uint_as_float(u << 16); }
__device__ __forceinline__ float bfhi(uint u){ return __uint_as_float(u & 0xffff0000u); }

__global__ void k_tobf16(const float* __restrict__ src, ushort* __restrict__ dst, int n){
  int i = blockIdx.x*256 + threadIdx.x;
  if (i < n) dst[i] = bfbits(src[i]);
}

// ---------------- generic tiled transpose
__global__ void k_transpose(const float* __restrict__ src, float* __restrict__ dst, int R, int C){
  __shared__ float t[32][33];
  int c0 = blockIdx.x*32, r0 = blockIdx.y*32;
  int tx = threadIdx.x, ty = threadIdx.y;
  #pragma unroll
  for (int i = 0; i < 4; ++i)
    t[ty+8*i][tx] = src[(size_t)(r0+ty+8*i)*C + c0+tx];
  __syncthreads();
  #pragma unroll
  for (int i = 0; i < 4; ++i)
    dst[(size_t)(c0+ty+8*i)*R + r0+tx] = t[tx][ty+8*i];
}

// ---------------- LSTM weight pack: fp8 e4m3, uint per k: bytes {i,f,g,o}
__global__ void k_w4prep(const float* __restrict__ Wih, const float* __restrict__ Whh,
                         uint4* __restrict__ Whq8, uint4* __restrict__ Wsq8,
                         float* __restrict__ stats){
  int k4 = blockIdx.x, j = threadIdx.x;
  if (k4 < 2) { int i = k4*256 + j; if (i < 448) stats[i] = 0.f; }
  uint h4[4], s4[4];
  #pragma unroll
  for (int d = 0; d < 4; ++d) {
    int k = 4*k4 + d;
    float hi = Whh[j*256+k],       hf = Whh[(256+j)*256+k];
    float hg = Whh[(512+j)*256+k], ho = Whh[(768+j)*256+k];
    float ii = Wih[j*256+k],       iff = Wih[(256+j)*256+k];
    float ig = Wih[(512+j)*256+k], io = Wih[(768+j)*256+k];
    int lo = __builtin_amdgcn_cvt_pk_fp8_f32(hi, hf, 0, false);
    h4[d] = (uint)__builtin_amdgcn_cvt_pk_fp8_f32(hg, ho, lo, true);
    lo = __builtin_amdgcn_cvt_pk_fp8_f32(hi+ii, hf+iff, 0, false);
    s4[d] = (uint)__builtin_amdgcn_cvt_pk_fp8_f32(hg+ig, ho+io, lo, true);
  }
  Whq8[k4*256+j] = make_uint4(h4[0], h4[1], h4[2], h4[3]);
  Wsq8[k4*256+j] = make_uint4(s4[0], s4[1], s4[2], s4[3]);
}

__global__ void k_xgbias(const float* __restrict__ Wih, const float* __restrict__ b_ih,
                         const float* __restrict__ b_hh, const float* __restrict__ init_in,
                         float4* __restrict__ xg4, float4* __restrict__ bias4){
  int b = blockIdx.x, t = threadIdx.x;
  float v = init_in[t];
  float p0 = v * Wih[b*256 + t];
  float p1 = v * Wih[(256+b)*256 + t];
  float p2 = v * Wih[(512+b)*256 + t];
  float p3 = v * Wih[(768+b)*256 + t];
  #pragma unroll
  for (int o = 32; o; o >>= 1) {
    p0 += __shfl_xor(p0, o); p1 += __shfl_xor(p1, o);
    p2 += __shfl_xor(p2, o); p3 += __shfl_xor(p3, o);
  }
  __shared__ float4 red[4];
  int lane = t & 63, wid = t >> 6;
  if (lane == 0) red[wid] = make_float4(p0,p1,p2,p3);
  __syncthreads();
  if (t == 0) {
    float4 bi = make_float4(b_ih[b]+b_hh[b], b_ih[256+b]+b_hh[256+b],
                            b_ih[512+b]+b_hh[512+b], b_ih[768+b]+b_hh[768+b]);
    bias4[b] = bi;
    float4 a = bi;
    #pragma unroll
    for (int w = 0; w < 4; ++w) { a.x += red[w].x; a.y += red[w].y; a.z += red[w].z; a.w += red[w].w; }
    xg4[b] = a;
  }
}

__global__ __launch_bounds__(256) void k_h0c0(const float* __restrict__ zc, const float* __restrict__ zm,
                      const float* __restrict__ WhT, const float* __restrict__ WcT,
                      const float* __restrict__ b_h, const float* __restrict__ b_c,
                      float* __restrict__ h, float* __restrict__ c){
  __shared__ float zs[256];
  int b = blockIdx.x, j = threadIdx.x;
  zs[j] = (j < 128) ? zc[b*128 + j] : zm[b*128 + (j-128)];
  __syncthreads();
  float ah = b_h[j], ac = b_c[j];
  #pragma unroll 4
  for (int k = 0; k < 256; ++k) {
    float zv = zs[k];
    ah = fmaf(zv, WhT[k*256 + j], ah);
    ac = fmaf(zv, WcT[k*256 + j], ac);
  }
  h[b*256+j] = ah; c[b*256+j] = ac;
}

// ---------------- entire 20-step LSTM; fp8 uint4 weight loads
__global__ __launch_bounds__(1024) void k_lstm_all(
    const uint4* __restrict__ Whq8, const uint4* __restrict__ Wsq8,
    const float4* __restrict__ xg4, const float4* __restrict__ bias4,
    const float* __restrict__ h0, const float* __restrict__ c0,
    ushort* __restrict__ outsb){
  __shared__ float hs[256];
  __shared__ float4 part[3][256];
  const int b = blockIdx.x, tid = threadIdx.x;
  const int j = tid & 255, kq = tid >> 8;
  float cj = 0.f;
  if (kq == 0) { hs[j] = h0[b*256 + j]; cj = c0[b*256 + j]; }
  __syncthreads();
  for (int t = 0; t < 20; ++t) {
    const uint4* __restrict__ Wp = ((t == 0) ? Whq8 : Wsq8) + (size_t)(kq*16)*256 + j;
    float4 a = make_float4(0.f, 0.f, 0.f, 0.f);
    #pragma unroll 8
    for (int kk = 0; kk < 16; ++kk) {
      uint4 wv = Wp[(size_t)kk*256];
      const float* __restrict__ hb = &hs[kq*64 + 4*kk];
      {
        f32x2 pif = __builtin_amdgcn_cvt_pk_f32_fp8((int)wv.x, false);
        f32x2 pgo = __builtin_amdgcn_cvt_pk_f32_fp8((int)wv.x, true);
        float hv = hb[0];
        a.x = fmaf(hv, pif[0], a.x); a.y = fmaf(hv, pif[1], a.y);
        a.z = fmaf(hv, pgo[0], a.z); a.w = fmaf(hv, pgo[1], a.w);
      }
      {
        f32x2 pif = __builtin_amdgcn_cvt_pk_f32_fp8((int)wv.y, false);
        f32x2 pgo = __builtin_amdgcn_cvt_pk_f32_fp8((int)wv.y, true);
        float hv = hb[1];
        a.x = fmaf(hv, pif[0], a.x); a.y = fmaf(hv, pif[1], a.y);
        a.z = fmaf(hv, pgo[0], a.z); a.w = fmaf(hv, pgo[1], a.w);
      }
      {
        f32x2 pif = __builtin_amdgcn_cvt_pk_f32_fp8((int)wv.z, false);
        f32x2 pgo = __builtin_amdgcn_cvt_pk_f32_fp8((int)wv.z, true);
        float hv = hb[2];
        a.x = fmaf(hv, pif[0], a.x); a.y = fmaf(hv, pif[1], a.y);
        a.z = fmaf(hv, pgo[0], a.z); a.w = fmaf(hv, pgo[1], a.w);
      }
      {
        f32x2 pif = __builtin_amdgcn_cvt_pk_f32_fp8((int)wv.w, false);
        f32x2 pgo = __builtin_amdgcn_cvt_pk_f32_fp8((int)wv.w, true);
        float hv = hb[3];
        a.x = fmaf(hv, pif[0], a.x); a.y = fmaf(hv, pif[1], a.y);
        a.z = fmaf(hv, pgo[0], a.z); a.w = fmaf(hv, pgo[1], a.w);
      }
    }
    if (kq) part[kq-1][j] = a;
    __syncthreads();
    if (kq == 0) {
      float4 p1 = part[0][j], p2 = part[1][j], p3 = part[2][j];
      float4 bb = (t == 0) ? xg4[j] : bias4[j];
      a.x += p1.x + p2.x + p3.x + bb.x;
      a.y += p1.y + p2.y + p3.y + bb.y;
      a.z += p1.z + p2.z + p3.z + bb.z;
      a.w += p1.w + p2.w + p3.w + bb.w;
      float ig = sig_f(a.x), fg = sig_f(a.y), gg = tanh_f(a.z), og = sig_f(a.w);
      cj = fmaf(fg, cj, ig*gg);
      float hj = og * tanh_f(cj);
      outsb[(b*20 + t)*256 + j] = bfbits(hj);
      hs[j] = hj;
    }
    __syncthreads();
  }
}

__global__ void k_zc(const float* __restrict__ zc, ushort* __restrict__ featb){
  int e = blockIdx.x*256 + threadIdx.x;
  int r = e >> 7, c = e & 127;
  featb[r*640 + 512 + c] = bfbits(zc[(r/20)*128 + c]);
}

// ---------------- MFMA ff GEMM
__global__ __launch_bounds__(256) void k_ff_m(
    const ushort* __restrict__ A, const ushort* __restrict__ W,
    const float* __restrict__ bias, ushort* __restrict__ C)
{
  constexpr int K = 256, BK = 64, NK = K/BK, BM = 128, BN = 64;
  constexpr int RS = 72;
  constexpr int NCF = BN/16;
  constexpr int AC = 4, WC = 2;

  __shared__ __align__(16) ushort Al[2][BM*RS];
  __shared__ __align__(16) ushort Wl[2][BN*RS];

  const int tid = threadIdx.x;
  const int col0 = blockIdx.x * BN, row0 = blockIdx.y * BM;
  const int w = tid >> 6, l = tid & 63, lm = l & 15, lk = l >> 4;

  f32x4 acc[NCF][2];
  #pragma unroll
  for (int m = 0; m < NCF; ++m)
    #pragma unroll
    for (int s = 0; s < 2; ++s)
      acc[m][s] = (f32x4){0.f,0.f,0.f,0.f};

  uint4 ar[AC], wr[WC];

  #define LOADG(kt) { \
    _Pragma("unroll") \
    for (int i = 0; i < AC; ++i) { \
      int chunk = tid + i*256; \
      int rl = chunk >> 3, kc = chunk & 7; \
      ar[i] = *(const uint4*)&A[(size_t)(row0+rl)*K + (kt)*BK + kc*8]; \
    } \
    _Pragma("unroll") \
    for (int i = 0; i < WC; ++i) { \
      int chunk = tid + i*256; \
      int co = chunk >> 3, kc = chunk & 7; \
      wr[i] = *(const uint4*)&W[(size_t)(col0+co)*K + (kt)*BK + kc*8]; \
    } }

  #define STOREL(buf) { \
    _Pragma("unroll") \
    for (int i = 0; i < AC; ++i) { \
      int chunk = tid + i*256; \
      int rl = chunk >> 3, kc = chunk & 7; \
      *(uint4*)&Al[buf][rl*RS + kc*8] = ar[i]; \
    } \
    _Pragma("unroll") \
    for (int i = 0; i < WC; ++i) { \
      int chunk = tid + i*256; \
      int co = chunk >> 3, kc = chunk & 7; \
      *(uint4*)&Wl[buf][co*RS + kc*8] = wr[i]; \
    } }

  LOADG(0);
  STOREL(0);
  int cur = 0;
  for (int kt = 0; kt < NK; ++kt) {
    if (kt + 1 < NK) LOADG(kt + 1);
    __syncthreads();
    #pragma unroll
    for (int kf = 0; kf < 2; ++kf) {
      bf16x8 bfr[2];
      #pragma unroll
      for (int s = 0; s < 2; ++s)
        bfr[s] = *(bf16x8*)&Al[cur][(w*32 + s*16 + lm)*RS + kf*32 + lk*8];
      #pragma unroll
      for (int m = 0; m < NCF; ++m) {
        bf16x8 afr = *(bf16x8*)&Wl[cur][(m*16 + lm)*RS + kf*32 + lk*8];
        acc[m][0] = __builtin_amdgcn_mfma_f32_16x16x32_bf16(afr, bfr[0], acc[m][0], 0, 0, 0);
        acc[m][1] = __builtin_amdgcn_mfma_f32_16x16x32_bf16(afr, bfr[1], acc[m][1], 0, 0, 0);
      }
    }
    if (kt + 1 < NK) STOREL(cur ^ 1);
    cur ^= 1;
  }

  #pragma unroll
  for (int m = 0; m < NCF; ++m) {
    #pragma unroll
    for (int s = 0; s < 2; ++s) {
      int row = row0 + w*32 + s*16 + lm;
      f32x4 v = acc[m][s];
      int u0 = col0 + m*16 + lk*4;
      union { ushort u[4]; uint2 q; } pk;
      #pragma unroll
      for (int j = 0; j < 4; ++j)
        pk.u[j] = bfbits(LRELU(v[j] + bias[u0+j]));
      *(uint2*)&C[(size_t)row*640 + u0] = pk.q;
    }
  }
  #undef LOADG
  #undef STOREL
}

// ---------------- MFMA FC GEMM: C[1280][4096] = lrelu(A@W^T + bias), NHWC bf16 out
__global__ __launch_bounds__(256) void k_gemm_fc_m(
    const ushort* __restrict__ A, const ushort* __restrict__ W,
    const float* __restrict__ bias, ushort* __restrict__ C)
{
  constexpr int K = 640, BK = 64, NK = K/BK, BM = 128, BN = 64;
  constexpr int RS = 72;
  constexpr int NCF = BN/16;
  constexpr int AC = 4, WC = 2;

  __shared__ __align__(16) ushort Al[2][BM*RS];
  __shared__ __align__(16) ushort Wl[2][BN*RS];

  const int tid = threadIdx.x;
  const int col0 = blockIdx.x * BN, row0 = blockIdx.y * BM;
  const int w = tid >> 6, l = tid & 63, lm = l & 15, lk = l >> 4;

  f32x4 acc[NCF][2];
  #pragma unroll
  for (int m = 0; m < NCF; ++m)
    #pragma unroll
    for (int s = 0; s < 2; ++s)
      acc[m][s] = (f32x4){0.f,0.f,0.f,0.f};

  uint4 ar[AC], wr[WC];

  #define LOADG(kt) { \
    _Pragma("unroll") \
    for (int i = 0; i < AC; ++i) { \
      int chunk = tid + i*256; \
      int rl = chunk >> 3, kc = chunk & 7; \
      ar[i] = *(const uint4*)&A[(size_t)(row0+rl)*K + (kt)*BK + kc*8]; \
    } \
    _Pragma("unroll") \
    for (int i = 0; i < WC; ++i) { \
      int chunk = tid + i*256; \
      int co = chunk >> 3, kc = chunk & 7; \
      wr[i] = *(const uint4*)&W[(size_t)(col0+co)*K + (kt)*BK + kc*8]; \
    } }

  #define STOREL(buf) { \
    _Pragma("unroll") \
    for (int i = 0; i < AC; ++i) { \
      int chunk = tid + i*256; \
      int rl = chunk >> 3, kc = chunk & 7; \
      *(uint4*)&Al[buf][rl*RS + kc*8] = ar[i]; \
    } \
    _Pragma("unroll") \
    for (int i = 0; i < WC; ++i) { \
      int chunk = tid + i*256; \
      int co = chunk >> 3, kc = chunk & 7; \
      *(uint4*)&Wl[buf][co*RS + kc*8] = wr[i]; \
    } }

  LOADG(0);
  STOREL(0);
  int cur = 0;
  for (int kt = 0; kt < NK; ++kt) {
    if (kt + 1 < NK) LOADG(kt + 1);
    __syncthreads();
    #pragma unroll
    for (int kf = 0; kf < 2; ++kf) {
      bf16x8 bfr[2];
      #pragma unroll
      for (int s = 0; s < 2; ++s)
        bfr[s] = *(bf16x8*)&Al[cur][(w*32 + s*16 + lm)*RS + kf*32 + lk*8];
      #pragma unroll
      for (int m = 0; m < NCF; ++m) {
        bf16x8 afr = *(bf16x8*)&Wl[cur][(m*16 + lm)*RS + kf*32 + lk*8];
        acc[m][0] = __builtin_amdgcn_mfma_f32_16x16x32_bf16(afr, bfr[0], acc[m][0], 0, 0, 0);
        acc[m][1] = __builtin_amdgcn_mfma_f32_16x16x32_bf16(afr, bfr[1], acc[m][1], 0, 0, 0);
      }
    }
    if (kt + 1 < NK) STOREL(cur ^ 1);
    cur ^= 1;
  }

  #pragma unroll
  for (int m = 0; m < NCF; ++m) {
    #pragma unroll
    for (int s = 0; s < 2; ++s) {
      int row = row0 + w*32 + s*16 + lm;
      f32x4 v = acc[m][s];
      #pragma unroll
      for (int j = 0; j < 4; ++j) {
        int u = col0 + m*16 + lk*4 + j;
        float val = LRELU(v[j] + bias[u]);
        C[((size_t)row << 12) + ((size_t)(u & 15) << 8) + (u >> 4)] = bfbits(val);
      }
    }
  }
  #undef LOADG
  #undef STOREL
}

// ---------------- dcv/dcvim weight prep: wave-coalesced slabs per (p, m), co = m*16+lm
template<int CI, int CO>
__global__ void k_wprep_im(const float* __restrict__ w, ushort* __restrict__ wpn){
  constexpr int K = 4*CI, KF = K/32, MMW2 = CO/16;
  int e = blockIdx.x*256 + threadIdx.x;
  if (e >= 16*CI*CO) return;
  int j  = e & 7;
  int lk = (e >> 3) & 3;
  int lm = (e >> 5) & 15;
  int r3 = e >> 9;
  int kf = r3 % KF; int r4 = r3 / KF;
  int m  = r4 % MMW2; int p = r4 / MMW2;
  int k  = kf*32 + lk*8 + j;
  int t  = k / CI, ci = k % CI;
  int co = m*16 + lm;
  int py = p >> 1, px = p & 1, dy = t >> 1, dx = t & 1;
  int ky = (py ? 0 : 1) + 2*dy;
  int kx = (px ? 0 : 1) + 2*dx;
  wpn[e] = bfbits(w[((ci*CO + co)*4 + ky)*4 + kx]);
}

// wfb[t][ci] bf16 for the final tap-dot MFMA (t = ky*4+kx)
__global__ void k_wfprep(const float* __restrict__ wf, ushort* __restrict__ wfb){
  int e = blockIdx.x*256 + threadIdx.x;
  if (e < 512) {
    int t = e >> 5, ci = e & 31;
    wfb[t*32 + ci] = bfbits(wf[ci*16 + t]);
  }
}

// ---------------- MFMA parity-GEMM deconv (stage 0): A in LDS dbuf, weights
// direct-from-global in slab layout; CO-split via blockIdx.z (coz half)
template<int CI, int CO, int HI>
__global__ __launch_bounds__(256) void k_dcv(
    const ushort* __restrict__ in, const ushort* __restrict__ wp,
    ushort* __restrict__ out, float* __restrict__ gsum, float* __restrict__ gsq)
{
  constexpr int WI = HI, HO = 2*HI, WO = 2*WI;
  constexpr int K = 4*CI, BK = 64, NK = K/BK, KFT = K/32;
  constexpr int BSP = 128;
  constexpr int RS = 72;
  constexpr int NCF = CO/32;       // per-block co-frags (half of CO/16)
  constexpr int COH = CO/2;
  constexpr int AC = BSP/32;

  __shared__ __align__(16) ushort Al[2][BSP*RS];
  __shared__ float s_sum[COH], s_sq[COH];

  const int tid = threadIdx.x;
  const int sp0 = blockIdx.x * BSP;
  const int p  = blockIdx.y;
  const int coz = blockIdx.z;
  const int py = p >> 1, px = p & 1;
  const int w  = tid >> 6, l = tid & 63;
  const int lm = l & 15, lk = l >> 4;

  if (tid < COH) { s_sum[tid] = 0.f; s_sq[tid] = 0.f; }

  f32x4 acc[NCF][2];
  #pragma unroll
  for (int m = 0; m < NCF; ++m)
    #pragma unroll
    for (int s = 0; s < 2; ++s)
      acc[m][s] = (f32x4){0.f,0.f,0.f,0.f};

  uint4 ar[AC];
  const ushort* wpb = wp + (size_t)(p*(CO/16) + coz*NCF)*KFT*512;

  #define LOADT(kt) { \
    int t = ((kt)*BK)/CI, ci0 = ((kt)*BK)%CI; \
    int dy = t >> 1, dx = t & 1; \
    _Pragma("unroll") \
    for (int i = 0; i < AC; ++i) { \
      int chunk = tid + i*256; \
      int rl = chunk >> 3, kc = chunk & 7; \
      int r = sp0 + rl; \
      int n = r / (HI*WI), rem = r % (HI*WI); \
      int oy = rem / WI, ox = rem % WI; \
      int iy = oy + py - dy, ix = ox + px - dx; \
      if ((unsigned)iy < (unsigned)HI && (unsigned)ix < (unsigned)WI) \
        ar[i] = *(const uint4*)&in[((((size_t)n*HI + iy)*WI + ix)*CI) + ci0 + kc*8]; \
      else ar[i] = make_uint4(0,0,0,0); \
    } }

  #define STORET(buf) { \
    _Pragma("unroll") \
    for (int i = 0; i < AC; ++i) { \
      int chunk = tid + i*256; \
      int rl = chunk >> 3, kc = chunk & 7; \
      *(uint4*)&Al[buf][rl*RS + kc*8] = ar[i]; \
    } }

  LOADT(0);
  STORET(0);
  int cur = 0;
  for (int kt = 0; kt < NK; ++kt) {
    if (kt + 1 < NK) LOADT(kt + 1);
    __syncthreads();
    #pragma unroll
    for (int kf = 0; kf < 2; ++kf) {
      const int ktg = kt*2 + kf;
      bf16x8 bfr[2];
      #pragma unroll
      for (int s = 0; s < 2; ++s)
        bfr[s] = *(bf16x8*)&Al[cur][(w*32 + s*16 + lm)*RS + kf*32 + lk*8];
      #pragma unroll
      for (int m = 0; m < NCF; ++m) {
        bf16x8 afr = *(const bf16x8*)&wpb[((size_t)m*KFT + ktg)*512 + lm*32 + lk*8];
        acc[m][0] = __builtin_amdgcn_mfma_f32_16x16x32_bf16(afr, bfr[0], acc[m][0], 0, 0, 0);
        acc[m][1] = __builtin_amdgcn_mfma_f32_16x16x32_bf16(afr, bfr[1], acc[m][1], 0, 0, 0);
      }
    }
    if (kt + 1 < NK) STORET(cur ^ 1);
    cur ^= 1;
  }

  // pass 1: batch stats only (this CO half)
  #pragma unroll
  for (int m = 0; m < NCF; ++m) {
    float s1[4] = {0,0,0,0}, s2[4] = {0,0,0,0};
    #pragma unroll
    for (int s = 0; s < 2; ++s) {
      f32x4 v = acc[m][s];
      #pragma unroll
      for (int j = 0; j < 4; ++j) { s1[j] += v[j]; s2[j] += v[j]*v[j]; }
    }
    #pragma unroll
    for (int j = 0; j < 4; ++j) {
      float a = s1[j], b = s2[j];
      #pragma unroll
      for (int o = 1; o < 16; o <<= 1) { a += __shfl_xor(a, o); b += __shfl_xor(b, o); }
      if (lm == 0) {
        atomicAdd(&s_sum[m*16 + lk*4 + j], a);
        atomicAdd(&s_sq [m*16 + lk*4 + j], b);
      }
    }
  }
  // pass 2: stores, s-outer / m-inner (contiguous 128B half-line per pixel)
  #pragma unroll
  for (int s = 0; s < 2; ++s) {
    int sp = sp0 + w*32 + s*16 + lm;
    int n = sp / (HI*WI), rem = sp % (HI*WI);
    int y = 2*(rem / WI) + py, x = 2*(rem % WI) + px;
    size_t ob = (((size_t)n*HO + y)*WO + x)*CO + coz*COH + lk*4;
    #pragma unroll
    for (int m = 0; m < NCF; ++m) {
      f32x4 v = acc[m][s];
      union { ushort u[4]; uint2 q; } pk;
      pk.u[0] = bfbits(v[0]); pk.u[1] = bfbits(v[1]);
      pk.u[2] = bfbits(v[2]); pk.u[3] = bfbits(v[3]);
      *(uint2*)&out[ob + m*16] = pk.q;
    }
  }
  __syncthreads();
  for (int cc = tid; cc < COH; cc += 256) {
    atomicAdd(&gsum[coz*COH + cc], s_sum[cc]);
    atomicAdd(&gsq[coz*COH + cc],  s_sq[cc]);
  }
  #undef LOADT
  #undef STORET
}

// ---------------- image-resident MFMA deconv (stages 1 & 2); weight fragments
// explicitly double-buffered in registers; __launch_bounds__(512,2) raises the
// VGPR cap to ~128 so the prefetch can actually hold registers
template<int CI, int CO, int HI>
__global__ __launch_bounds__(512, 2) void k_dcvim(
    const ushort* __restrict__ in, const ushort* __restrict__ wp,
    const float* __restrict__ gsumP, const float* __restrict__ gsqP,
    const float* __restrict__ gP, const float* __restrict__ beP, float invNP,
    ushort* __restrict__ out, float* __restrict__ gsum, float* __restrict__ gsq)
{
  constexpr int WI = HI, HO = 2*HI, WO = 2*WI;
  constexpr int K = 4*CI;
  constexpr int KF = K/32;
  constexpr int PAD = HI + 2;
  constexpr int CICH = CI/8;
  constexpr int MMW2 = CO/16;
  constexpr int SFTH = HI*WI/32;

  __shared__ __align__(16) ushort Ain[PAD*PAD*CI];
  __shared__ float s_sum[CO], s_sq[CO];
  __shared__ float s_scale[CI], s_shift[CI];

  const int tid = threadIdx.x;
  const int n = blockIdx.x;
  const int w = tid >> 6, l = tid & 63, lm = l & 15, lk = l >> 4;
  const int p = w >> 1, py = p >> 1, px = p & 1, ph = w & 1;

  if (tid < CO) { s_sum[tid] = 0.f; s_sq[tid] = 0.f; }
  if (tid >= 512-CI) {
    int c = tid - (512-CI);
    float m = gsumP[c]*invNP;
    float v = gsqP[c]*invNP - m*m;
    float sc = gP[c]*rsqrtf(v + 1e-5f);
    s_scale[c] = sc;
    s_shift[c] = beP[c] - m*sc;
  }
  __syncthreads();

  const ushort* inb = in + (size_t)n * HI * WI * CI;
  constexpr int NPCH = PAD*PAD*CICH;
  for (int e = tid; e < NPCH; e += 512) {
    int ci8 = e % CICH; int sp = e / CICH;
    int c = sp % PAD, r = sp / PAD;
    int chS = ci8 ^ (c & 7);
    if (r >= 1 && r <= HI && c >= 1 && c <= WI) {
      uint4 u = *(const uint4*)&inb[(((size_t)(r-1)*WI + (c-1))*CI) + ci8*8];
      int ci0 = ci8*8;
      float4 sc0 = *(const float4*)&s_scale[ci0];
      float4 sc1 = *(const float4*)&s_scale[ci0+4];
      float4 sh0 = *(const float4*)&s_shift[ci0];
      float4 sh1 = *(const float4*)&s_shift[ci0+4];
      float v0 = LRELU(fmaf(bflo(u.x), sc0.x, sh0.x));
      float v1 = LRELU(fmaf(bfhi(u.x), sc0.y, sh0.y));
      float v2 = LRELU(fmaf(bflo(u.y), sc0.z, sh0.z));
      float v3 = LRELU(fmaf(bfhi(u.y), sc0.w, sh0.w));
      float v4 = LRELU(fmaf(bflo(u.z), sc1.x, sh1.x));
      float v5 = LRELU(fmaf(bfhi(u.z), sc1.y, sh1.y));
      float v6 = LRELU(fmaf(bflo(u.w), sc1.z, sh1.z));
      float v7 = LRELU(fmaf(bfhi(u.w), sc1.w, sh1.w));
      uint4 o;
      o.x = (uint)bfpack(v0, v1);
      o.y = (uint)bfpack(v2, v3);
      o.z = (uint)bfpack(v4, v5);
      o.w = (uint)bfpack(v6, v7);
      ((uint4*)Ain)[(r*PAD + c)*CICH + chS] = o;
    } else {
      ((uint4*)Ain)[(r*PAD + c)*CICH + chS] = make_uint4(0,0,0,0);
    }
  }
  __syncthreads();

  f32x4 acc[MMW2][SFTH];
  #pragma unroll
  for (int m = 0; m < MMW2; ++m)
    #pragma unroll
    for (int sf = 0; sf < SFTH; ++sf)
      acc[m][sf] = (f32x4){0.f,0.f,0.f,0.f};

  const ushort* wpb = wp + (size_t)(p*MMW2)*KF*512;
  // prefetch kf=0 weight fragments
  bf16x8 afrN[MMW2];
  #pragma unroll
  for (int m = 0; m < MMW2; ++m)
    afrN[m] = *(const bf16x8*)&wpb[((size_t)m*KF)*512 + lm*32 + lk*8];
  #pragma unroll
  for (int kf = 0; kf < KF; ++kf) {
    const int t = (kf*32)/CI, cib = (kf*32)%CI;
    const int dy = t >> 1, dx = t & 1;
    bf16x8 afr[MMW2];
    #pragma unroll
    for (int m = 0; m < MMW2; ++m) afr[m] = afrN[m];
    if (kf + 1 < KF) {
      #pragma unroll
      for (int m = 0; m < MMW2; ++m)
        afrN[m] = *(const bf16x8*)&wpb[((size_t)m*KF + (kf+1))*512 + lm*32 + lk*8];
    }
    const int ch = (cib >> 3) + lk;
    #pragma unroll
    for (int sf = 0; sf < SFTH; ++sf) {
      int s = (ph*SFTH + sf)*16 + lm;
      int y = s / WI, x = s % WI;
      int r = y + py - dy + 1, c = x + px - dx + 1;
      bf16x8 bfr = *(const bf16x8*)&Ain[((r*PAD + c)*CICH + (ch ^ (c & 7)))*8];
      #pragma unroll
      for (int m = 0; m < MMW2; ++m)
        acc[m][sf] = __builtin_amdgcn_mfma_f32_16x16x32_bf16(afr[m], bfr, acc[m][sf], 0, 0, 0);
    }
  }

  float s1[MMW2][4], s2[MMW2][4];
  #pragma unroll
  for (int m = 0; m < MMW2; ++m)
    #pragma unroll
    for (int j = 0; j < 4; ++j) { s1[m][j] = 0.f; s2[m][j] = 0.f; }

  #pragma unroll
  for (int sf = 0; sf < SFTH; ++sf) {
    int s = (ph*SFTH + sf)*16 + lm;
    int y = 2*(s / WI) + py, x = 2*(s % WI) + px;
    size_t ob = (((size_t)n*HO + y)*WO + x)*CO + lk*4;
    #pragma unroll
    for (int m = 0; m < MMW2; ++m) {
      f32x4 v = acc[m][sf];
      union { ushort u[4]; uint2 q; } pk;
      #pragma unroll
      for (int j = 0; j < 4; ++j) {
        pk.u[j] = bfbits(v[j]);
        s1[m][j] += v[j];
        s2[m][j] += v[j]*v[j];
      }
      *(uint2*)&out[ob + m*16] = pk.q;
    }
  }

  #pragma unroll
  for (int m = 0; m < MMW2; ++m) {
    #pragma unroll
    for (int j = 0; j < 4; ++j) {
      float a = s1[m][j], b = s2[m][j];
      #pragma unroll
      for (int o = 1; o < 16; o <<= 1) { a += __shfl_xor(a, o); b += __shfl_xor(b, o); }
      if (lm == 0) {
        atomicAdd(&s_sum[m*16 + lk*4 + j], a);
        atomicAdd(&s_sq [m*16 + lk*4 + j], b);
      }
    }
  }

  __syncthreads();
  for (int cc = tid; cc < CO; cc += 512) {
    atomicAdd(&gsum[cc], s_sum[cc]);
    atomicAdd(&gsq[cc],  s_sq[cc]);
  }
}

// ---------------- final deconv 32->1 + sigmoid via tap-dot MFMA
__global__ __launch_bounds__(256) void k_final(
    const ushort* __restrict__ in, const ushort* __restrict__ wfb,
    const float* __restrict__ gsumP, const float* __restrict__ gsqP,
    const float* __restrict__ gP, const float* __restrict__ beP, float invNP,
    const float* __restrict__ bfb, float* __restrict__ outp)
{
  constexpr int CI=32, HI=32, WI=32, HO=64, WO=64, SPLIT=4, HOq=HO/SPLIT;
  constexpr int RMAX = 10;
  constexpr int DP = 20;
  __shared__ float Dl[RMAX*32*DP];
  __shared__ float s_scale[CI], s_shift[CI];

  const int tid = threadIdx.x, bid = blockIdx.x;
  const int n = bid % 1280, q = bid / 1280;
  const int y0 = q * HOq;
  const int rows_lo = max(0, y0/2 - 1);
  const int rows_hi = min(HI-1, (y0 + HOq)/2);
  const int nrows = rows_hi - rows_lo + 1;

  if (tid < CI) {
    float m = gsumP[tid]*invNP;
    float v = gsqP[tid]*invNP - m*m;
    float sc = gP[tid]*rsqrtf(v + 1e-5f);
    s_scale[tid] = sc;
    s_shift[tid] = beP[tid] - m*sc;
  }
  __syncthreads();

  const int w = tid >> 6, l = tid & 63, lm = l & 15, lk = l >> 4;
  const bf16x8 afr = *(const bf16x8*)&wfb[lm*32 + lk*8];
  const float4 sc0 = *(const float4*)&s_scale[lk*8];
  const float4 sc1 = *(const float4*)&s_scale[lk*8+4];
  const float4 sh0 = *(const float4*)&s_shift[lk*8];
  const float4 sh1 = *(const float4*)&s_shift[lk*8+4];

  const ushort* inb = in + (size_t)n * HI * WI * CI;
  const int ngrp = nrows * 2;
  for (int g = w; g < ngrp; g += 4) {
    int px = g*16 + lm;
    int rl = px >> 5, ix = px & 31;
    uint4 u = *(const uint4*)&inb[(((size_t)(rows_lo+rl)*WI + ix)*CI) + lk*8];
    float v0 = LRELU(fmaf(bflo(u.x), sc0.x, sh0.x));
    float v1 = LRELU(fmaf(bfhi(u.x), sc0.y, sh0.y));
    float v2 = LRELU(fmaf(bflo(u.y), sc0.z, sh0.z));
    float v3 = LRELU(fmaf(bfhi(u.y), sc0.w, sh0.w));
    float v4 = LRELU(fmaf(bflo(u.z), sc1.x, sh1.x));
    float v5 = LRELU(fmaf(bfhi(u.z), sc1.y, sh1.y));
    float v6 = LRELU(fmaf(bflo(u.w), sc1.z, sh1.z));
    float v7 = LRELU(fmaf(bfhi(u.w), sc1.w, sh1.w));
    union { uint uu[4]; bf16x8 v; } pk;
    pk.uu[0] = bfpack(v0, v1);
    pk.uu[1] = bfpack(v2, v3);
    pk.uu[2] = bfpack(v4, v5);
    pk.uu[3] = bfpack(v6, v7);
    f32x4 d = __builtin_amdgcn_mfma_f32_16x16x32_bf16(afr, pk.v, (f32x4){0.f,0.f,0.f,0.f}, 0, 0, 0);
    *(f32x4*)&Dl[px*DP + lk*4] = d;
  }
  __syncthreads();

  const float b0 = bfb[0];
  #pragma unroll
  for (int i = 0; i < (HOq*WO)/256; ++i) {
    int e = tid + i*256;
    int oy = e >> 6, x = e & 63;
    int y = y0 + oy;
    int kya = (y + 1) & 1, iya = (y + 1) >> 1;
    int kxa = (x + 1) & 1, ixa = (x + 1) >> 1;
    float acc = b0;
    #pragma unroll
    for (int dy = 0; dy < 2; ++dy) {
      int iy = iya - dy, ky = kya + 2*dy;
      if (iy < 0 || iy >= HI) continue;
      #pragma unroll
      for (int dx = 0; dx < 2; ++dx) {
        int ix = ixa - dx, kx = kxa + 2*dx;
        if (ix < 0 || ix >= WI) continue;
        acc += Dl[((iy - rows_lo)*WI + ix)*DP + (ky*4 + kx)];
      }
    }
    outp[(size_t)n*HO*WO + y*WO + x] = 1.f/(1.f + __expf(-acc));
  }
}

extern "C" void kernel_launch(void* const* d_in, const int* in_sizes, int n_in,
                              void* d_out, int out_size, void* d_ws, size_t ws_size,
                              hipStream_t stream) {
  const float* z_content = (const float*)d_in[0];
  const float* z_motion  = (const float*)d_in[1];
  const float* W_h  = (const float*)d_in[2];
  const float* b_h  = (const float*)d_in[3];
  const float* W_c  = (const float*)d_in[4];
  const float* b_c  = (const float*)d_in[5];
  const float* W_ih = (const float*)d_in[6];
  const float* W_hh = (const float*)d_in[7];
  const float* b_ih = (const float*)d_in[8];
  const float* b_hh = (const float*)d_in[9];
  const float* W_f  = (const float*)d_in[10];
  const float* b_f  = (const float*)d_in[11];
  const float* init_in = (const float*)d_in[12];
  const float* fc_W = (const float*)d_in[13];
  const float* fc_b = (const float*)d_in[14];
  const float* w0 = (const float*)d_in[15];
  const float* g0 = (const float*)d_in[16];
  const float* be0 = (const float*)d_in[17];
  const float* w1 = (const float*)d_in[18];
  const float* g1 = (const float*)d_in[19];
  const float* be1 = (const float*)d_in[20];
  const float* w2 = (const float*)d_in[21];
  const float* g2 = (const float*)d_in[22];
  const float* be2 = (const float*)d_in[23];
  const float* wf = (const float*)d_in[24];
  const float* bf_ = (const float*)d_in[25];

  const size_t P_BYTES = 10631168;
  const size_t X_OFF   = P_BYTES;
  const size_t X_BYTES = 83886080;
  const size_t Y_OFF   = X_OFF + X_BYTES;
  const size_t NEED    = Y_OFF + 41943040;
  if (ws_size < NEED) return;

  float* ws = (float*)d_ws;
  char*  wsb = (char*)d_ws;
  float* sum0 = ws + 0;        float* sq0 = ws + 128;
  float* sum1 = ws + 256;      float* sq1 = ws + 320;
  float* sum2 = ws + 384;      float* sq2 = ws + 416;
  float4* xg4   = (float4*)(ws + 1024);
  float4* bias4 = (float4*)(ws + 2048);
  float* h    = ws + 3072;
  float* c    = ws + 19456;
  ushort* outsb = (ushort*)(ws + 35840);
  float* WhT  = ws + 199680;
  float* WcT  = ws + 265216;
  uint4* Whq8 = (uint4*)(ws + 330752);
  uint4* Wsq8 = (uint4*)(ws + 592896);
  ushort* wp0 = (ushort*)(ws + 855040);
  ushort* wp1 = (ushort*)(ws + 1117184);
  ushort* wp2 = (ushort*)(ws + 1182720);
  ushort* wfb = (ushort*)(ws + 1199104);
  ushort* wpff = (ushort*)(ws + 1199616);
  ushort* featb = (ushort*)(ws + 1265152);

  ushort* wpfc = (ushort*)(wsb + X_OFF);
  ushort* out0 = (ushort*)(wsb + X_OFF);
  ushort* out2 = (ushort*)(wsb + X_OFF);
  ushort* h1   = (ushort*)(wsb + Y_OFF);
  ushort* out1 = (ushort*)(wsb + Y_OFF);

  dim3 tb(32,8);
  k_transpose<<<dim3(8,8),   tb, 0, stream>>>(W_h,  WhT, 256, 256);
  k_transpose<<<dim3(8,8),   tb, 0, stream>>>(W_c,  WcT, 256, 256);
  k_tobf16<<<10240, 256, 0, stream>>>(fc_W, wpfc, 2621440);
  k_tobf16<<<512, 256, 0, stream>>>(W_f, wpff, 131072);
  k_w4prep<<<64, 256, 0, stream>>>(W_ih, W_hh, Whq8, Wsq8, ws);
  k_xgbias<<<256, 256, 0, stream>>>(W_ih, b_ih, b_hh, init_in, xg4, bias4);
  k_h0c0<<<64, 256, 0, stream>>>(z_content, z_motion, WhT, WcT, b_h, b_c, h, c);
  k_wprep_im<256,128><<<2048, 256, 0, stream>>>(w0, wp0);
  k_wprep_im<128,64><<<512, 256, 0, stream>>>(w1, wp1);
  k_wprep_im<64,32><<<128, 256, 0, stream>>>(w2, wp2);
  k_wfprep<<<2, 256, 0, stream>>>(wf, wfb);

  // ---- whole LSTM in one launch (fp8 weights)
  k_lstm_all<<<64, 1024, 0, stream>>>(Whq8, Wsq8, xg4, bias4, h, c, outsb);

  // ---- ff (MFMA) + concat + fc (MFMA)
  k_ff_m<<<dim3(8, 10), 256, 0, stream>>>(outsb, wpff, b_f, featb);
  k_zc<<<640, 256, 0, stream>>>(z_content, featb);
  k_gemm_fc_m<<<dim3(64, 10), 256, 0, stream>>>(featb, wpfc, fc_b, h1);

  // ---- deconv pipeline (stage0 CO-split; dcvim reg-dbuf + (512,2) bounds)
  k_dcv<256,128,4><<<dim3(160,4,2), 256, 0, stream>>>(h1, wp0, out0, sum0, sq0);
  k_dcvim<128,64,8><<<1280, 512, 0, stream>>>(out0, wp1, sum0, sq0, g0, be0, 1.f/81920.f, out1, sum1, sq1);
  k_dcvim<64,32,16><<<1280, 512, 0, stream>>>(out1, wp2, sum1, sq1, g1, be1, 1.f/327680.f, out2, sum2, sq2);
  k_final<<<5120, 256, 0, stream>>>(out2, wfb, sum2, sq2, g2, be2, 1.f/1310720.f, bf_, (float*)d_out);
}

// Round 26
// 435.822 us; speedup vs baseline: 1.1148x; 1.0210x over previous
//
#include <hip/hip_runtime.h>
#include <hip/hip_bf16.h>
#include <math.h>

typedef __hip_bfloat16 bf16;
typedef __attribute__((ext_vector_type(8))) short bf16x8;
typedef __attribute__((ext_vector_type(4))) float f32x4;
typedef __attribute__((ext_vector_type(2))) float f32x2;

#define LRELU(v) ((v) > 0.f ? (v) : 0.2f*(v))

__device__ __forceinline__ float sig_f(float x){ return 1.f/(1.f + __expf(-x)); }
__device__ __forceinline__ float tanh_f(float x){
  float ax = fabsf(x);
  float e = __expf(-2.f*ax);
  float t = (1.f - e)/(1.f + e);
  return x >= 0.f ? t : -t;
}
__device__ __forceinline__ ushort bfbits(float v){
  bf16 b = __float2bfloat16(v);
  return *(ushort*)&b;
}
__device__ __forceinline__ uint bfpack(float a, float b){
  return (uint)bfbits(a) | ((uint)bfbits(b) << 16);
}
__device__ __forceinline__ float bflo(uint u){ return __uint_as_float(u << 16); }
__device__ __forceinline__ float bfhi(uint u){ return __uint_as_float(u & 0xffff0000u); }

// wprep body (shared by the three deconv weight packs)
template<int CI, int CO>
__device__ __forceinline__ void wprep_body(const float* __restrict__ w,
                                           ushort* __restrict__ wpn, int e){
  constexpr int K = 4*CI, KF = K/32, MMW2 = CO/16;
  if (e >= 16*CI*CO) return;
  int j  = e & 7;
  int lk = (e >> 3) & 3;
  int lm = (e >> 5) & 15;
  int r3 = e >> 9;
  int kf = r3 % KF; int r4 = r3 / KF;
  int m  = r4 % MMW2; int p = r4 / MMW2;
  int k  = kf*32 + lk*8 + j;
  int t  = k / CI, ci = k % CI;
  int co = m*16 + lm;
  int py = p >> 1, px = p & 1, dy = t >> 1, dx = t & 1;
  int ky = (py ? 0 : 1) + 2*dy;
  int kx = (px ? 0 : 1) + 2*dx;
  wpn[e] = bfbits(w[((ci*CO + co)*4 + ky)*4 + kx]);
}

// ---------------- fused prep: all independent preprocessing in ONE launch.
// blockIdx.x ranges: [0,128) transposes | [128,10368) fc_W cast |
// [10368,10880) W_f cast | [10880,10944) lstm fp8 pack | [10944,11200) xgbias |
// [11200,13248) wp0 | [13248,13760) wp1 | [13760,13888) wp2 | [13888,13890) wfb
__global__ __launch_bounds__(256) void k_prep(
    const float* __restrict__ W_h, const float* __restrict__ W_c,
    float* __restrict__ WhT, float* __restrict__ WcT,
    const float* __restrict__ fc_W, ushort* __restrict__ wpfc,
    const float* __restrict__ W_f, ushort* __restrict__ wpff,
    const float* __restrict__ Wih, const float* __restrict__ Whh,
    uint4* __restrict__ Whq8, uint4* __restrict__ Wsq8, float* __restrict__ stats,
    const float* __restrict__ b_ih, const float* __restrict__ b_hh,
    const float* __restrict__ init_in,
    float4* __restrict__ xg4, float4* __restrict__ bias4,
    const float* __restrict__ w0, ushort* __restrict__ wp0,
    const float* __restrict__ w1, ushort* __restrict__ wp1,
    const float* __restrict__ w2, ushort* __restrict__ wp2,
    const float* __restrict__ wf, ushort* __restrict__ wfb)
{
  __shared__ float t[32][33];
  __shared__ float4 red[4];
  const int b = blockIdx.x, tid = threadIdx.x;

  if (b < 128) {
    // two 256x256 transposes
    const float* src = (b < 64) ? W_h : W_c;
    float* dst = (b < 64) ? WhT : WcT;
    int bb = b & 63;
    int c0 = (bb & 7)*32, r0 = (bb >> 3)*32;
    int tx = tid & 31, ty = tid >> 5;
    #pragma unroll
    for (int i = 0; i < 4; ++i)
      t[ty+8*i][tx] = src[(size_t)(r0+ty+8*i)*256 + c0+tx];
    __syncthreads();
    #pragma unroll
    for (int i = 0; i < 4; ++i)
      dst[(size_t)(c0+ty+8*i)*256 + r0+tx] = t[tx][ty+8*i];
    return;
  }
  if (b < 10368) {               // fc_W -> bf16
    int i = (b - 128)*256 + tid;
    if (i < 2621440) wpfc[i] = bfbits(fc_W[i]);
    return;
  }
  if (b < 10880) {               // W_f -> bf16
    int i = (b - 10368)*256 + tid;
    if (i < 131072) wpff[i] = bfbits(W_f[i]);
    return;
  }
  if (b < 10944) {               // lstm fp8 weight pack + stats zero
    int k4 = b - 10880, j = tid;
    if (k4 < 2) { int i = k4*256 + j; if (i < 448) stats[i] = 0.f; }
    uint h4[4], s4[4];
    #pragma unroll
    for (int d = 0; d < 4; ++d) {
      int k = 4*k4 + d;
      float hi = Whh[j*256+k],       hf = Whh[(256+j)*256+k];
      float hg = Whh[(512+j)*256+k], ho = Whh[(768+j)*256+k];
      float ii = Wih[j*256+k],       iff = Wih[(256+j)*256+k];
      float ig = Wih[(512+j)*256+k], io = Wih[(768+j)*256+k];
      int lo = __builtin_amdgcn_cvt_pk_fp8_f32(hi, hf, 0, false);
      h4[d] = (uint)__builtin_amdgcn_cvt_pk_fp8_f32(hg, ho, lo, true);
      lo = __builtin_amdgcn_cvt_pk_fp8_f32(hi+ii, hf+iff, 0, false);
      s4[d] = (uint)__builtin_amdgcn_cvt_pk_fp8_f32(hg+ig, ho+io, lo, true);
    }
    Whq8[k4*256+j] = make_uint4(h4[0], h4[1], h4[2], h4[3]);
    Wsq8[k4*256+j] = make_uint4(s4[0], s4[1], s4[2], s4[3]);
    return;
  }
  if (b < 11200) {               // xgbias
    int bb = b - 10944, tt = tid;
    float v = init_in[tt];
    float p0 = v * Wih[bb*256 + tt];
    float p1 = v * Wih[(256+bb)*256 + tt];
    float p2 = v * Wih[(512+bb)*256 + tt];
    float p3 = v * Wih[(768+bb)*256 + tt];
    #pragma unroll
    for (int o = 32; o; o >>= 1) {
      p0 += __shfl_xor(p0, o); p1 += __shfl_xor(p1, o);
      p2 += __shfl_xor(p2, o); p3 += __shfl_xor(p3, o);
    }
    int lane = tt & 63, wid = tt >> 6;
    if (lane == 0) red[wid] = make_float4(p0,p1,p2,p3);
    __syncthreads();
    if (tt == 0) {
      float4 bi = make_float4(b_ih[bb]+b_hh[bb], b_ih[256+bb]+b_hh[256+bb],
                              b_ih[512+bb]+b_hh[512+bb], b_ih[768+bb]+b_hh[768+bb]);
      bias4[bb] = bi;
      float4 a = bi;
      #pragma unroll
      for (int w = 0; w < 4; ++w) { a.x += red[w].x; a.y += red[w].y; a.z += red[w].z; a.w += red[w].w; }
      xg4[bb] = a;
    }
    return;
  }
  if (b < 13248) { wprep_body<256,128>(w0, wp0, (b - 11200)*256 + tid); return; }
  if (b < 13760) { wprep_body<128,64>(w1, wp1, (b - 13248)*256 + tid); return; }
  if (b < 13888) { wprep_body<64,32>(w2, wp2, (b - 13760)*256 + tid); return; }
  {                              // wfprep
    int e = (b - 13888)*256 + tid;
    if (e < 512) {
      int tt = e >> 5, ci = e & 31;
      wfb[tt*32 + ci] = bfbits(wf[ci*16 + tt]);
    }
  }
}

__global__ __launch_bounds__(256) void k_h0c0(const float* __restrict__ zc, const float* __restrict__ zm,
                      const float* __restrict__ WhT, const float* __restrict__ WcT,
                      const float* __restrict__ b_h, const float* __restrict__ b_c,
                      float* __restrict__ h, float* __restrict__ c){
  __shared__ float zs[256];
  int b = blockIdx.x, j = threadIdx.x;
  zs[j] = (j < 128) ? zc[b*128 + j] : zm[b*128 + (j-128)];
  __syncthreads();
  float ah = b_h[j], ac = b_c[j];
  #pragma unroll 4
  for (int k = 0; k < 256; ++k) {
    float zv = zs[k];
    ah = fmaf(zv, WhT[k*256 + j], ah);
    ac = fmaf(zv, WcT[k*256 + j], ac);
  }
  h[b*256+j] = ah; c[b*256+j] = ac;
}

// ---------------- entire 20-step LSTM; fp8 uint4 weight loads
__global__ __launch_bounds__(1024) void k_lstm_all(
    const uint4* __restrict__ Whq8, const uint4* __restrict__ Wsq8,
    const float4* __restrict__ xg4, const float4* __restrict__ bias4,
    const float* __restrict__ h0, const float* __restrict__ c0,
    ushort* __restrict__ outsb){
  __shared__ float hs[256];
  __shared__ float4 part[3][256];
  const int b = blockIdx.x, tid = threadIdx.x;
  const int j = tid & 255, kq = tid >> 8;
  float cj = 0.f;
  if (kq == 0) { hs[j] = h0[b*256 + j]; cj = c0[b*256 + j]; }
  __syncthreads();
  for (int t = 0; t < 20; ++t) {
    const uint4* __restrict__ Wp = ((t == 0) ? Whq8 : Wsq8) + (size_t)(kq*16)*256 + j;
    float4 a = make_float4(0.f, 0.f, 0.f, 0.f);
    #pragma unroll 8
    for (int kk = 0; kk < 16; ++kk) {
      uint4 wv = Wp[(size_t)kk*256];
      const float* __restrict__ hb = &hs[kq*64 + 4*kk];
      {
        f32x2 pif = __builtin_amdgcn_cvt_pk_f32_fp8((int)wv.x, false);
        f32x2 pgo = __builtin_amdgcn_cvt_pk_f32_fp8((int)wv.x, true);
        float hv = hb[0];
        a.x = fmaf(hv, pif[0], a.x); a.y = fmaf(hv, pif[1], a.y);
        a.z = fmaf(hv, pgo[0], a.z); a.w = fmaf(hv, pgo[1], a.w);
      }
      {
        f32x2 pif = __builtin_amdgcn_cvt_pk_f32_fp8((int)wv.y, false);
        f32x2 pgo = __builtin_amdgcn_cvt_pk_f32_fp8((int)wv.y, true);
        float hv = hb[1];
        a.x = fmaf(hv, pif[0], a.x); a.y = fmaf(hv, pif[1], a.y);
        a.z = fmaf(hv, pgo[0], a.z); a.w = fmaf(hv, pgo[1], a.w);
      }
      {
        f32x2 pif = __builtin_amdgcn_cvt_pk_f32_fp8((int)wv.z, false);
        f32x2 pgo = __builtin_amdgcn_cvt_pk_f32_fp8((int)wv.z, true);
        float hv = hb[2];
        a.x = fmaf(hv, pif[0], a.x); a.y = fmaf(hv, pif[1], a.y);
        a.z = fmaf(hv, pgo[0], a.z); a.w = fmaf(hv, pgo[1], a.w);
      }
      {
        f32x2 pif = __builtin_amdgcn_cvt_pk_f32_fp8((int)wv.w, false);
        f32x2 pgo = __builtin_amdgcn_cvt_pk_f32_fp8((int)wv.w, true);
        float hv = hb[3];
        a.x = fmaf(hv, pif[0], a.x); a.y = fmaf(hv, pif[1], a.y);
        a.z = fmaf(hv, pgo[0], a.z); a.w = fmaf(hv, pgo[1], a.w);
      }
    }
    if (kq) part[kq-1][j] = a;
    __syncthreads();
    if (kq == 0) {
      float4 p1 = part[0][j], p2 = part[1][j], p3 = part[2][j];
      float4 bb = (t == 0) ? xg4[j] : bias4[j];
      a.x += p1.x + p2.x + p3.x + bb.x;
      a.y += p1.y + p2.y + p3.y + bb.y;
      a.z += p1.z + p2.z + p3.z + bb.z;
      a.w += p1.w + p2.w + p3.w + bb.w;
      float ig = sig_f(a.x), fg = sig_f(a.y), gg = tanh_f(a.z), og = sig_f(a.w);
      cj = fmaf(fg, cj, ig*gg);
      float hj = og * tanh_f(cj);
      outsb[(b*20 + t)*256 + j] = bfbits(hj);
      hs[j] = hj;
    }
    __syncthreads();
  }
}

// ---------------- MFMA ff GEMM (+ fused zc concat)
__global__ __launch_bounds__(256) void k_ff_m(
    const ushort* __restrict__ A, const ushort* __restrict__ W,
    const float* __restrict__ bias, const float* __restrict__ zc,
    ushort* __restrict__ C)
{
  constexpr int K = 256, BK = 64, NK = K/BK, BM = 128, BN = 64;
  constexpr int RS = 72;
  constexpr int NCF = BN/16;
  constexpr int AC = 4, WC = 2;

  __shared__ __align__(16) ushort Al[2][BM*RS];
  __shared__ __align__(16) ushort Wl[2][BN*RS];

  const int tid = threadIdx.x;
  const int col0 = blockIdx.x * BN, row0 = blockIdx.y * BM;
  const int w = tid >> 6, l = tid & 63, lm = l & 15, lk = l >> 4;

  f32x4 acc[NCF][2];
  #pragma unroll
  for (int m = 0; m < NCF; ++m)
    #pragma unroll
    for (int s = 0; s < 2; ++s)
      acc[m][s] = (f32x4){0.f,0.f,0.f,0.f};

  uint4 ar[AC], wr[WC];

  #define LOADG(kt) { \
    _Pragma("unroll") \
    for (int i = 0; i < AC; ++i) { \
      int chunk = tid + i*256; \
      int rl = chunk >> 3, kc = chunk & 7; \
      ar[i] = *(const uint4*)&A[(size_t)(row0+rl)*K + (kt)*BK + kc*8]; \
    } \
    _Pragma("unroll") \
    for (int i = 0; i < WC; ++i) { \
      int chunk = tid + i*256; \
      int co = chunk >> 3, kc = chunk & 7; \
      wr[i] = *(const uint4*)&W[(size_t)(col0+co)*K + (kt)*BK + kc*8]; \
    } }

  #define STOREL(buf) { \
    _Pragma("unroll") \
    for (int i = 0; i < AC; ++i) { \
      int chunk = tid + i*256; \
      int rl = chunk >> 3, kc = chunk & 7; \
      *(uint4*)&Al[buf][rl*RS + kc*8] = ar[i]; \
    } \
    _Pragma("unroll") \
    for (int i = 0; i < WC; ++i) { \
      int chunk = tid + i*256; \
      int co = chunk >> 3, kc = chunk & 7; \
      *(uint4*)&Wl[buf][co*RS + kc*8] = wr[i]; \
    } }

  LOADG(0);
  STOREL(0);
  int cur = 0;
  for (int kt = 0; kt < NK; ++kt) {
    if (kt + 1 < NK) LOADG(kt + 1);
    __syncthreads();
    #pragma unroll
    for (int kf = 0; kf < 2; ++kf) {
      bf16x8 bfr[2];
      #pragma unroll
      for (int s = 0; s < 2; ++s)
        bfr[s] = *(bf16x8*)&Al[cur][(w*32 + s*16 + lm)*RS + kf*32 + lk*8];
      #pragma unroll
      for (int m = 0; m < NCF; ++m) {
        bf16x8 afr = *(bf16x8*)&Wl[cur][(m*16 + lm)*RS + kf*32 + lk*8];
        acc[m][0] = __builtin_amdgcn_mfma_f32_16x16x32_bf16(afr, bfr[0], acc[m][0], 0, 0, 0);
        acc[m][1] = __builtin_amdgcn_mfma_f32_16x16x32_bf16(afr, bfr[1], acc[m][1], 0, 0, 0);
      }
    }
    if (kt + 1 < NK) STOREL(cur ^ 1);
    cur ^= 1;
  }

  #pragma unroll
  for (int m = 0; m < NCF; ++m) {
    #pragma unroll
    for (int s = 0; s < 2; ++s) {
      int row = row0 + w*32 + s*16 + lm;
      f32x4 v = acc[m][s];
      int u0 = col0 + m*16 + lk*4;
      union { ushort u[4]; uint2 q; } pk;
      #pragma unroll
      for (int j = 0; j < 4; ++j)
        pk.u[j] = bfbits(LRELU(v[j] + bias[u0+j]));
      *(uint2*)&C[(size_t)row*640 + u0] = pk.q;
    }
  }
  // fused zc concat: this block covers 2048 of the 163840 concat elems
  {
    int base = ((int)blockIdx.y*8 + (int)blockIdx.x)*2048 + tid;
    #pragma unroll
    for (int i = 0; i < 8; ++i) {
      int e = base + i*256;
      int r = e >> 7, c2 = e & 127;
      C[r*640 + 512 + c2] = bfbits(zc[(r/20)*128 + c2]);
    }
  }
  #undef LOADG
  #undef STOREL
}

// ---------------- MFMA FC GEMM: C[1280][4096] = lrelu(A@W^T + bias), NHWC bf16 out
__global__ __launch_bounds__(256) void k_gemm_fc_m(
    const ushort* __restrict__ A, const ushort* __restrict__ W,
    const float* __restrict__ bias, ushort* __restrict__ C)
{
  constexpr int K = 640, BK = 64, NK = K/BK, BM = 128, BN = 64;
  constexpr int RS = 72;
  constexpr int NCF = BN/16;
  constexpr int AC = 4, WC = 2;

  __shared__ __align__(16) ushort Al[2][BM*RS];
  __shared__ __align__(16) ushort Wl[2][BN*RS];

  const int tid = threadIdx.x;
  const int col0 = blockIdx.x * BN, row0 = blockIdx.y * BM;
  const int w = tid >> 6, l = tid & 63, lm = l & 15, lk = l >> 4;

  f32x4 acc[NCF][2];
  #pragma unroll
  for (int m = 0; m < NCF; ++m)
    #pragma unroll
    for (int s = 0; s < 2; ++s)
      acc[m][s] = (f32x4){0.f,0.f,0.f,0.f};

  uint4 ar[AC], wr[WC];

  #define LOADG(kt) { \
    _Pragma("unroll") \
    for (int i = 0; i < AC; ++i) { \
      int chunk = tid + i*256; \
      int rl = chunk >> 3, kc = chunk & 7; \
      ar[i] = *(const uint4*)&A[(size_t)(row0+rl)*K + (kt)*BK + kc*8]; \
    } \
    _Pragma("unroll") \
    for (int i = 0; i < WC; ++i) { \
      int chunk = tid + i*256; \
      int co = chunk >> 3, kc = chunk & 7; \
      wr[i] = *(const uint4*)&W[(size_t)(col0+co)*K + (kt)*BK + kc*8]; \
    } }

  #define STOREL(buf) { \
    _Pragma("unroll") \
    for (int i = 0; i < AC; ++i) { \
      int chunk = tid + i*256; \
      int rl = chunk >> 3, kc = chunk & 7; \
      *(uint4*)&Al[buf][rl*RS + kc*8] = ar[i]; \
    } \
    _Pragma("unroll") \
    for (int i = 0; i < WC; ++i) { \
      int chunk = tid + i*256; \
      int co = chunk >> 3, kc = chunk & 7; \
      *(uint4*)&Wl[buf][co*RS + kc*8] = wr[i]; \
    } }

  LOADG(0);
  STOREL(0);
  int cur = 0;
  for (int kt = 0; kt < NK; ++kt) {
    if (kt + 1 < NK) LOADG(kt + 1);
    __syncthreads();
    #pragma unroll
    for (int kf = 0; kf < 2; ++kf) {
      bf16x8 bfr[2];
      #pragma unroll
      for (int s = 0; s < 2; ++s)
        bfr[s] = *(bf16x8*)&Al[cur][(w*32 + s*16 + lm)*RS + kf*32 + lk*8];
      #pragma unroll
      for (int m = 0; m < NCF; ++m) {
        bf16x8 afr = *(bf16x8*)&Wl[cur][(m*16 + lm)*RS + kf*32 + lk*8];
        acc[m][0] = __builtin_amdgcn_mfma_f32_16x16x32_bf16(afr, bfr[0], acc[m][0], 0, 0, 0);
        acc[m][1] = __builtin_amdgcn_mfma_f32_16x16x32_bf16(afr, bfr[1], acc[m][1], 0, 0, 0);
      }
    }
    if (kt + 1 < NK) STOREL(cur ^ 1);
    cur ^= 1;
  }

  #pragma unroll
  for (int m = 0; m < NCF; ++m) {
    #pragma unroll
    for (int s = 0; s < 2; ++s) {
      int row = row0 + w*32 + s*16 + lm;
      f32x4 v = acc[m][s];
      #pragma unroll
      for (int j = 0; j < 4; ++j) {
        int u = col0 + m*16 + lk*4 + j;
        float val = LRELU(v[j] + bias[u]);
        C[((size_t)row << 12) + ((size_t)(u & 15) << 8) + (u >> 4)] = bfbits(val);
      }
    }
  }
  #undef LOADG
  #undef STOREL
}

// ---------------- MFMA parity-GEMM deconv (stage 0): A in LDS dbuf, weights
// direct-from-global in slab layout; CO-split via blockIdx.z (coz half)
template<int CI, int CO, int HI>
__global__ __launch_bounds__(256) void k_dcv(
    const ushort* __restrict__ in, const ushort* __restrict__ wp,
    ushort* __restrict__ out, float* __restrict__ gsum, float* __restrict__ gsq)
{
  constexpr int WI = HI, HO = 2*HI, WO = 2*WI;
  constexpr int K = 4*CI, BK = 64, NK = K/BK, KFT = K/32;
  constexpr int BSP = 128;
  constexpr int RS = 72;
  constexpr int NCF = CO/32;
  constexpr int COH = CO/2;
  constexpr int AC = BSP/32;

  __shared__ __align__(16) ushort Al[2][BSP*RS];
  __shared__ float s_sum[COH], s_sq[COH];

  const int tid = threadIdx.x;
  const int sp0 = blockIdx.x * BSP;
  const int p  = blockIdx.y;
  const int coz = blockIdx.z;
  const int py = p >> 1, px = p & 1;
  const int w  = tid >> 6, l = tid & 63;
  const int lm = l & 15, lk = l >> 4;

  if (tid < COH) { s_sum[tid] = 0.f; s_sq[tid] = 0.f; }

  f32x4 acc[NCF][2];
  #pragma unroll
  for (int m = 0; m < NCF; ++m)
    #pragma unroll
    for (int s = 0; s < 2; ++s)
      acc[m][s] = (f32x4){0.f,0.f,0.f,0.f};

  uint4 ar[AC];
  const ushort* wpb = wp + (size_t)(p*(CO/16) + coz*NCF)*KFT*512;

  #define LOADT(kt) { \
    int t = ((kt)*BK)/CI, ci0 = ((kt)*BK)%CI; \
    int dy = t >> 1, dx = t & 1; \
    _Pragma("unroll") \
    for (int i = 0; i < AC; ++i) { \
      int chunk = tid + i*256; \
      int rl = chunk >> 3, kc = chunk & 7; \
      int r = sp0 + rl; \
      int n = r / (HI*WI), rem = r % (HI*WI); \
      int oy = rem / WI, ox = rem % WI; \
      int iy = oy + py - dy, ix = ox + px - dx; \
      if ((unsigned)iy < (unsigned)HI && (unsigned)ix < (unsigned)WI) \
        ar[i] = *(const uint4*)&in[((((size_t)n*HI + iy)*WI + ix)*CI) + ci0 + kc*8]; \
      else ar[i] = make_uint4(0,0,0,0); \
    } }

  #define STORET(buf) { \
    _Pragma("unroll") \
    for (int i = 0; i < AC; ++i) { \
      int chunk = tid + i*256; \
      int rl = chunk >> 3, kc = chunk & 7; \
      *(uint4*)&Al[buf][rl*RS + kc*8] = ar[i]; \
    } }

  LOADT(0);
  STORET(0);
  int cur = 0;
  for (int kt = 0; kt < NK; ++kt) {
    if (kt + 1 < NK) LOADT(kt + 1);
    __syncthreads();
    #pragma unroll
    for (int kf = 0; kf < 2; ++kf) {
      const int ktg = kt*2 + kf;
      bf16x8 bfr[2];
      #pragma unroll
      for (int s = 0; s < 2; ++s)
        bfr[s] = *(bf16x8*)&Al[cur][(w*32 + s*16 + lm)*RS + kf*32 + lk*8];
      #pragma unroll
      for (int m = 0; m < NCF; ++m) {
        bf16x8 afr = *(const bf16x8*)&wpb[((size_t)m*KFT + ktg)*512 + lm*32 + lk*8];
        acc[m][0] = __builtin_amdgcn_mfma_f32_16x16x32_bf16(afr, bfr[0], acc[m][0], 0, 0, 0);
        acc[m][1] = __builtin_amdgcn_mfma_f32_16x16x32_bf16(afr, bfr[1], acc[m][1], 0, 0, 0);
      }
    }
    if (kt + 1 < NK) STORET(cur ^ 1);
    cur ^= 1;
  }

  // pass 1: batch stats only (this CO half)
  #pragma unroll
  for (int m = 0; m < NCF; ++m) {
    float s1[4] = {0,0,0,0}, s2[4] = {0,0,0,0};
    #pragma unroll
    for (int s = 0; s < 2; ++s) {
      f32x4 v = acc[m][s];
      #pragma unroll
      for (int j = 0; j < 4; ++j) { s1[j] += v[j]; s2[j] += v[j]*v[j]; }
    }
    #pragma unroll
    for (int j = 0; j < 4; ++j) {
      float a = s1[j], b = s2[j];
      #pragma unroll
      for (int o = 1; o < 16; o <<= 1) { a += __shfl_xor(a, o); b += __shfl_xor(b, o); }
      if (lm == 0) {
        atomicAdd(&s_sum[m*16 + lk*4 + j], a);
        atomicAdd(&s_sq [m*16 + lk*4 + j], b);
      }
    }
  }
  // pass 2: stores, s-outer / m-inner
  #pragma unroll
  for (int s = 0; s < 2; ++s) {
    int sp = sp0 + w*32 + s*16 + lm;
    int n = sp / (HI*WI), rem = sp % (HI*WI);
    int y = 2*(rem / WI) + py, x = 2*(rem % WI) + px;
    size_t ob = (((size_t)n*HO + y)*WO + x)*CO + coz*COH + lk*4;
    #pragma unroll
    for (int m = 0; m < NCF; ++m) {
      f32x4 v = acc[m][s];
      union { ushort u[4]; uint2 q; } pk;
      pk.u[0] = bfbits(v[0]); pk.u[1] = bfbits(v[1]);
      pk.u[2] = bfbits(v[2]); pk.u[3] = bfbits(v[3]);
      *(uint2*)&out[ob + m*16] = pk.q;
    }
  }
  __syncthreads();
  for (int cc = tid; cc < COH; cc += 256) {
    atomicAdd(&gsum[coz*COH + cc], s_sum[cc]);
    atomicAdd(&gsq[coz*COH + cc],  s_sq[cc]);
  }
  #undef LOADT
  #undef STORET
}

// ---------------- image-resident MFMA deconv (stages 1 & 2)
template<int CI, int CO, int HI>
__global__ __launch_bounds__(512, 2) void k_dcvim(
    const ushort* __restrict__ in, const ushort* __restrict__ wp,
    const float* __restrict__ gsumP, const float* __restrict__ gsqP,
    const float* __restrict__ gP, const float* __restrict__ beP, float invNP,
    ushort* __restrict__ out, float* __restrict__ gsum, float* __restrict__ gsq)
{
  constexpr int WI = HI, HO = 2*HI, WO = 2*WI;
  constexpr int K = 4*CI;
  constexpr int KF = K/32;
  constexpr int PAD = HI + 2;
  constexpr int CICH = CI/8;
  constexpr int MMW2 = CO/16;
  constexpr int SFTH = HI*WI/32;

  __shared__ __align__(16) ushort Ain[PAD*PAD*CI];
  __shared__ float s_sum[CO], s_sq[CO];
  __shared__ float s_scale[CI], s_shift[CI];

  const int tid = threadIdx.x;
  const int n = blockIdx.x;
  const int w = tid >> 6, l = tid & 63, lm = l & 15, lk = l >> 4;
  const int p = w >> 1, py = p >> 1, px = p & 1, ph = w & 1;

  if (tid < CO) { s_sum[tid] = 0.f; s_sq[tid] = 0.f; }
  if (tid >= 512-CI) {
    int c = tid - (512-CI);
    float m = gsumP[c]*invNP;
    float v = gsqP[c]*invNP - m*m;
    float sc = gP[c]*rsqrtf(v + 1e-5f);
    s_scale[c] = sc;
    s_shift[c] = beP[c] - m*sc;
  }
  __syncthreads();

  const ushort* inb = in + (size_t)n * HI * WI * CI;
  constexpr int NPCH = PAD*PAD*CICH;
  for (int e = tid; e < NPCH; e += 512) {
    int ci8 = e % CICH; int sp = e / CICH;
    int c = sp % PAD, r = sp / PAD;
    int chS = ci8 ^ (c & 7);
    if (r >= 1 && r <= HI && c >= 1 && c <= WI) {
      uint4 u = *(const uint4*)&inb[(((size_t)(r-1)*WI + (c-1))*CI) + ci8*8];
      int ci0 = ci8*8;
      float4 sc0 = *(const float4*)&s_scale[ci0];
      float4 sc1 = *(const float4*)&s_scale[ci0+4];
      float4 sh0 = *(const float4*)&s_shift[ci0];
      float4 sh1 = *(const float4*)&s_shift[ci0+4];
      float v0 = LRELU(fmaf(bflo(u.x), sc0.x, sh0.x));
      float v1 = LRELU(fmaf(bfhi(u.x), sc0.y, sh0.y));
      float v2 = LRELU(fmaf(bflo(u.y), sc0.z, sh0.z));
      float v3 = LRELU(fmaf(bfhi(u.y), sc0.w, sh0.w));
      float v4 = LRELU(fmaf(bflo(u.z), sc1.x, sh1.x));
      float v5 = LRELU(fmaf(bfhi(u.z), sc1.y, sh1.y));
      float v6 = LRELU(fmaf(bflo(u.w), sc1.z, sh1.z));
      float v7 = LRELU(fmaf(bfhi(u.w), sc1.w, sh1.w));
      uint4 o;
      o.x = (uint)bfpack(v0, v1);
      o.y = (uint)bfpack(v2, v3);
      o.z = (uint)bfpack(v4, v5);
      o.w = (uint)bfpack(v6, v7);
      ((uint4*)Ain)[(r*PAD + c)*CICH + chS] = o;
    } else {
      ((uint4*)Ain)[(r*PAD + c)*CICH + chS] = make_uint4(0,0,0,0);
    }
  }
  __syncthreads();

  f32x4 acc[MMW2][SFTH];
  #pragma unroll
  for (int m = 0; m < MMW2; ++m)
    #pragma unroll
    for (int sf = 0; sf < SFTH; ++sf)
      acc[m][sf] = (f32x4){0.f,0.f,0.f,0.f};

  const ushort* wpb = wp + (size_t)(p*MMW2)*KF*512;
  bf16x8 afrN[MMW2];
  #pragma unroll
  for (int m = 0; m < MMW2; ++m)
    afrN[m] = *(const bf16x8*)&wpb[((size_t)m*KF)*512 + lm*32 + lk*8];
  #pragma unroll
  for (int kf = 0; kf < KF; ++kf) {
    const int t = (kf*32)/CI, cib = (kf*32)%CI;
    const int dy = t >> 1, dx = t & 1;
    bf16x8 afr[MMW2];
    #pragma unroll
    for (int m = 0; m < MMW2; ++m) afr[m] = afrN[m];
    if (kf + 1 < KF) {
      #pragma unroll
      for (int m = 0; m < MMW2; ++m)
        afrN[m] = *(const bf16x8*)&wpb[((size_t)m*KF + (kf+1))*512 + lm*32 + lk*8];
    }
    const int ch = (cib >> 3) + lk;
    #pragma unroll
    for (int sf = 0; sf < SFTH; ++sf) {
      int s = (ph*SFTH + sf)*16 + lm;
      int y = s / WI, x = s % WI;
      int r = y + py - dy + 1, c = x + px - dx + 1;
      bf16x8 bfr = *(const bf16x8*)&Ain[((r*PAD + c)*CICH + (ch ^ (c & 7)))*8];
      #pragma unroll
      for (int m = 0; m < MMW2; ++m)
        acc[m][sf] = __builtin_amdgcn_mfma_f32_16x16x32_bf16(afr[m], bfr, acc[m][sf], 0, 0, 0);
    }
  }

  float s1[MMW2][4], s2[MMW2][4];
  #pragma unroll
  for (int m = 0; m < MMW2; ++m)
    #pragma unroll
    for (int j = 0; j < 4; ++j) { s1[m][j] = 0.f; s2[m][j] = 0.f; }

  #pragma unroll
  for (int sf = 0; sf < SFTH; ++sf) {
    int s = (ph*SFTH + sf)*16 + lm;
    int y = 2*(s / WI) + py, x = 2*(s % WI) + px;
    size_t ob = (((size_t)n*HO + y)*WO + x)*CO + lk*4;
    #pragma unroll
    for (int m = 0; m < MMW2; ++m) {
      f32x4 v = acc[m][sf];
      union { ushort u[4]; uint2 q; } pk;
      #pragma unroll
      for (int j = 0; j < 4; ++j) {
        pk.u[j] = bfbits(v[j]);
        s1[m][j] += v[j];
        s2[m][j] += v[j]*v[j];
      }
      *(uint2*)&out[ob + m*16] = pk.q;
    }
  }

  #pragma unroll
  for (int m = 0; m < MMW2; ++m) {
    #pragma unroll
    for (int j = 0; j < 4; ++j) {
      float a = s1[m][j], b = s2[m][j];
      #pragma unroll
      for (int o = 1; o < 16; o <<= 1) { a += __shfl_xor(a, o); b += __shfl_xor(b, o); }
      if (lm == 0) {
        atomicAdd(&s_sum[m*16 + lk*4 + j], a);
        atomicAdd(&s_sq [m*16 + lk*4 + j], b);
      }
    }
  }

  __syncthreads();
  for (int cc = tid; cc < CO; cc += 512) {
    atomicAdd(&gsum[cc], s_sum[cc]);
    atomicAdd(&gsq[cc],  s_sq[cc]);
  }
}

// ---------------- final deconv 32->1 + sigmoid via tap-dot MFMA
__global__ __launch_bounds__(256) void k_final(
    const ushort* __restrict__ in, const ushort* __restrict__ wfb,
    const float* __restrict__ gsumP, const float* __restrict__ gsqP,
    const float* __restrict__ gP, const float* __restrict__ beP, float invNP,
    const float* __restrict__ bfb, float* __restrict__ outp)
{
  constexpr int CI=32, HI=32, WI=32, HO=64, WO=64, SPLIT=4, HOq=HO/SPLIT;
  constexpr int RMAX = 10;
  constexpr int DP = 20;
  __shared__ float Dl[RMAX*32*DP];
  __shared__ float s_scale[CI], s_shift[CI];

  const int tid = threadIdx.x, bid = blockIdx.x;
  const int n = bid % 1280, q = bid / 1280;
  const int y0 = q * HOq;
  const int rows_lo = max(0, y0/2 - 1);
  const int rows_hi = min(HI-1, (y0 + HOq)/2);
  const int nrows = rows_hi - rows_lo + 1;

  if (tid < CI) {
    float m = gsumP[tid]*invNP;
    float v = gsqP[tid]*invNP - m*m;
    float sc = gP[tid]*rsqrtf(v + 1e-5f);
    s_scale[tid] = sc;
    s_shift[tid] = beP[tid] - m*sc;
  }
  __syncthreads();

  const int w = tid >> 6, l = tid & 63, lm = l & 15, lk = l >> 4;
  const bf16x8 afr = *(const bf16x8*)&wfb[lm*32 + lk*8];
  const float4 sc0 = *(const float4*)&s_scale[lk*8];
  const float4 sc1 = *(const float4*)&s_scale[lk*8+4];
  const float4 sh0 = *(const float4*)&s_shift[lk*8];
  const float4 sh1 = *(const float4*)&s_shift[lk*8+4];

  const ushort* inb = in + (size_t)n * HI * WI * CI;
  const int ngrp = nrows * 2;
  for (int g = w; g < ngrp; g += 4) {
    int px = g*16 + lm;
    int rl = px >> 5, ix = px & 31;
    uint4 u = *(const uint4*)&inb[(((size_t)(rows_lo+rl)*WI + ix)*CI) + lk*8];
    float v0 = LRELU(fmaf(bflo(u.x), sc0.x, sh0.x));
    float v1 = LRELU(fmaf(bfhi(u.x), sc0.y, sh0.y));
    float v2 = LRELU(fmaf(bflo(u.y), sc0.z, sh0.z));
    float v3 = LRELU(fmaf(bfhi(u.y), sc0.w, sh0.w));
    float v4 = LRELU(fmaf(bflo(u.z), sc1.x, sh1.x));
    float v5 = LRELU(fmaf(bfhi(u.z), sc1.y, sh1.y));
    float v6 = LRELU(fmaf(bflo(u.w), sc1.z, sh1.z));
    float v7 = LRELU(fmaf(bfhi(u.w), sc1.w, sh1.w));
    union { uint uu[4]; bf16x8 v; } pk;
    pk.uu[0] = bfpack(v0, v1);
    pk.uu[1] = bfpack(v2, v3);
    pk.uu[2] = bfpack(v4, v5);
    pk.uu[3] = bfpack(v6, v7);
    f32x4 d = __builtin_amdgcn_mfma_f32_16x16x32_bf16(afr, pk.v, (f32x4){0.f,0.f,0.f,0.f}, 0, 0, 0);
    *(f32x4*)&Dl[px*DP + lk*4] = d;
  }
  __syncthreads();

  const float b0 = bfb[0];
  #pragma unroll
  for (int i = 0; i < (HOq*WO)/256; ++i) {
    int e = tid + i*256;
    int oy = e >> 6, x = e & 63;
    int y = y0 + oy;
    int kya = (y + 1) & 1, iya = (y + 1) >> 1;
    int kxa = (x + 1) & 1, ixa = (x + 1) >> 1;
    float acc = b0;
    #pragma unroll
    for (int dy = 0; dy < 2; ++dy) {
      int iy = iya - dy, ky = kya + 2*dy;
      if (iy < 0 || iy >= HI) continue;
      #pragma unroll
      for (int dx = 0; dx < 2; ++dx) {
        int ix = ixa - dx, kx = kxa + 2*dx;
        if (ix < 0 || ix >= WI) continue;
        acc += Dl[((iy - rows_lo)*WI + ix)*DP + (ky*4 + kx)];
      }
    }
    outp[(size_t)n*HO*WO + y*WO + x] = 1.f/(1.f + __expf(-acc));
  }
}

extern "C" void kernel_launch(void* const* d_in, const int* in_sizes, int n_in,
                              void* d_out, int out_size, void* d_ws, size_t ws_size,
                              hipStream_t stream) {
  const float* z_content = (const float*)d_in[0];
  const float* z_motion  = (const float*)d_in[1];
  const float* W_h  = (const float*)d_in[2];
  const float* b_h  = (const float*)d_in[3];
  const float* W_c  = (const float*)d_in[4];
  const float* b_c  = (const float*)d_in[5];
  const float* W_ih = (const float*)d_in[6];
  const float* W_hh = (const float*)d_in[7];
  const float* b_ih = (const float*)d_in[8];
  const float* b_hh = (const float*)d_in[9];
  const float* W_f  = (const float*)d_in[10];
  const float* b_f  = (const float*)d_in[11];
  const float* init_in = (const float*)d_in[12];
  const float* fc_W = (const float*)d_in[13];
  const float* fc_b = (const float*)d_in[14];
  const float* w0 = (const float*)d_in[15];
  const float* g0 = (const float*)d_in[16];
  const float* be0 = (const float*)d_in[17];
  const float* w1 = (const float*)d_in[18];
  const float* g1 = (const float*)d_in[19];
  const float* be1 = (const float*)d_in[20];
  const float* w2 = (const float*)d_in[21];
  const float* g2 = (const float*)d_in[22];
  const float* be2 = (const float*)d_in[23];
  const float* wf = (const float*)d_in[24];
  const float* bf_ = (const float*)d_in[25];

  const size_t P_BYTES = 10631168;
  const size_t X_OFF   = P_BYTES;
  const size_t X_BYTES = 83886080;
  const size_t Y_OFF   = X_OFF + X_BYTES;
  const size_t NEED    = Y_OFF + 41943040;
  if (ws_size < NEED) return;

  float* ws = (float*)d_ws;
  char*  wsb = (char*)d_ws;
  float* sum0 = ws + 0;        float* sq0 = ws + 128;
  float* sum1 = ws + 256;      float* sq1 = ws + 320;
  float* sum2 = ws + 384;      float* sq2 = ws + 416;
  float4* xg4   = (float4*)(ws + 1024);
  float4* bias4 = (float4*)(ws + 2048);
  float* h    = ws + 3072;
  float* c    = ws + 19456;
  ushort* outsb = (ushort*)(ws + 35840);
  float* WhT  = ws + 199680;
  float* WcT  = ws + 265216;
  uint4* Whq8 = (uint4*)(ws + 330752);
  uint4* Wsq8 = (uint4*)(ws + 592896);
  ushort* wp0 = (ushort*)(ws + 855040);
  ushort* wp1 = (ushort*)(ws + 1117184);
  ushort* wp2 = (ushort*)(ws + 1182720);
  ushort* wfb = (ushort*)(ws + 1199104);
  ushort* wpff = (ushort*)(ws + 1199616);
  ushort* featb = (ushort*)(ws + 1265152);

  ushort* wpfc = (ushort*)(wsb + X_OFF);
  ushort* out0 = (ushort*)(wsb + X_OFF);
  ushort* out2 = (ushort*)(wsb + X_OFF);
  ushort* h1   = (ushort*)(wsb + Y_OFF);
  ushort* out1 = (ushort*)(wsb + Y_OFF);

  // ---- all independent prep in ONE launch
  k_prep<<<13890, 256, 0, stream>>>(
      W_h, W_c, WhT, WcT, fc_W, wpfc, W_f, wpff,
      W_ih, W_hh, Whq8, Wsq8, ws, b_ih, b_hh, init_in, xg4, bias4,
      w0, wp0, w1, wp1, w2, wp2, wf, wfb);
  k_h0c0<<<64, 256, 0, stream>>>(z_content, z_motion, WhT, WcT, b_h, b_c, h, c);

  // ---- whole LSTM in one launch (fp8 weights)
  k_lstm_all<<<64, 1024, 0, stream>>>(Whq8, Wsq8, xg4, bias4, h, c, outsb);

  // ---- ff (MFMA, + fused zc concat) + fc (MFMA)
  k_ff_m<<<dim3(8, 10), 256, 0, stream>>>(outsb, wpff, b_f, z_content, featb);
  k_gemm_fc_m<<<dim3(64, 10), 256, 0, stream>>>(featb, wpfc, fc_b, h1);

  // ---- deconv pipeline
  k_dcv<256,128,4><<<dim3(160,4,2), 256, 0, stream>>>(h1, wp0, out0, sum0, sq0);
  k_dcvim<128,64,8><<<1280, 512, 0, stream>>>(out0, wp1, sum0, sq0, g0, be0, 1.f/81920.f, out1, sum1, sq1);
  k_dcvim<64,32,16><<<1280, 512, 0, stream>>>(out1, wp2, sum1, sq1, g1, be1, 1.f/327680.f, out2, sum2, sq2);
  k_final<<<5120, 256, 0, stream>>>(out2, wfb, sum2, sq2, g2, be2, 1.f/1310720.f, bf_, (float*)d_out);
}

// Round 27
// 402.183 us; speedup vs baseline: 1.2080x; 1.0836x over previous
//
#include <hip/hip_runtime.h>
#include <hip/hip_bf16.h>
#include <math.h>

typedef __hip_bfloat16 bf16;
typedef __attribute__((ext_vector_type(8))) short bf16x8;
typedef __attribute__((ext_vector_type(4))) float f32x4;
typedef __attribute__((ext_vector_type(2))) float f32x2;

#define LRELU(v) ((v) > 0.f ? (v) : 0.2f*(v))

__device__ __forceinline__ float sig_f(float x){ return 1.f/(1.f + __expf(-x)); }
__device__ __forceinline__ float tanh_f(float x){
  float ax = fabsf(x);
  float e = __expf(-2.f*ax);
  float t = (1.f - e)/(1.f + e);
  return x >= 0.f ? t : -t;
}
__device__ __forceinline__ ushort bfbits(float v){
  bf16 b = __float2bfloat16(v);
  return *(ushort*)&b;
}
__device__ __forceinline__ uint bfpack(float a, float b){
  return (uint)bfbits(a) | ((uint)bfbits(b) << 16);
}
__device__ __forceinline__ float bflo(uint u){ return __uint_as_float(u << 16); }
__device__ __forceinline__ float bfhi(uint u){ return __uint_as_float(u & 0xffff0000u); }

// wprep body (shared by the three deconv weight packs)
template<int CI, int CO>
__device__ __forceinline__ void wprep_body(const float* __restrict__ w,
                                           ushort* __restrict__ wpn, int e){
  constexpr int K = 4*CI, KF = K/32, MMW2 = CO/16;
  if (e >= 16*CI*CO) return;
  int j  = e & 7;
  int lk = (e >> 3) & 3;
  int lm = (e >> 5) & 15;
  int r3 = e >> 9;
  int kf = r3 % KF; int r4 = r3 / KF;
  int m  = r4 % MMW2; int p = r4 / MMW2;
  int k  = kf*32 + lk*8 + j;
  int t  = k / CI, ci = k % CI;
  int co = m*16 + lm;
  int py = p >> 1, px = p & 1, dy = t >> 1, dx = t & 1;
  int ky = (py ? 0 : 1) + 2*dy;
  int kx = (px ? 0 : 1) + 2*dx;
  wpn[e] = bfbits(w[((ci*CO + co)*4 + ky)*4 + kx]);
}

// ---------------- fused prep: all independent preprocessing in ONE launch.
__global__ __launch_bounds__(256) void k_prep(
    const float* __restrict__ W_h, const float* __restrict__ W_c,
    float* __restrict__ WhT, float* __restrict__ WcT,
    const float* __restrict__ fc_W, ushort* __restrict__ wpfc,
    const float* __restrict__ W_f, ushort* __restrict__ wpff,
    const float* __restrict__ Wih, const float* __restrict__ Whh,
    uint4* __restrict__ Whq8, uint4* __restrict__ Wsq8, float* __restrict__ stats,
    const float* __restrict__ b_ih, const float* __restrict__ b_hh,
    const float* __restrict__ init_in,
    float4* __restrict__ xg4, float4* __restrict__ bias4,
    const float* __restrict__ w0, ushort* __restrict__ wp0,
    const float* __restrict__ w1, ushort* __restrict__ wp1,
    const float* __restrict__ w2, ushort* __restrict__ wp2,
    const float* __restrict__ wf, ushort* __restrict__ wfb)
{
  __shared__ float t[32][33];
  __shared__ float4 red[4];
  const int b = blockIdx.x, tid = threadIdx.x;

  if (b < 128) {
    const float* src = (b < 64) ? W_h : W_c;
    float* dst = (b < 64) ? WhT : WcT;
    int bb = b & 63;
    int c0 = (bb & 7)*32, r0 = (bb >> 3)*32;
    int tx = tid & 31, ty = tid >> 5;
    #pragma unroll
    for (int i = 0; i < 4; ++i)
      t[ty+8*i][tx] = src[(size_t)(r0+ty+8*i)*256 + c0+tx];
    __syncthreads();
    #pragma unroll
    for (int i = 0; i < 4; ++i)
      dst[(size_t)(c0+ty+8*i)*256 + r0+tx] = t[tx][ty+8*i];
    return;
  }
  if (b < 10368) {               // fc_W -> bf16
    int i = (b - 128)*256 + tid;
    if (i < 2621440) wpfc[i] = bfbits(fc_W[i]);
    return;
  }
  if (b < 10880) {               // W_f -> bf16
    int i = (b - 10368)*256 + tid;
    if (i < 131072) wpff[i] = bfbits(W_f[i]);
    return;
  }
  if (b < 10944) {               // lstm fp8 weight pack + stats zero
    int k4 = b - 10880, j = tid;
    if (k4 < 2) { int i = k4*256 + j; if (i < 448) stats[i] = 0.f; }
    uint h4[4], s4[4];
    #pragma unroll
    for (int d = 0; d < 4; ++d) {
      int k = 4*k4 + d;
      float hi = Whh[j*256+k],       hf = Whh[(256+j)*256+k];
      float hg = Whh[(512+j)*256+k], ho = Whh[(768+j)*256+k];
      float ii = Wih[j*256+k],       iff = Wih[(256+j)*256+k];
      float ig = Wih[(512+j)*256+k], io = Wih[(768+j)*256+k];
      int lo = __builtin_amdgcn_cvt_pk_fp8_f32(hi, hf, 0, false);
      h4[d] = (uint)__builtin_amdgcn_cvt_pk_fp8_f32(hg, ho, lo, true);
      lo = __builtin_amdgcn_cvt_pk_fp8_f32(hi+ii, hf+iff, 0, false);
      s4[d] = (uint)__builtin_amdgcn_cvt_pk_fp8_f32(hg+ig, ho+io, lo, true);
    }
    Whq8[k4*256+j] = make_uint4(h4[0], h4[1], h4[2], h4[3]);
    Wsq8[k4*256+j] = make_uint4(s4[0], s4[1], s4[2], s4[3]);
    return;
  }
  if (b < 11200) {               // xgbias
    int bb = b - 10944, tt = tid;
    float v = init_in[tt];
    float p0 = v * Wih[bb*256 + tt];
    float p1 = v * Wih[(256+bb)*256 + tt];
    float p2 = v * Wih[(512+bb)*256 + tt];
    float p3 = v * Wih[(768+bb)*256 + tt];
    #pragma unroll
    for (int o = 32; o; o >>= 1) {
      p0 += __shfl_xor(p0, o); p1 += __shfl_xor(p1, o);
      p2 += __shfl_xor(p2, o); p3 += __shfl_xor(p3, o);
    }
    int lane = tt & 63, wid = tt >> 6;
    if (lane == 0) red[wid] = make_float4(p0,p1,p2,p3);
    __syncthreads();
    if (tt == 0) {
      float4 bi = make_float4(b_ih[bb]+b_hh[bb], b_ih[256+bb]+b_hh[256+bb],
                              b_ih[512+bb]+b_hh[512+bb], b_ih[768+bb]+b_hh[768+bb]);
      bias4[bb] = bi;
      float4 a = bi;
      #pragma unroll
      for (int w = 0; w < 4; ++w) { a.x += red[w].x; a.y += red[w].y; a.z += red[w].z; a.w += red[w].w; }
      xg4[bb] = a;
    }
    return;
  }
  if (b < 13248) { wprep_body<256,128>(w0, wp0, (b - 11200)*256 + tid); return; }
  if (b < 13760) { wprep_body<128,64>(w1, wp1, (b - 13248)*256 + tid); return; }
  if (b < 13888) { wprep_body<64,32>(w2, wp2, (b - 13760)*256 + tid); return; }
  {                              // wfprep
    int e = (b - 13888)*256 + tid;
    if (e < 512) {
      int tt = e >> 5, ci = e & 31;
      wfb[tt*32 + ci] = bfbits(wf[ci*16 + tt]);
    }
  }
}

__global__ __launch_bounds__(256) void k_h0c0(const float* __restrict__ zc, const float* __restrict__ zm,
                      const float* __restrict__ WhT, const float* __restrict__ WcT,
                      const float* __restrict__ b_h, const float* __restrict__ b_c,
                      float* __restrict__ h, float* __restrict__ c){
  __shared__ float zs[256];
  int b = blockIdx.x, j = threadIdx.x;
  zs[j] = (j < 128) ? zc[b*128 + j] : zm[b*128 + (j-128)];
  __syncthreads();
  float ah = b_h[j], ac = b_c[j];
  #pragma unroll 4
  for (int k = 0; k < 256; ++k) {
    float zv = zs[k];
    ah = fmaf(zv, WhT[k*256 + j], ah);
    ac = fmaf(zv, WcT[k*256 + j], ac);
  }
  h[b*256+j] = ah; c[b*256+j] = ac;
}

// ---------------- entire 20-step LSTM; fp8 uint4 weight loads
__global__ __launch_bounds__(1024) void k_lstm_all(
    const uint4* __restrict__ Whq8, const uint4* __restrict__ Wsq8,
    const float4* __restrict__ xg4, const float4* __restrict__ bias4,
    const float* __restrict__ h0, const float* __restrict__ c0,
    ushort* __restrict__ outsb){
  __shared__ float hs[256];
  __shared__ float4 part[3][256];
  const int b = blockIdx.x, tid = threadIdx.x;
  const int j = tid & 255, kq = tid >> 8;
  float cj = 0.f;
  if (kq == 0) { hs[j] = h0[b*256 + j]; cj = c0[b*256 + j]; }
  __syncthreads();
  for (int t = 0; t < 20; ++t) {
    const uint4* __restrict__ Wp = ((t == 0) ? Whq8 : Wsq8) + (size_t)(kq*16)*256 + j;
    float4 a = make_float4(0.f, 0.f, 0.f, 0.f);
    #pragma unroll 8
    for (int kk = 0; kk < 16; ++kk) {
      uint4 wv = Wp[(size_t)kk*256];
      const float* __restrict__ hb = &hs[kq*64 + 4*kk];
      {
        f32x2 pif = __builtin_amdgcn_cvt_pk_f32_fp8((int)wv.x, false);
        f32x2 pgo = __builtin_amdgcn_cvt_pk_f32_fp8((int)wv.x, true);
        float hv = hb[0];
        a.x = fmaf(hv, pif[0], a.x); a.y = fmaf(hv, pif[1], a.y);
        a.z = fmaf(hv, pgo[0], a.z); a.w = fmaf(hv, pgo[1], a.w);
      }
      {
        f32x2 pif = __builtin_amdgcn_cvt_pk_f32_fp8((int)wv.y, false);
        f32x2 pgo = __builtin_amdgcn_cvt_pk_f32_fp8((int)wv.y, true);
        float hv = hb[1];
        a.x = fmaf(hv, pif[0], a.x); a.y = fmaf(hv, pif[1], a.y);
        a.z = fmaf(hv, pgo[0], a.z); a.w = fmaf(hv, pgo[1], a.w);
      }
      {
        f32x2 pif = __builtin_amdgcn_cvt_pk_f32_fp8((int)wv.z, false);
        f32x2 pgo = __builtin_amdgcn_cvt_pk_f32_fp8((int)wv.z, true);
        float hv = hb[2];
        a.x = fmaf(hv, pif[0], a.x); a.y = fmaf(hv, pif[1], a.y);
        a.z = fmaf(hv, pgo[0], a.z); a.w = fmaf(hv, pgo[1], a.w);
      }
      {
        f32x2 pif = __builtin_amdgcn_cvt_pk_f32_fp8((int)wv.w, false);
        f32x2 pgo = __builtin_amdgcn_cvt_pk_f32_fp8((int)wv.w, true);
        float hv = hb[3];
        a.x = fmaf(hv, pif[0], a.x); a.y = fmaf(hv, pif[1], a.y);
        a.z = fmaf(hv, pgo[0], a.z); a.w = fmaf(hv, pgo[1], a.w);
      }
    }
    if (kq) part[kq-1][j] = a;
    __syncthreads();
    if (kq == 0) {
      float4 p1 = part[0][j], p2 = part[1][j], p3 = part[2][j];
      float4 bb = (t == 0) ? xg4[j] : bias4[j];
      a.x += p1.x + p2.x + p3.x + bb.x;
      a.y += p1.y + p2.y + p3.y + bb.y;
      a.z += p1.z + p2.z + p3.z + bb.z;
      a.w += p1.w + p2.w + p3.w + bb.w;
      float ig = sig_f(a.x), fg = sig_f(a.y), gg = tanh_f(a.z), og = sig_f(a.w);
      cj = fmaf(fg, cj, ig*gg);
      float hj = og * tanh_f(cj);
      outsb[(b*20 + t)*256 + j] = bfbits(hj);
      hs[j] = hj;
    }
    __syncthreads();
  }
}

// ---------------- MFMA ff GEMM (+ fused zc concat)
__global__ __launch_bounds__(256) void k_ff_m(
    const ushort* __restrict__ A, const ushort* __restrict__ W,
    const float* __restrict__ bias, const float* __restrict__ zc,
    ushort* __restrict__ C)
{
  constexpr int K = 256, BK = 64, NK = K/BK, BM = 128, BN = 64;
  constexpr int RS = 72;
  constexpr int NCF = BN/16;
  constexpr int AC = 4, WC = 2;

  __shared__ __align__(16) ushort Al[2][BM*RS];
  __shared__ __align__(16) ushort Wl[2][BN*RS];

  const int tid = threadIdx.x;
  const int col0 = blockIdx.x * BN, row0 = blockIdx.y * BM;
  const int w = tid >> 6, l = tid & 63, lm = l & 15, lk = l >> 4;

  f32x4 acc[NCF][2];
  #pragma unroll
  for (int m = 0; m < NCF; ++m)
    #pragma unroll
    for (int s = 0; s < 2; ++s)
      acc[m][s] = (f32x4){0.f,0.f,0.f,0.f};

  uint4 ar[AC], wr[WC];

  #define LOADG(kt) { \
    _Pragma("unroll") \
    for (int i = 0; i < AC; ++i) { \
      int chunk = tid + i*256; \
      int rl = chunk >> 3, kc = chunk & 7; \
      ar[i] = *(const uint4*)&A[(size_t)(row0+rl)*K + (kt)*BK + kc*8]; \
    } \
    _Pragma("unroll") \
    for (int i = 0; i < WC; ++i) { \
      int chunk = tid + i*256; \
      int co = chunk >> 3, kc = chunk & 7; \
      wr[i] = *(const uint4*)&W[(size_t)(col0+co)*K + (kt)*BK + kc*8]; \
    } }

  #define STOREL(buf) { \
    _Pragma("unroll") \
    for (int i = 0; i < AC; ++i) { \
      int chunk = tid + i*256; \
      int rl = chunk >> 3, kc = chunk & 7; \
      *(uint4*)&Al[buf][rl*RS + kc*8] = ar[i]; \
    } \
    _Pragma("unroll") \
    for (int i = 0; i < WC; ++i) { \
      int chunk = tid + i*256; \
      int co = chunk >> 3, kc = chunk & 7; \
      *(uint4*)&Wl[buf][co*RS + kc*8] = wr[i]; \
    } }

  LOADG(0);
  STOREL(0);
  int cur = 0;
  for (int kt = 0; kt < NK; ++kt) {
    if (kt + 1 < NK) LOADG(kt + 1);
    __syncthreads();
    #pragma unroll
    for (int kf = 0; kf < 2; ++kf) {
      bf16x8 bfr[2];
      #pragma unroll
      for (int s = 0; s < 2; ++s)
        bfr[s] = *(bf16x8*)&Al[cur][(w*32 + s*16 + lm)*RS + kf*32 + lk*8];
      #pragma unroll
      for (int m = 0; m < NCF; ++m) {
        bf16x8 afr = *(bf16x8*)&Wl[cur][(m*16 + lm)*RS + kf*32 + lk*8];
        acc[m][0] = __builtin_amdgcn_mfma_f32_16x16x32_bf16(afr, bfr[0], acc[m][0], 0, 0, 0);
        acc[m][1] = __builtin_amdgcn_mfma_f32_16x16x32_bf16(afr, bfr[1], acc[m][1], 0, 0, 0);
      }
    }
    if (kt + 1 < NK) STOREL(cur ^ 1);
    cur ^= 1;
  }

  #pragma unroll
  for (int m = 0; m < NCF; ++m) {
    #pragma unroll
    for (int s = 0; s < 2; ++s) {
      int row = row0 + w*32 + s*16 + lm;
      f32x4 v = acc[m][s];
      int u0 = col0 + m*16 + lk*4;
      union { ushort u[4]; uint2 q; } pk;
      #pragma unroll
      for (int j = 0; j < 4; ++j)
        pk.u[j] = bfbits(LRELU(v[j] + bias[u0+j]));
      *(uint2*)&C[(size_t)row*640 + u0] = pk.q;
    }
  }
  // fused zc concat
  {
    int base = ((int)blockIdx.y*8 + (int)blockIdx.x)*2048 + tid;
    #pragma unroll
    for (int i = 0; i < 8; ++i) {
      int e = base + i*256;
      int r = e >> 7, c2 = e & 127;
      C[r*640 + 512 + c2] = bfbits(zc[(r/20)*128 + c2]);
    }
  }
  #undef LOADG
  #undef STOREL
}

// ---------------- MFMA FC GEMM: C[1280][4096] = lrelu(A@W^T + bias), NHWC bf16 out
__global__ __launch_bounds__(256) void k_gemm_fc_m(
    const ushort* __restrict__ A, const ushort* __restrict__ W,
    const float* __restrict__ bias, ushort* __restrict__ C)
{
  constexpr int K = 640, BK = 64, NK = K/BK, BM = 128, BN = 64;
  constexpr int RS = 72;
  constexpr int NCF = BN/16;
  constexpr int AC = 4, WC = 2;

  __shared__ __align__(16) ushort Al[2][BM*RS];
  __shared__ __align__(16) ushort Wl[2][BN*RS];

  const int tid = threadIdx.x;
  const int col0 = blockIdx.x * BN, row0 = blockIdx.y * BM;
  const int w = tid >> 6, l = tid & 63, lm = l & 15, lk = l >> 4;

  f32x4 acc[NCF][2];
  #pragma unroll
  for (int m = 0; m < NCF; ++m)
    #pragma unroll
    for (int s = 0; s < 2; ++s)
      acc[m][s] = (f32x4){0.f,0.f,0.f,0.f};

  uint4 ar[AC], wr[WC];

  #define LOADG(kt) { \
    _Pragma("unroll") \
    for (int i = 0; i < AC; ++i) { \
      int chunk = tid + i*256; \
      int rl = chunk >> 3, kc = chunk & 7; \
      ar[i] = *(const uint4*)&A[(size_t)(row0+rl)*K + (kt)*BK + kc*8]; \
    } \
    _Pragma("unroll") \
    for (int i = 0; i < WC; ++i) { \
      int chunk = tid + i*256; \
      int co = chunk >> 3, kc = chunk & 7; \
      wr[i] = *(const uint4*)&W[(size_t)(col0+co)*K + (kt)*BK + kc*8]; \
    } }

  #define STOREL(buf) { \
    _Pragma("unroll") \
    for (int i = 0; i < AC; ++i) { \
      int chunk = tid + i*256; \
      int rl = chunk >> 3, kc = chunk & 7; \
      *(uint4*)&Al[buf][rl*RS + kc*8] = ar[i]; \
    } \
    _Pragma("unroll") \
    for (int i = 0; i < WC; ++i) { \
      int chunk = tid + i*256; \
      int co = chunk >> 3, kc = chunk & 7; \
      *(uint4*)&Wl[buf][co*RS + kc*8] = wr[i]; \
    } }

  LOADG(0);
  STOREL(0);
  int cur = 0;
  for (int kt = 0; kt < NK; ++kt) {
    if (kt + 1 < NK) LOADG(kt + 1);
    __syncthreads();
    #pragma unroll
    for (int kf = 0; kf < 2; ++kf) {
      bf16x8 bfr[2];
      #pragma unroll
      for (int s = 0; s < 2; ++s)
        bfr[s] = *(bf16x8*)&Al[cur][(w*32 + s*16 + lm)*RS + kf*32 + lk*8];
      #pragma unroll
      for (int m = 0; m < NCF; ++m) {
        bf16x8 afr = *(bf16x8*)&Wl[cur][(m*16 + lm)*RS + kf*32 + lk*8];
        acc[m][0] = __builtin_amdgcn_mfma_f32_16x16x32_bf16(afr, bfr[0], acc[m][0], 0, 0, 0);
        acc[m][1] = __builtin_amdgcn_mfma_f32_16x16x32_bf16(afr, bfr[1], acc[m][1], 0, 0, 0);
      }
    }
    if (kt + 1 < NK) STOREL(cur ^ 1);
    cur ^= 1;
  }

  #pragma unroll
  for (int m = 0; m < NCF; ++m) {
    #pragma unroll
    for (int s = 0; s < 2; ++s) {
      int row = row0 + w*32 + s*16 + lm;
      f32x4 v = acc[m][s];
      #pragma unroll
      for (int j = 0; j < 4; ++j) {
        int u = col0 + m*16 + lk*4 + j;
        float val = LRELU(v[j] + bias[u]);
        C[((size_t)row << 12) + ((size_t)(u & 15) << 8) + (u >> 4)] = bfbits(val);
      }
    }
  }
  #undef LOADG
  #undef STOREL
}

// ---------------- MFMA parity-GEMM deconv (stage 0): A in LDS dbuf, weights
// direct-from-global in slab layout; CO-split via blockIdx.z (coz half)
template<int CI, int CO, int HI>
__global__ __launch_bounds__(256) void k_dcv(
    const ushort* __restrict__ in, const ushort* __restrict__ wp,
    ushort* __restrict__ out, float* __restrict__ gsum, float* __restrict__ gsq)
{
  constexpr int WI = HI, HO = 2*HI, WO = 2*WI;
  constexpr int K = 4*CI, BK = 64, NK = K/BK, KFT = K/32;
  constexpr int BSP = 128;
  constexpr int RS = 72;
  constexpr int NCF = CO/32;
  constexpr int COH = CO/2;
  constexpr int AC = BSP/32;

  __shared__ __align__(16) ushort Al[2][BSP*RS];
  __shared__ float s_sum[COH], s_sq[COH];

  const int tid = threadIdx.x;
  const int sp0 = blockIdx.x * BSP;
  const int p  = blockIdx.y;
  const int coz = blockIdx.z;
  const int py = p >> 1, px = p & 1;
  const int w  = tid >> 6, l = tid & 63;
  const int lm = l & 15, lk = l >> 4;

  if (tid < COH) { s_sum[tid] = 0.f; s_sq[tid] = 0.f; }

  f32x4 acc[NCF][2];
  #pragma unroll
  for (int m = 0; m < NCF; ++m)
    #pragma unroll
    for (int s = 0; s < 2; ++s)
      acc[m][s] = (f32x4){0.f,0.f,0.f,0.f};

  uint4 ar[AC];
  const ushort* wpb = wp + (size_t)(p*(CO/16) + coz*NCF)*KFT*512;

  #define LOADT(kt) { \
    int t = ((kt)*BK)/CI, ci0 = ((kt)*BK)%CI; \
    int dy = t >> 1, dx = t & 1; \
    _Pragma("unroll") \
    for (int i = 0; i < AC; ++i) { \
      int chunk = tid + i*256; \
      int rl = chunk >> 3, kc = chunk & 7; \
      int r = sp0 + rl; \
      int n = r / (HI*WI), rem = r % (HI*WI); \
      int oy = rem / WI, ox = rem % WI; \
      int iy = oy + py - dy, ix = ox + px - dx; \
      if ((unsigned)iy < (unsigned)HI && (unsigned)ix < (unsigned)WI) \
        ar[i] = *(const uint4*)&in[((((size_t)n*HI + iy)*WI + ix)*CI) + ci0 + kc*8]; \
      else ar[i] = make_uint4(0,0,0,0); \
    } }

  #define STORET(buf) { \
    _Pragma("unroll") \
    for (int i = 0; i < AC; ++i) { \
      int chunk = tid + i*256; \
      int rl = chunk >> 3, kc = chunk & 7; \
      *(uint4*)&Al[buf][rl*RS + kc*8] = ar[i]; \
    } }

  LOADT(0);
  STORET(0);
  int cur = 0;
  for (int kt = 0; kt < NK; ++kt) {
    if (kt + 1 < NK) LOADT(kt + 1);
    __syncthreads();
    #pragma unroll
    for (int kf = 0; kf < 2; ++kf) {
      const int ktg = kt*2 + kf;
      bf16x8 bfr[2];
      #pragma unroll
      for (int s = 0; s < 2; ++s)
        bfr[s] = *(bf16x8*)&Al[cur][(w*32 + s*16 + lm)*RS + kf*32 + lk*8];
      #pragma unroll
      for (int m = 0; m < NCF; ++m) {
        bf16x8 afr = *(const bf16x8*)&wpb[((size_t)m*KFT + ktg)*512 + lm*32 + lk*8];
        acc[m][0] = __builtin_amdgcn_mfma_f32_16x16x32_bf16(afr, bfr[0], acc[m][0], 0, 0, 0);
        acc[m][1] = __builtin_amdgcn_mfma_f32_16x16x32_bf16(afr, bfr[1], acc[m][1], 0, 0, 0);
      }
    }
    if (kt + 1 < NK) STORET(cur ^ 1);
    cur ^= 1;
  }

  // pass 1: batch stats only (this CO half)
  #pragma unroll
  for (int m = 0; m < NCF; ++m) {
    float s1[4] = {0,0,0,0}, s2[4] = {0,0,0,0};
    #pragma unroll
    for (int s = 0; s < 2; ++s) {
      f32x4 v = acc[m][s];
      #pragma unroll
      for (int j = 0; j < 4; ++j) { s1[j] += v[j]; s2[j] += v[j]*v[j]; }
    }
    #pragma unroll
    for (int j = 0; j < 4; ++j) {
      float a = s1[j], b = s2[j];
      #pragma unroll
      for (int o = 1; o < 16; o <<= 1) { a += __shfl_xor(a, o); b += __shfl_xor(b, o); }
      if (lm == 0) {
        atomicAdd(&s_sum[m*16 + lk*4 + j], a);
        atomicAdd(&s_sq [m*16 + lk*4 + j], b);
      }
    }
  }
  // pass 2: stores, s-outer / m-inner
  #pragma unroll
  for (int s = 0; s < 2; ++s) {
    int sp = sp0 + w*32 + s*16 + lm;
    int n = sp / (HI*WI), rem = sp % (HI*WI);
    int y = 2*(rem / WI) + py, x = 2*(rem % WI) + px;
    size_t ob = (((size_t)n*HO + y)*WO + x)*CO + coz*COH + lk*4;
    #pragma unroll
    for (int m = 0; m < NCF; ++m) {
      f32x4 v = acc[m][s];
      union { ushort u[4]; uint2 q; } pk;
      pk.u[0] = bfbits(v[0]); pk.u[1] = bfbits(v[1]);
      pk.u[2] = bfbits(v[2]); pk.u[3] = bfbits(v[3]);
      *(uint2*)&out[ob + m*16] = pk.q;
    }
  }
  __syncthreads();
  for (int cc = tid; cc < COH; cc += 256) {
    atomicAdd(&gsum[coz*COH + cc], s_sum[cc]);
    atomicAdd(&gsq[coz*COH + cc],  s_sq[cc]);
  }
  #undef LOADT
  #undef STORET
}

// ---------------- image-resident MFMA deconv (stages 1 & 2); waves_per_eu max=4
// caps occupancy at 2 blocks/CU so the register allocator gets a 128-VGPR budget
// and the weight-fragment prefetch can stay live across the MFMA block
template<int CI, int CO, int HI>
__global__ __attribute__((amdgpu_flat_work_group_size(512, 512), amdgpu_waves_per_eu(2, 4)))
void k_dcvim(
    const ushort* __restrict__ in, const ushort* __restrict__ wp,
    const float* __restrict__ gsumP, const float* __restrict__ gsqP,
    const float* __restrict__ gP, const float* __restrict__ beP, float invNP,
    ushort* __restrict__ out, float* __restrict__ gsum, float* __restrict__ gsq)
{
  constexpr int WI = HI, HO = 2*HI, WO = 2*WI;
  constexpr int K = 4*CI;
  constexpr int KF = K/32;
  constexpr int PAD = HI + 2;
  constexpr int CICH = CI/8;
  constexpr int MMW2 = CO/16;
  constexpr int SFTH = HI*WI/32;

  __shared__ __align__(16) ushort Ain[PAD*PAD*CI];
  __shared__ float s_sum[CO], s_sq[CO];
  __shared__ float s_scale[CI], s_shift[CI];

  const int tid = threadIdx.x;
  const int n = blockIdx.x;
  const int w = tid >> 6, l = tid & 63, lm = l & 15, lk = l >> 4;
  const int p = w >> 1, py = p >> 1, px = p & 1, ph = w & 1;

  if (tid < CO) { s_sum[tid] = 0.f; s_sq[tid] = 0.f; }
  if (tid >= 512-CI) {
    int c = tid - (512-CI);
    float m = gsumP[c]*invNP;
    float v = gsqP[c]*invNP - m*m;
    float sc = gP[c]*rsqrtf(v + 1e-5f);
    s_scale[c] = sc;
    s_shift[c] = beP[c] - m*sc;
  }
  __syncthreads();

  const ushort* inb = in + (size_t)n * HI * WI * CI;
  constexpr int NPCH = PAD*PAD*CICH;
  for (int e = tid; e < NPCH; e += 512) {
    int ci8 = e % CICH; int sp = e / CICH;
    int c = sp % PAD, r = sp / PAD;
    int chS = ci8 ^ (c & 7);
    if (r >= 1 && r <= HI && c >= 1 && c <= WI) {
      uint4 u = *(const uint4*)&inb[(((size_t)(r-1)*WI + (c-1))*CI) + ci8*8];
      int ci0 = ci8*8;
      float4 sc0 = *(const float4*)&s_scale[ci0];
      float4 sc1 = *(const float4*)&s_scale[ci0+4];
      float4 sh0 = *(const float4*)&s_shift[ci0];
      float4 sh1 = *(const float4*)&s_shift[ci0+4];
      float v0 = LRELU(fmaf(bflo(u.x), sc0.x, sh0.x));
      float v1 = LRELU(fmaf(bfhi(u.x), sc0.y, sh0.y));
      float v2 = LRELU(fmaf(bflo(u.y), sc0.z, sh0.z));
      float v3 = LRELU(fmaf(bfhi(u.y), sc0.w, sh0.w));
      float v4 = LRELU(fmaf(bflo(u.z), sc1.x, sh1.x));
      float v5 = LRELU(fmaf(bfhi(u.z), sc1.y, sh1.y));
      float v6 = LRELU(fmaf(bflo(u.w), sc1.z, sh1.z));
      float v7 = LRELU(fmaf(bfhi(u.w), sc1.w, sh1.w));
      uint4 o;
      o.x = (uint)bfpack(v0, v1);
      o.y = (uint)bfpack(v2, v3);
      o.z = (uint)bfpack(v4, v5);
      o.w = (uint)bfpack(v6, v7);
      ((uint4*)Ain)[(r*PAD + c)*CICH + chS] = o;
    } else {
      ((uint4*)Ain)[(r*PAD + c)*CICH + chS] = make_uint4(0,0,0,0);
    }
  }
  __syncthreads();

  f32x4 acc[MMW2][SFTH];
  #pragma unroll
  for (int m = 0; m < MMW2; ++m)
    #pragma unroll
    for (int sf = 0; sf < SFTH; ++sf)
      acc[m][sf] = (f32x4){0.f,0.f,0.f,0.f};

  const ushort* wpb = wp + (size_t)(p*MMW2)*KF*512;
  bf16x8 afrN[MMW2];
  #pragma unroll
  for (int m = 0; m < MMW2; ++m)
    afrN[m] = *(const bf16x8*)&wpb[((size_t)m*KF)*512 + lm*32 + lk*8];
  #pragma unroll
  for (int kf = 0; kf < KF; ++kf) {
    const int t = (kf*32)/CI, cib = (kf*32)%CI;
    const int dy = t >> 1, dx = t & 1;
    bf16x8 afr[MMW2];
    #pragma unroll
    for (int m = 0; m < MMW2; ++m) afr[m] = afrN[m];
    if (kf + 1 < KF) {
      #pragma unroll
      for (int m = 0; m < MMW2; ++m)
        afrN[m] = *(const bf16x8*)&wpb[((size_t)m*KF + (kf+1))*512 + lm*32 + lk*8];
    }
    const int ch = (cib >> 3) + lk;
    #pragma unroll
    for (int sf = 0; sf < SFTH; ++sf) {
      int s = (ph*SFTH + sf)*16 + lm;
      int y = s / WI, x = s % WI;
      int r = y + py - dy + 1, c = x + px - dx + 1;
      bf16x8 bfr = *(const bf16x8*)&Ain[((r*PAD + c)*CICH + (ch ^ (c & 7)))*8];
      #pragma unroll
      for (int m = 0; m < MMW2; ++m)
        acc[m][sf] = __builtin_amdgcn_mfma_f32_16x16x32_bf16(afr[m], bfr, acc[m][sf], 0, 0, 0);
    }
  }

  float s1[MMW2][4], s2[MMW2][4];
  #pragma unroll
  for (int m = 0; m < MMW2; ++m)
    #pragma unroll
    for (int j = 0; j < 4; ++j) { s1[m][j] = 0.f; s2[m][j] = 0.f; }

  #pragma unroll
  for (int sf = 0; sf < SFTH; ++sf) {
    int s = (ph*SFTH + sf)*16 + lm;
    int y = 2*(s / WI) + py, x = 2*(s % WI) + px;
    size_t ob = (((size_t)n*HO + y)*WO + x)*CO + lk*4;
    #pragma unroll
    for (int m = 0; m < MMW2; ++m) {
      f32x4 v = acc[m][sf];
      union { ushort u[4]; uint2 q; } pk;
      #pragma unroll
      for (int j = 0; j < 4; ++j) {
        pk.u[j] = bfbits(v[j]);
        s1[m][j] += v[j];
        s2[m][j] += v[j]*v[j];
      }
      *(uint2*)&out[ob + m*16] = pk.q;
    }
  }

  #pragma unroll
  for (int m = 0; m < MMW2; ++m) {
    #pragma unroll
    for (int j = 0; j < 4; ++j) {
      float a = s1[m][j], b = s2[m][j];
      #pragma unroll
      for (int o = 1; o < 16; o <<= 1) { a += __shfl_xor(a, o); b += __shfl_xor(b, o); }
      if (lm == 0) {
        atomicAdd(&s_sum[m*16 + lk*4 + j], a);
        atomicAdd(&s_sq [m*16 + lk*4 + j], b);
      }
    }
  }

  __syncthreads();
  for (int cc = tid; cc < CO; cc += 512) {
    atomicAdd(&gsum[cc], s_sum[cc]);
    atomicAdd(&gsq[cc],  s_sq[cc]);
  }
}

// ---------------- final deconv 32->1 + sigmoid via tap-dot MFMA
__global__ __launch_bounds__(256) void k_final(
    const ushort* __restrict__ in, const ushort* __restrict__ wfb,
    const float* __restrict__ gsumP, const float* __restrict__ gsqP,
    const float* __restrict__ gP, const float* __restrict__ beP, float invNP,
    const float* __restrict__ bfb, float* __restrict__ outp)
{
  constexpr int CI=32, HI=32, WI=32, HO=64, WO=64, SPLIT=4, HOq=HO/SPLIT;
  constexpr int RMAX = 10;
  constexpr int DP = 20;
  __shared__ float Dl[RMAX*32*DP];
  __shared__ float s_scale[CI], s_shift[CI];

  const int tid = threadIdx.x, bid = blockIdx.x;
  const int n = bid % 1280, q = bid / 1280;
  const int y0 = q * HOq;
  const int rows_lo = max(0, y0/2 - 1);
  const int rows_hi = min(HI-1, (y0 + HOq)/2);
  const int nrows = rows_hi - rows_lo + 1;

  if (tid < CI) {
    float m = gsumP[tid]*invNP;
    float v = gsqP[tid]*invNP - m*m;
    float sc = gP[tid]*rsqrtf(v + 1e-5f);
    s_scale[tid] = sc;
    s_shift[tid] = beP[tid] - m*sc;
  }
  __syncthreads();

  const int w = tid >> 6, l = tid & 63, lm = l & 15, lk = l >> 4;
  const bf16x8 afr = *(const bf16x8*)&wfb[lm*32 + lk*8];
  const float4 sc0 = *(const float4*)&s_scale[lk*8];
  const float4 sc1 = *(const float4*)&s_scale[lk*8+4];
  const float4 sh0 = *(const float4*)&s_shift[lk*8];
  const float4 sh1 = *(const float4*)&s_shift[lk*8+4];

  const ushort* inb = in + (size_t)n * HI * WI * CI;
  const int ngrp = nrows * 2;
  for (int g = w; g < ngrp; g += 4) {
    int px = g*16 + lm;
    int rl = px >> 5, ix = px & 31;
    uint4 u = *(const uint4*)&inb[(((size_t)(rows_lo+rl)*WI + ix)*CI) + lk*8];
    float v0 = LRELU(fmaf(bflo(u.x), sc0.x, sh0.x));
    float v1 = LRELU(fmaf(bfhi(u.x), sc0.y, sh0.y));
    float v2 = LRELU(fmaf(bflo(u.y), sc0.z, sh0.z));
    float v3 = LRELU(fmaf(bfhi(u.y), sc0.w, sh0.w));
    float v4 = LRELU(fmaf(bflo(u.z), sc1.x, sh1.x));
    float v5 = LRELU(fmaf(bfhi(u.z), sc1.y, sh1.y));
    float v6 = LRELU(fmaf(bflo(u.w), sc1.z, sh1.z));
    float v7 = LRELU(fmaf(bfhi(u.w), sc1.w, sh1.w));
    union { uint uu[4]; bf16x8 v; } pk;
    pk.uu[0] = bfpack(v0, v1);
    pk.uu[1] = bfpack(v2, v3);
    pk.uu[2] = bfpack(v4, v5);
    pk.uu[3] = bfpack(v6, v7);
    f32x4 d = __builtin_amdgcn_mfma_f32_16x16x32_bf16(afr, pk.v, (f32x4){0.f,0.f,0.f,0.f}, 0, 0, 0);
    *(f32x4*)&Dl[px*DP + lk*4] = d;
  }
  __syncthreads();

  const float b0 = bfb[0];
  #pragma unroll
  for (int i = 0; i < (HOq*WO)/256; ++i) {
    int e = tid + i*256;
    int oy = e >> 6, x = e & 63;
    int y = y0 + oy;
    int kya = (y + 1) & 1, iya = (y + 1) >> 1;
    int kxa = (x + 1) & 1, ixa = (x + 1) >> 1;
    float acc = b0;
    #pragma unroll
    for (int dy = 0; dy < 2; ++dy) {
      int iy = iya - dy, ky = kya + 2*dy;
      if (iy < 0 || iy >= HI) continue;
      #pragma unroll
      for (int dx = 0; dx < 2; ++dx) {
        int ix = ixa - dx, kx = kxa + 2*dx;
        if (ix < 0 || ix >= WI) continue;
        acc += Dl[((iy - rows_lo)*WI + ix)*DP + (ky*4 + kx)];
      }
    }
    outp[(size_t)n*HO*WO + y*WO + x] = 1.f/(1.f + __expf(-acc));
  }
}

extern "C" void kernel_launch(void* const* d_in, const int* in_sizes, int n_in,
                              void* d_out, int out_size, void* d_ws, size_t ws_size,
                              hipStream_t stream) {
  const float* z_content = (const float*)d_in[0];
  const float* z_motion  = (const float*)d_in[1];
  const float* W_h  = (const float*)d_in[2];
  const float* b_h  = (const float*)d_in[3];
  const float* W_c  = (const float*)d_in[4];
  const float* b_c  = (const float*)d_in[5];
  const float* W_ih = (const float*)d_in[6];
  const float* W_hh = (const float*)d_in[7];
  const float* b_ih = (const float*)d_in[8];
  const float* b_hh = (const float*)d_in[9];
  const float* W_f  = (const float*)d_in[10];
  const float* b_f  = (const float*)d_in[11];
  const float* init_in = (const float*)d_in[12];
  const float* fc_W = (const float*)d_in[13];
  const float* fc_b = (const float*)d_in[14];
  const float* w0 = (const float*)d_in[15];
  const float* g0 = (const float*)d_in[16];
  const float* be0 = (const float*)d_in[17];
  const float* w1 = (const float*)d_in[18];
  const float* g1 = (const float*)d_in[19];
  const float* be1 = (const float*)d_in[20];
  const float* w2 = (const float*)d_in[21];
  const float* g2 = (const float*)d_in[22];
  const float* be2 = (const float*)d_in[23];
  const float* wf = (const float*)d_in[24];
  const float* bf_ = (const float*)d_in[25];

  const size_t P_BYTES = 10631168;
  const size_t X_OFF   = P_BYTES;
  const size_t X_BYTES = 83886080;
  const size_t Y_OFF   = X_OFF + X_BYTES;
  const size_t NEED    = Y_OFF + 41943040;
  if (ws_size < NEED) return;

  float* ws = (float*)d_ws;
  char*  wsb = (char*)d_ws;
  float* sum0 = ws + 0;        float* sq0 = ws + 128;
  float* sum1 = ws + 256;      float* sq1 = ws + 320;
  float* sum2 = ws + 384;      float* sq2 = ws + 416;
  float4* xg4   = (float4*)(ws + 1024);
  float4* bias4 = (float4*)(ws + 2048);
  float* h    = ws + 3072;
  float* c    = ws + 19456;
  ushort* outsb = (ushort*)(ws + 35840);
  float* WhT  = ws + 199680;
  float* WcT  = ws + 265216;
  uint4* Whq8 = (uint4*)(ws + 330752);
  uint4* Wsq8 = (uint4*)(ws + 592896);
  ushort* wp0 = (ushort*)(ws + 855040);
  ushort* wp1 = (ushort*)(ws + 1117184);
  ushort* wp2 = (ushort*)(ws + 1182720);
  ushort* wfb = (ushort*)(ws + 1199104);
  ushort* wpff = (ushort*)(ws + 1199616);
  ushort* featb = (ushort*)(ws + 1265152);

  ushort* wpfc = (ushort*)(wsb + X_OFF);
  ushort* out0 = (ushort*)(wsb + X_OFF);
  ushort* out2 = (ushort*)(wsb + X_OFF);
  ushort* h1   = (ushort*)(wsb + Y_OFF);
  ushort* out1 = (ushort*)(wsb + Y_OFF);

  // ---- all independent prep in ONE launch
  k_prep<<<13890, 256, 0, stream>>>(
      W_h, W_c, WhT, WcT, fc_W, wpfc, W_f, wpff,
      W_ih, W_hh, Whq8, Wsq8, ws, b_ih, b_hh, init_in, xg4, bias4,
      w0, wp0, w1, wp1, w2, wp2, wf, wfb);
  k_h0c0<<<64, 256, 0, stream>>>(z_content, z_motion, WhT, WcT, b_h, b_c, h, c);

  // ---- whole LSTM in one launch (fp8 weights)
  k_lstm_all<<<64, 1024, 0, stream>>>(Whq8, Wsq8, xg4, bias4, h, c, outsb);

  // ---- ff (MFMA, + fused zc concat) + fc (MFMA)
  k_ff_m<<<dim3(8, 10), 256, 0, stream>>>(outsb, wpff, b_f, z_content, featb);
  k_gemm_fc_m<<<dim3(64, 10), 256, 0, stream>>>(featb, wpfc, fc_b, h1);

  // ---- deconv pipeline
  k_dcv<256,128,4><<<dim3(160,4,2), 256, 0, stream>>>(h1, wp0, out0, sum0, sq0);
  k_dcvim<128,64,8><<<1280, 512, 0, stream>>>(out0, wp1, sum0, sq0, g0, be0, 1.f/81920.f, out1, sum1, sq1);
  k_dcvim<64,32,16><<<1280, 512, 0, stream>>>(out1, wp2, sum1, sq1, g1, be1, 1.f/327680.f, out2, sum2, sq2);
  k_final<<<5120, 256, 0, stream>>>(out2, wfb, sum2, sq2, g2, be2, 1.f/1310720.f, bf_, (float*)d_out);
}

// Round 28
// 400.775 us; speedup vs baseline: 1.2122x; 1.0035x over previous
//
#include <hip/hip_runtime.h>
#include <hip/hip_bf16.h>
#include <math.h>

typedef __hip_bfloat16 bf16;
typedef __attribute__((ext_vector_type(8))) short bf16x8;
typedef __attribute__((ext_vector_type(4))) float f32x4;
typedef __attribute__((ext_vector_type(2))) float f32x2;

#define LRELU(v) ((v) > 0.f ? (v) : 0.2f*(v))

__device__ __forceinline__ float sig_f(float x){ return 1.f/(1.f + __expf(-x)); }
__device__ __forceinline__ float tanh_f(float x){
  float ax = fabsf(x);
  float e = __expf(-2.f*ax);
  float t = (1.f - e)/(1.f + e);
  return x >= 0.f ? t : -t;
}
__device__ __forceinline__ ushort bfbits(float v){
  bf16 b = __float2bfloat16(v);
  return *(ushort*)&b;
}
__device__ __forceinline__ uint bfpack(float a, float b){
  return (uint)bfbits(a) | ((uint)bfbits(b) << 16);
}
__device__ __forceinline__ float bflo(uint u){ return __uint_as_float(u << 16); }
__device__ __forceinline__ float bfhi(uint u){ return __uint_as_float(u & 0xffff0000u); }

// wprep body (shared by the three deconv weight packs)
template<int CI, int CO>
__device__ __forceinline__ void wprep_body(const float* __restrict__ w,
                                           ushort* __restrict__ wpn, int e){
  constexpr int K = 4*CI, KF = K/32, MMW2 = CO/16;
  if (e >= 16*CI*CO) return;
  int j  = e & 7;
  int lk = (e >> 3) & 3;
  int lm = (e >> 5) & 15;
  int r3 = e >> 9;
  int kf = r3 % KF; int r4 = r3 / KF;
  int m  = r4 % MMW2; int p = r4 / MMW2;
  int k  = kf*32 + lk*8 + j;
  int t  = k / CI, ci = k % CI;
  int co = m*16 + lm;
  int py = p >> 1, px = p & 1, dy = t >> 1, dx = t & 1;
  int ky = (py ? 0 : 1) + 2*dy;
  int kx = (px ? 0 : 1) + 2*dx;
  wpn[e] = bfbits(w[((ci*CO + co)*4 + ky)*4 + kx]);
}

// ---------------- fused prep: all independent preprocessing in ONE launch.
__global__ __launch_bounds__(256) void k_prep(
    const float* __restrict__ W_h, const float* __restrict__ W_c,
    float* __restrict__ WhT, float* __restrict__ WcT,
    const float* __restrict__ fc_W, ushort* __restrict__ wpfc,
    const float* __restrict__ W_f, ushort* __restrict__ wpff,
    const float* __restrict__ Wih, const float* __restrict__ Whh,
    uint4* __restrict__ Whq8, uint4* __restrict__ Wsq8, float* __restrict__ stats,
    const float* __restrict__ b_ih, const float* __restrict__ b_hh,
    const float* __restrict__ init_in,
    float4* __restrict__ xg4, float4* __restrict__ bias4,
    const float* __restrict__ w0, ushort* __restrict__ wp0,
    const float* __restrict__ w1, ushort* __restrict__ wp1,
    const float* __restrict__ w2, ushort* __restrict__ wp2,
    const float* __restrict__ wf, ushort* __restrict__ wfb)
{
  __shared__ float t[32][33];
  __shared__ float4 red[4];
  const int b = blockIdx.x, tid = threadIdx.x;

  if (b < 128) {
    const float* src = (b < 64) ? W_h : W_c;
    float* dst = (b < 64) ? WhT : WcT;
    int bb = b & 63;
    int c0 = (bb & 7)*32, r0 = (bb >> 3)*32;
    int tx = tid & 31, ty = tid >> 5;
    #pragma unroll
    for (int i = 0; i < 4; ++i)
      t[ty+8*i][tx] = src[(size_t)(r0+ty+8*i)*256 + c0+tx];
    __syncthreads();
    #pragma unroll
    for (int i = 0; i < 4; ++i)
      dst[(size_t)(c0+ty+8*i)*256 + r0+tx] = t[tx][ty+8*i];
    return;
  }
  if (b < 10368) {               // fc_W -> bf16
    int i = (b - 128)*256 + tid;
    if (i < 2621440) wpfc[i] = bfbits(fc_W[i]);
    return;
  }
  if (b < 10880) {               // W_f -> bf16
    int i = (b - 10368)*256 + tid;
    if (i < 131072) wpff[i] = bfbits(W_f[i]);
    return;
  }
  if (b < 10944) {               // lstm fp8 weight pack + stats zero
    int k4 = b - 10880, j = tid;
    if (k4 < 2) { int i = k4*256 + j; if (i < 448) stats[i] = 0.f; }
    uint h4[4], s4[4];
    #pragma unroll
    for (int d = 0; d < 4; ++d) {
      int k = 4*k4 + d;
      float hi = Whh[j*256+k],       hf = Whh[(256+j)*256+k];
      float hg = Whh[(512+j)*256+k], ho = Whh[(768+j)*256+k];
      float ii = Wih[j*256+k],       iff = Wih[(256+j)*256+k];
      float ig = Wih[(512+j)*256+k], io = Wih[(768+j)*256+k];
      int lo = __builtin_amdgcn_cvt_pk_fp8_f32(hi, hf, 0, false);
      h4[d] = (uint)__builtin_amdgcn_cvt_pk_fp8_f32(hg, ho, lo, true);
      lo = __builtin_amdgcn_cvt_pk_fp8_f32(hi+ii, hf+iff, 0, false);
      s4[d] = (uint)__builtin_amdgcn_cvt_pk_fp8_f32(hg+ig, ho+io, lo, true);
    }
    Whq8[k4*256+j] = make_uint4(h4[0], h4[1], h4[2], h4[3]);
    Wsq8[k4*256+j] = make_uint4(s4[0], s4[1], s4[2], s4[3]);
    return;
  }
  if (b < 11200) {               // xgbias
    int bb = b - 10944, tt = tid;
    float v = init_in[tt];
    float p0 = v * Wih[bb*256 + tt];
    float p1 = v * Wih[(256+bb)*256 + tt];
    float p2 = v * Wih[(512+bb)*256 + tt];
    float p3 = v * Wih[(768+bb)*256 + tt];
    #pragma unroll
    for (int o = 32; o; o >>= 1) {
      p0 += __shfl_xor(p0, o); p1 += __shfl_xor(p1, o);
      p2 += __shfl_xor(p2, o); p3 += __shfl_xor(p3, o);
    }
    int lane = tt & 63, wid = tt >> 6;
    if (lane == 0) red[wid] = make_float4(p0,p1,p2,p3);
    __syncthreads();
    if (tt == 0) {
      float4 bi = make_float4(b_ih[bb]+b_hh[bb], b_ih[256+bb]+b_hh[256+bb],
                              b_ih[512+bb]+b_hh[512+bb], b_ih[768+bb]+b_hh[768+bb]);
      bias4[bb] = bi;
      float4 a = bi;
      #pragma unroll
      for (int w = 0; w < 4; ++w) { a.x += red[w].x; a.y += red[w].y; a.z += red[w].z; a.w += red[w].w; }
      xg4[bb] = a;
    }
    return;
  }
  if (b < 13248) { wprep_body<256,128>(w0, wp0, (b - 11200)*256 + tid); return; }
  if (b < 13760) { wprep_body<128,64>(w1, wp1, (b - 13248)*256 + tid); return; }
  if (b < 13888) { wprep_body<64,32>(w2, wp2, (b - 13760)*256 + tid); return; }
  {                              // wfprep
    int e = (b - 13888)*256 + tid;
    if (e < 512) {
      int tt = e >> 5, ci = e & 31;
      wfb[tt*32 + ci] = bfbits(wf[ci*16 + tt]);
    }
  }
}

__global__ __launch_bounds__(256) void k_h0c0(const float* __restrict__ zc, const float* __restrict__ zm,
                      const float* __restrict__ WhT, const float* __restrict__ WcT,
                      const float* __restrict__ b_h, const float* __restrict__ b_c,
                      float* __restrict__ h, float* __restrict__ c){
  __shared__ float zs[256];
  int b = blockIdx.x, j = threadIdx.x;
  zs[j] = (j < 128) ? zc[b*128 + j] : zm[b*128 + (j-128)];
  __syncthreads();
  float ah = b_h[j], ac = b_c[j];
  #pragma unroll 4
  for (int k = 0; k < 256; ++k) {
    float zv = zs[k];
    ah = fmaf(zv, WhT[k*256 + j], ah);
    ac = fmaf(zv, WcT[k*256 + j], ac);
  }
  h[b*256+j] = ah; c[b*256+j] = ac;
}

// ---------------- entire 20-step LSTM; fp8 uint4 weight loads
__global__ __launch_bounds__(1024) void k_lstm_all(
    const uint4* __restrict__ Whq8, const uint4* __restrict__ Wsq8,
    const float4* __restrict__ xg4, const float4* __restrict__ bias4,
    const float* __restrict__ h0, const float* __restrict__ c0,
    ushort* __restrict__ outsb){
  __shared__ float hs[256];
  __shared__ float4 part[3][256];
  const int b = blockIdx.x, tid = threadIdx.x;
  const int j = tid & 255, kq = tid >> 8;
  float cj = 0.f;
  if (kq == 0) { hs[j] = h0[b*256 + j]; cj = c0[b*256 + j]; }
  __syncthreads();
  for (int t = 0; t < 20; ++t) {
    const uint4* __restrict__ Wp = ((t == 0) ? Whq8 : Wsq8) + (size_t)(kq*16)*256 + j;
    float4 a = make_float4(0.f, 0.f, 0.f, 0.f);
    #pragma unroll 8
    for (int kk = 0; kk < 16; ++kk) {
      uint4 wv = Wp[(size_t)kk*256];
      const float* __restrict__ hb = &hs[kq*64 + 4*kk];
      {
        f32x2 pif = __builtin_amdgcn_cvt_pk_f32_fp8((int)wv.x, false);
        f32x2 pgo = __builtin_amdgcn_cvt_pk_f32_fp8((int)wv.x, true);
        float hv = hb[0];
        a.x = fmaf(hv, pif[0], a.x); a.y = fmaf(hv, pif[1], a.y);
        a.z = fmaf(hv, pgo[0], a.z); a.w = fmaf(hv, pgo[1], a.w);
      }
      {
        f32x2 pif = __builtin_amdgcn_cvt_pk_f32_fp8((int)wv.y, false);
        f32x2 pgo = __builtin_amdgcn_cvt_pk_f32_fp8((int)wv.y, true);
        float hv = hb[1];
        a.x = fmaf(hv, pif[0], a.x); a.y = fmaf(hv, pif[1], a.y);
        a.z = fmaf(hv, pgo[0], a.z); a.w = fmaf(hv, pgo[1], a.w);
      }
      {
        f32x2 pif = __builtin_amdgcn_cvt_pk_f32_fp8((int)wv.z, false);
        f32x2 pgo = __builtin_amdgcn_cvt_pk_f32_fp8((int)wv.z, true);
        float hv = hb[2];
        a.x = fmaf(hv, pif[0], a.x); a.y = fmaf(hv, pif[1], a.y);
        a.z = fmaf(hv, pgo[0], a.z); a.w = fmaf(hv, pgo[1], a.w);
      }
      {
        f32x2 pif = __builtin_amdgcn_cvt_pk_f32_fp8((int)wv.w, false);
        f32x2 pgo = __builtin_amdgcn_cvt_pk_f32_fp8((int)wv.w, true);
        float hv = hb[3];
        a.x = fmaf(hv, pif[0], a.x); a.y = fmaf(hv, pif[1], a.y);
        a.z = fmaf(hv, pgo[0], a.z); a.w = fmaf(hv, pgo[1], a.w);
      }
    }
    if (kq) part[kq-1][j] = a;
    __syncthreads();
    if (kq == 0) {
      float4 p1 = part[0][j], p2 = part[1][j], p3 = part[2][j];
      float4 bb = (t == 0) ? xg4[j] : bias4[j];
      a.x += p1.x + p2.x + p3.x + bb.x;
      a.y += p1.y + p2.y + p3.y + bb.y;
      a.z += p1.z + p2.z + p3.z + bb.z;
      a.w += p1.w + p2.w + p3.w + bb.w;
      float ig = sig_f(a.x), fg = sig_f(a.y), gg = tanh_f(a.z), og = sig_f(a.w);
      cj = fmaf(fg, cj, ig*gg);
      float hj = og * tanh_f(cj);
      outsb[(b*20 + t)*256 + j] = bfbits(hj);
      hs[j] = hj;
    }
    __syncthreads();
  }
}

// ---------------- MFMA ff GEMM (+ fused zc concat)
__global__ __launch_bounds__(256) void k_ff_m(
    const ushort* __restrict__ A, const ushort* __restrict__ W,
    const float* __restrict__ bias, const float* __restrict__ zc,
    ushort* __restrict__ C)
{
  constexpr int K = 256, BK = 64, NK = K/BK, BM = 128, BN = 64;
  constexpr int RS = 72;
  constexpr int NCF = BN/16;
  constexpr int AC = 4, WC = 2;

  __shared__ __align__(16) ushort Al[2][BM*RS];
  __shared__ __align__(16) ushort Wl[2][BN*RS];

  const int tid = threadIdx.x;
  const int col0 = blockIdx.x * BN, row0 = blockIdx.y * BM;
  const int w = tid >> 6, l = tid & 63, lm = l & 15, lk = l >> 4;

  f32x4 acc[NCF][2];
  #pragma unroll
  for (int m = 0; m < NCF; ++m)
    #pragma unroll
    for (int s = 0; s < 2; ++s)
      acc[m][s] = (f32x4){0.f,0.f,0.f,0.f};

  uint4 ar[AC], wr[WC];

  #define LOADG(kt) { \
    _Pragma("unroll") \
    for (int i = 0; i < AC; ++i) { \
      int chunk = tid + i*256; \
      int rl = chunk >> 3, kc = chunk & 7; \
      ar[i] = *(const uint4*)&A[(size_t)(row0+rl)*K + (kt)*BK + kc*8]; \
    } \
    _Pragma("unroll") \
    for (int i = 0; i < WC; ++i) { \
      int chunk = tid + i*256; \
      int co = chunk >> 3, kc = chunk & 7; \
      wr[i] = *(const uint4*)&W[(size_t)(col0+co)*K + (kt)*BK + kc*8]; \
    } }

  #define STOREL(buf) { \
    _Pragma("unroll") \
    for (int i = 0; i < AC; ++i) { \
      int chunk = tid + i*256; \
      int rl = chunk >> 3, kc = chunk & 7; \
      *(uint4*)&Al[buf][rl*RS + kc*8] = ar[i]; \
    } \
    _Pragma("unroll") \
    for (int i = 0; i < WC; ++i) { \
      int chunk = tid + i*256; \
      int co = chunk >> 3, kc = chunk & 7; \
      *(uint4*)&Wl[buf][co*RS + kc*8] = wr[i]; \
    } }

  LOADG(0);
  STOREL(0);
  int cur = 0;
  for (int kt = 0; kt < NK; ++kt) {
    if (kt + 1 < NK) LOADG(kt + 1);
    __syncthreads();
    #pragma unroll
    for (int kf = 0; kf < 2; ++kf) {
      bf16x8 bfr[2];
      #pragma unroll
      for (int s = 0; s < 2; ++s)
        bfr[s] = *(bf16x8*)&Al[cur][(w*32 + s*16 + lm)*RS + kf*32 + lk*8];
      #pragma unroll
      for (int m = 0; m < NCF; ++m) {
        bf16x8 afr = *(bf16x8*)&Wl[cur][(m*16 + lm)*RS + kf*32 + lk*8];
        acc[m][0] = __builtin_amdgcn_mfma_f32_16x16x32_bf16(afr, bfr[0], acc[m][0], 0, 0, 0);
        acc[m][1] = __builtin_amdgcn_mfma_f32_16x16x32_bf16(afr, bfr[1], acc[m][1], 0, 0, 0);
      }
    }
    if (kt + 1 < NK) STOREL(cur ^ 1);
    cur ^= 1;
  }

  #pragma unroll
  for (int m = 0; m < NCF; ++m) {
    #pragma unroll
    for (int s = 0; s < 2; ++s) {
      int row = row0 + w*32 + s*16 + lm;
      f32x4 v = acc[m][s];
      int u0 = col0 + m*16 + lk*4;
      union { ushort u[4]; uint2 q; } pk;
      #pragma unroll
      for (int j = 0; j < 4; ++j)
        pk.u[j] = bfbits(LRELU(v[j] + bias[u0+j]));
      *(uint2*)&C[(size_t)row*640 + u0] = pk.q;
    }
  }
  // fused zc concat
  {
    int base = ((int)blockIdx.y*8 + (int)blockIdx.x)*2048 + tid;
    #pragma unroll
    for (int i = 0; i < 8; ++i) {
      int e = base + i*256;
      int r = e >> 7, c2 = e & 127;
      C[r*640 + 512 + c2] = bfbits(zc[(r/20)*128 + c2]);
    }
  }
  #undef LOADG
  #undef STOREL
}

// ---------------- MFMA FC GEMM: C[1280][4096] = lrelu(A@W^T + bias), NHWC bf16 out
__global__ __launch_bounds__(256) void k_gemm_fc_m(
    const ushort* __restrict__ A, const ushort* __restrict__ W,
    const float* __restrict__ bias, ushort* __restrict__ C)
{
  constexpr int K = 640, BK = 64, NK = K/BK, BM = 128, BN = 64;
  constexpr int RS = 72;
  constexpr int NCF = BN/16;
  constexpr int AC = 4, WC = 2;

  __shared__ __align__(16) ushort Al[2][BM*RS];
  __shared__ __align__(16) ushort Wl[2][BN*RS];

  const int tid = threadIdx.x;
  const int col0 = blockIdx.x * BN, row0 = blockIdx.y * BM;
  const int w = tid >> 6, l = tid & 63, lm = l & 15, lk = l >> 4;

  f32x4 acc[NCF][2];
  #pragma unroll
  for (int m = 0; m < NCF; ++m)
    #pragma unroll
    for (int s = 0; s < 2; ++s)
      acc[m][s] = (f32x4){0.f,0.f,0.f,0.f};

  uint4 ar[AC], wr[WC];

  #define LOADG(kt) { \
    _Pragma("unroll") \
    for (int i = 0; i < AC; ++i) { \
      int chunk = tid + i*256; \
      int rl = chunk >> 3, kc = chunk & 7; \
      ar[i] = *(const uint4*)&A[(size_t)(row0+rl)*K + (kt)*BK + kc*8]; \
    } \
    _Pragma("unroll") \
    for (int i = 0; i < WC; ++i) { \
      int chunk = tid + i*256; \
      int co = chunk >> 3, kc = chunk & 7; \
      wr[i] = *(const uint4*)&W[(size_t)(col0+co)*K + (kt)*BK + kc*8]; \
    } }

  #define STOREL(buf) { \
    _Pragma("unroll") \
    for (int i = 0; i < AC; ++i) { \
      int chunk = tid + i*256; \
      int rl = chunk >> 3, kc = chunk & 7; \
      *(uint4*)&Al[buf][rl*RS + kc*8] = ar[i]; \
    } \
    _Pragma("unroll") \
    for (int i = 0; i < WC; ++i) { \
      int chunk = tid + i*256; \
      int co = chunk >> 3, kc = chunk & 7; \
      *(uint4*)&Wl[buf][co*RS + kc*8] = wr[i]; \
    } }

  LOADG(0);
  STOREL(0);
  int cur = 0;
  for (int kt = 0; kt < NK; ++kt) {
    if (kt + 1 < NK) LOADG(kt + 1);
    __syncthreads();
    #pragma unroll
    for (int kf = 0; kf < 2; ++kf) {
      bf16x8 bfr[2];
      #pragma unroll
      for (int s = 0; s < 2; ++s)
        bfr[s] = *(bf16x8*)&Al[cur][(w*32 + s*16 + lm)*RS + kf*32 + lk*8];
      #pragma unroll
      for (int m = 0; m < NCF; ++m) {
        bf16x8 afr = *(bf16x8*)&Wl[cur][(m*16 + lm)*RS + kf*32 + lk*8];
        acc[m][0] = __builtin_amdgcn_mfma_f32_16x16x32_bf16(afr, bfr[0], acc[m][0], 0, 0, 0);
        acc[m][1] = __builtin_amdgcn_mfma_f32_16x16x32_bf16(afr, bfr[1], acc[m][1], 0, 0, 0);
      }
    }
    if (kt + 1 < NK) STOREL(cur ^ 1);
    cur ^= 1;
  }

  #pragma unroll
  for (int m = 0; m < NCF; ++m) {
    #pragma unroll
    for (int s = 0; s < 2; ++s) {
      int row = row0 + w*32 + s*16 + lm;
      f32x4 v = acc[m][s];
      #pragma unroll
      for (int j = 0; j < 4; ++j) {
        int u = col0 + m*16 + lk*4 + j;
        float val = LRELU(v[j] + bias[u]);
        C[((size_t)row << 12) + ((size_t)(u & 15) << 8) + (u >> 4)] = bfbits(val);
      }
    }
  }
  #undef LOADG
  #undef STOREL
}

// ---------------- MFMA parity-GEMM deconv (stage 0): A in LDS dbuf, weights
// direct-from-global in slab layout with register double-buffer; CO-split via
// blockIdx.z; waves_per_eu(2,4) raises VGPR budget to 128 (LDS caps at 4
// blocks/CU anyway) so the weight prefetch stays live across the MFMA block
template<int CI, int CO, int HI>
__global__ __attribute__((amdgpu_flat_work_group_size(256, 256), amdgpu_waves_per_eu(2, 4)))
void k_dcv(
    const ushort* __restrict__ in, const ushort* __restrict__ wp,
    ushort* __restrict__ out, float* __restrict__ gsum, float* __restrict__ gsq)
{
  constexpr int WI = HI, HO = 2*HI, WO = 2*WI;
  constexpr int K = 4*CI, BK = 64, NK = K/BK, KFT = K/32;
  constexpr int BSP = 128;
  constexpr int RS = 72;
  constexpr int NCF = CO/32;
  constexpr int COH = CO/2;
  constexpr int AC = BSP/32;

  __shared__ __align__(16) ushort Al[2][BSP*RS];
  __shared__ float s_sum[COH], s_sq[COH];

  const int tid = threadIdx.x;
  const int sp0 = blockIdx.x * BSP;
  const int p  = blockIdx.y;
  const int coz = blockIdx.z;
  const int py = p >> 1, px = p & 1;
  const int w  = tid >> 6, l = tid & 63;
  const int lm = l & 15, lk = l >> 4;

  if (tid < COH) { s_sum[tid] = 0.f; s_sq[tid] = 0.f; }

  f32x4 acc[NCF][2];
  #pragma unroll
  for (int m = 0; m < NCF; ++m)
    #pragma unroll
    for (int s = 0; s < 2; ++s)
      acc[m][s] = (f32x4){0.f,0.f,0.f,0.f};

  uint4 ar[AC];
  const ushort* wpb = wp + (size_t)(p*(CO/16) + coz*NCF)*KFT*512;

  #define LOADT(kt) { \
    int t = ((kt)*BK)/CI, ci0 = ((kt)*BK)%CI; \
    int dy = t >> 1, dx = t & 1; \
    _Pragma("unroll") \
    for (int i = 0; i < AC; ++i) { \
      int chunk = tid + i*256; \
      int rl = chunk >> 3, kc = chunk & 7; \
      int r = sp0 + rl; \
      int n = r / (HI*WI), rem = r % (HI*WI); \
      int oy = rem / WI, ox = rem % WI; \
      int iy = oy + py - dy, ix = ox + px - dx; \
      if ((unsigned)iy < (unsigned)HI && (unsigned)ix < (unsigned)WI) \
        ar[i] = *(const uint4*)&in[((((size_t)n*HI + iy)*WI + ix)*CI) + ci0 + kc*8]; \
      else ar[i] = make_uint4(0,0,0,0); \
    } }

  #define STORET(buf) { \
    _Pragma("unroll") \
    for (int i = 0; i < AC; ++i) { \
      int chunk = tid + i*256; \
      int rl = chunk >> 3, kc = chunk & 7; \
      *(uint4*)&Al[buf][rl*RS + kc*8] = ar[i]; \
    } }

  LOADT(0);
  STORET(0);
  // prefetch weight fragments for ktg=0
  bf16x8 afrN[NCF];
  #pragma unroll
  for (int m = 0; m < NCF; ++m)
    afrN[m] = *(const bf16x8*)&wpb[((size_t)m*KFT)*512 + lm*32 + lk*8];
  int cur = 0;
  for (int kt = 0; kt < NK; ++kt) {
    if (kt + 1 < NK) LOADT(kt + 1);
    __syncthreads();
    #pragma unroll
    for (int kf = 0; kf < 2; ++kf) {
      const int ktg = kt*2 + kf;
      bf16x8 afr[NCF];
      #pragma unroll
      for (int m = 0; m < NCF; ++m) afr[m] = afrN[m];
      if (ktg + 1 < KFT) {
        #pragma unroll
        for (int m = 0; m < NCF; ++m)
          afrN[m] = *(const bf16x8*)&wpb[((size_t)m*KFT + ktg + 1)*512 + lm*32 + lk*8];
      }
      bf16x8 bfr[2];
      #pragma unroll
      for (int s = 0; s < 2; ++s)
        bfr[s] = *(bf16x8*)&Al[cur][(w*32 + s*16 + lm)*RS + kf*32 + lk*8];
      #pragma unroll
      for (int m = 0; m < NCF; ++m) {
        acc[m][0] = __builtin_amdgcn_mfma_f32_16x16x32_bf16(afr[m], bfr[0], acc[m][0], 0, 0, 0);
        acc[m][1] = __builtin_amdgcn_mfma_f32_16x16x32_bf16(afr[m], bfr[1], acc[m][1], 0, 0, 0);
      }
    }
    if (kt + 1 < NK) STORET(cur ^ 1);
    cur ^= 1;
  }

  // pass 1: batch stats only (this CO half)
  #pragma unroll
  for (int m = 0; m < NCF; ++m) {
    float s1[4] = {0,0,0,0}, s2[4] = {0,0,0,0};
    #pragma unroll
    for (int s = 0; s < 2; ++s) {
      f32x4 v = acc[m][s];
      #pragma unroll
      for (int j = 0; j < 4; ++j) { s1[j] += v[j]; s2[j] += v[j]*v[j]; }
    }
    #pragma unroll
    for (int j = 0; j < 4; ++j) {
      float a = s1[j], b = s2[j];
      #pragma unroll
      for (int o = 1; o < 16; o <<= 1) { a += __shfl_xor(a, o); b += __shfl_xor(b, o); }
      if (lm == 0) {
        atomicAdd(&s_sum[m*16 + lk*4 + j], a);
        atomicAdd(&s_sq [m*16 + lk*4 + j], b);
      }
    }
  }
  // pass 2: stores, s-outer / m-inner
  #pragma unroll
  for (int s = 0; s < 2; ++s) {
    int sp = sp0 + w*32 + s*16 + lm;
    int n = sp / (HI*WI), rem = sp % (HI*WI);
    int y = 2*(rem / WI) + py, x = 2*(rem % WI) + px;
    size_t ob = (((size_t)n*HO + y)*WO + x)*CO + coz*COH + lk*4;
    #pragma unroll
    for (int m = 0; m < NCF; ++m) {
      f32x4 v = acc[m][s];
      union { ushort u[4]; uint2 q; } pk;
      pk.u[0] = bfbits(v[0]); pk.u[1] = bfbits(v[1]);
      pk.u[2] = bfbits(v[2]); pk.u[3] = bfbits(v[3]);
      *(uint2*)&out[ob + m*16] = pk.q;
    }
  }
  __syncthreads();
  for (int cc = tid; cc < COH; cc += 256) {
    atomicAdd(&gsum[coz*COH + cc], s_sum[cc]);
    atomicAdd(&gsq[coz*COH + cc],  s_sq[cc]);
  }
  #undef LOADT
  #undef STORET
}

// ---------------- image-resident MFMA deconv (stages 1 & 2); waves_per_eu max=4
template<int CI, int CO, int HI>
__global__ __attribute__((amdgpu_flat_work_group_size(512, 512), amdgpu_waves_per_eu(2, 4)))
void k_dcvim(
    const ushort* __restrict__ in, const ushort* __restrict__ wp,
    const float* __restrict__ gsumP, const float* __restrict__ gsqP,
    const float* __restrict__ gP, const float* __restrict__ beP, float invNP,
    ushort* __restrict__ out, float* __restrict__ gsum, float* __restrict__ gsq)
{
  constexpr int WI = HI, HO = 2*HI, WO = 2*WI;
  constexpr int K = 4*CI;
  constexpr int KF = K/32;
  constexpr int PAD = HI + 2;
  constexpr int CICH = CI/8;
  constexpr int MMW2 = CO/16;
  constexpr int SFTH = HI*WI/32;

  __shared__ __align__(16) ushort Ain[PAD*PAD*CI];
  __shared__ float s_sum[CO], s_sq[CO];
  __shared__ float s_scale[CI], s_shift[CI];

  const int tid = threadIdx.x;
  const int n = blockIdx.x;
  const int w = tid >> 6, l = tid & 63, lm = l & 15, lk = l >> 4;
  const int p = w >> 1, py = p >> 1, px = p & 1, ph = w & 1;

  if (tid < CO) { s_sum[tid] = 0.f; s_sq[tid] = 0.f; }
  if (tid >= 512-CI) {
    int c = tid - (512-CI);
    float m = gsumP[c]*invNP;
    float v = gsqP[c]*invNP - m*m;
    float sc = gP[c]*rsqrtf(v + 1e-5f);
    s_scale[c] = sc;
    s_shift[c] = beP[c] - m*sc;
  }
  __syncthreads();

  const ushort* inb = in + (size_t)n * HI * WI * CI;
  constexpr int NPCH = PAD*PAD*CICH;
  for (int e = tid; e < NPCH; e += 512) {
    int ci8 = e % CICH; int sp = e / CICH;
    int c = sp % PAD, r = sp / PAD;
    int chS = ci8 ^ (c & 7);
    if (r >= 1 && r <= HI && c >= 1 && c <= WI) {
      uint4 u = *(const uint4*)&inb[(((size_t)(r-1)*WI + (c-1))*CI) + ci8*8];
      int ci0 = ci8*8;
      float4 sc0 = *(const float4*)&s_scale[ci0];
      float4 sc1 = *(const float4*)&s_scale[ci0+4];
      float4 sh0 = *(const float4*)&s_shift[ci0];
      float4 sh1 = *(const float4*)&s_shift[ci0+4];
      float v0 = LRELU(fmaf(bflo(u.x), sc0.x, sh0.x));
      float v1 = LRELU(fmaf(bfhi(u.x), sc0.y, sh0.y));
      float v2 = LRELU(fmaf(bflo(u.y), sc0.z, sh0.z));
      float v3 = LRELU(fmaf(bfhi(u.y), sc0.w, sh0.w));
      float v4 = LRELU(fmaf(bflo(u.z), sc1.x, sh1.x));
      float v5 = LRELU(fmaf(bfhi(u.z), sc1.y, sh1.y));
      float v6 = LRELU(fmaf(bflo(u.w), sc1.z, sh1.z));
      float v7 = LRELU(fmaf(bfhi(u.w), sc1.w, sh1.w));
      uint4 o;
      o.x = (uint)bfpack(v0, v1);
      o.y = (uint)bfpack(v2, v3);
      o.z = (uint)bfpack(v4, v5);
      o.w = (uint)bfpack(v6, v7);
      ((uint4*)Ain)[(r*PAD + c)*CICH + chS] = o;
    } else {
      ((uint4*)Ain)[(r*PAD + c)*CICH + chS] = make_uint4(0,0,0,0);
    }
  }
  __syncthreads();

  f32x4 acc[MMW2][SFTH];
  #pragma unroll
  for (int m = 0; m < MMW2; ++m)
    #pragma unroll
    for (int sf = 0; sf < SFTH; ++sf)
      acc[m][sf] = (f32x4){0.f,0.f,0.f,0.f};

  const ushort* wpb = wp + (size_t)(p*MMW2)*KF*512;
  bf16x8 afrN[MMW2];
  #pragma unroll
  for (int m = 0; m < MMW2; ++m)
    afrN[m] = *(const bf16x8*)&wpb[((size_t)m*KF)*512 + lm*32 + lk*8];
  #pragma unroll
  for (int kf = 0; kf < KF; ++kf) {
    const int t = (kf*32)/CI, cib = (kf*32)%CI;
    const int dy = t >> 1, dx = t & 1;
    bf16x8 afr[MMW2];
    #pragma unroll
    for (int m = 0; m < MMW2; ++m) afr[m] = afrN[m];
    if (kf + 1 < KF) {
      #pragma unroll
      for (int m = 0; m < MMW2; ++m)
        afrN[m] = *(const bf16x8*)&wpb[((size_t)m*KF + (kf+1))*512 + lm*32 + lk*8];
    }
    const int ch = (cib >> 3) + lk;
    #pragma unroll
    for (int sf = 0; sf < SFTH; ++sf) {
      int s = (ph*SFTH + sf)*16 + lm;
      int y = s / WI, x = s % WI;
      int r = y + py - dy + 1, c = x + px - dx + 1;
      bf16x8 bfr = *(const bf16x8*)&Ain[((r*PAD + c)*CICH + (ch ^ (c & 7)))*8];
      #pragma unroll
      for (int m = 0; m < MMW2; ++m)
        acc[m][sf] = __builtin_amdgcn_mfma_f32_16x16x32_bf16(afr[m], bfr, acc[m][sf], 0, 0, 0);
    }
  }

  float s1[MMW2][4], s2[MMW2][4];
  #pragma unroll
  for (int m = 0; m < MMW2; ++m)
    #pragma unroll
    for (int j = 0; j < 4; ++j) { s1[m][j] = 0.f; s2[m][j] = 0.f; }

  #pragma unroll
  for (int sf = 0; sf < SFTH; ++sf) {
    int s = (ph*SFTH + sf)*16 + lm;
    int y = 2*(s / WI) + py, x = 2*(s % WI) + px;
    size_t ob = (((size_t)n*HO + y)*WO + x)*CO + lk*4;
    #pragma unroll
    for (int m = 0; m < MMW2; ++m) {
      f32x4 v = acc[m][sf];
      union { ushort u[4]; uint2 q; } pk;
      #pragma unroll
      for (int j = 0; j < 4; ++j) {
        pk.u[j] = bfbits(v[j]);
        s1[m][j] += v[j];
        s2[m][j] += v[j]*v[j];
      }
      *(uint2*)&out[ob + m*16] = pk.q;
    }
  }

  #pragma unroll
  for (int m = 0; m < MMW2; ++m) {
    #pragma unroll
    for (int j = 0; j < 4; ++j) {
      float a = s1[m][j], b = s2[m][j];
      #pragma unroll
      for (int o = 1; o < 16; o <<= 1) { a += __shfl_xor(a, o); b += __shfl_xor(b, o); }
      if (lm == 0) {
        atomicAdd(&s_sum[m*16 + lk*4 + j], a);
        atomicAdd(&s_sq [m*16 + lk*4 + j], b);
      }
    }
  }

  __syncthreads();
  for (int cc = tid; cc < CO; cc += 512) {
    atomicAdd(&gsum[cc], s_sum[cc]);
    atomicAdd(&gsq[cc],  s_sq[cc]);
  }
}

// ---------------- final deconv 32->1 + sigmoid via tap-dot MFMA
__global__ __launch_bounds__(256) void k_final(
    const ushort* __restrict__ in, const ushort* __restrict__ wfb,
    const float* __restrict__ gsumP, const float* __restrict__ gsqP,
    const float* __restrict__ gP, const float* __restrict__ beP, float invNP,
    const float* __restrict__ bfb, float* __restrict__ outp)
{
  constexpr int CI=32, HI=32, WI=32, HO=64, WO=64, SPLIT=4, HOq=HO/SPLIT;
  constexpr int RMAX = 10;
  constexpr int DP = 20;
  __shared__ float Dl[RMAX*32*DP];
  __shared__ float s_scale[CI], s_shift[CI];

  const int tid = threadIdx.x, bid = blockIdx.x;
  const int n = bid % 1280, q = bid / 1280;
  const int y0 = q * HOq;
  const int rows_lo = max(0, y0/2 - 1);
  const int rows_hi = min(HI-1, (y0 + HOq)/2);
  const int nrows = rows_hi - rows_lo + 1;

  if (tid < CI) {
    float m = gsumP[tid]*invNP;
    float v = gsqP[tid]*invNP - m*m;
    float sc = gP[tid]*rsqrtf(v + 1e-5f);
    s_scale[tid] = sc;
    s_shift[tid] = beP[tid] - m*sc;
  }
  __syncthreads();

  const int w = tid >> 6, l = tid & 63, lm = l & 15, lk = l >> 4;
  const bf16x8 afr = *(const bf16x8*)&wfb[lm*32 + lk*8];
  const float4 sc0 = *(const float4*)&s_scale[lk*8];
  const float4 sc1 = *(const float4*)&s_scale[lk*8+4];
  const float4 sh0 = *(const float4*)&s_shift[lk*8];
  const float4 sh1 = *(const float4*)&s_shift[lk*8+4];

  const ushort* inb = in + (size_t)n * HI * WI * CI;
  const int ngrp = nrows * 2;
  for (int g = w; g < ngrp; g += 4) {
    int px = g*16 + lm;
    int rl = px >> 5, ix = px & 31;
    uint4 u = *(const uint4*)&inb[(((size_t)(rows_lo+rl)*WI + ix)*CI) + lk*8];
    float v0 = LRELU(fmaf(bflo(u.x), sc0.x, sh0.x));
    float v1 = LRELU(fmaf(bfhi(u.x), sc0.y, sh0.y));
    float v2 = LRELU(fmaf(bflo(u.y), sc0.z, sh0.z));
    float v3 = LRELU(fmaf(bfhi(u.y), sc0.w, sh0.w));
    float v4 = LRELU(fmaf(bflo(u.z), sc1.x, sh1.x));
    float v5 = LRELU(fmaf(bfhi(u.z), sc1.y, sh1.y));
    float v6 = LRELU(fmaf(bflo(u.w), sc1.z, sh1.z));
    float v7 = LRELU(fmaf(bfhi(u.w), sc1.w, sh1.w));
    union { uint uu[4]; bf16x8 v; } pk;
    pk.uu[0] = bfpack(v0, v1);
    pk.uu[1] = bfpack(v2, v3);
    pk.uu[2] = bfpack(v4, v5);
    pk.uu[3] = bfpack(v6, v7);
    f32x4 d = __builtin_amdgcn_mfma_f32_16x16x32_bf16(afr, pk.v, (f32x4){0.f,0.f,0.f,0.f}, 0, 0, 0);
    *(f32x4*)&Dl[px*DP + lk*4] = d;
  }
  __syncthreads();

  const float b0 = bfb[0];
  #pragma unroll
  for (int i = 0; i < (HOq*WO)/256; ++i) {
    int e = tid + i*256;
    int oy = e >> 6, x = e & 63;
    int y = y0 + oy;
    int kya = (y + 1) & 1, iya = (y + 1) >> 1;
    int kxa = (x + 1) & 1, ixa = (x + 1) >> 1;
    float acc = b0;
    #pragma unroll
    for (int dy = 0; dy < 2; ++dy) {
      int iy = iya - dy, ky = kya + 2*dy;
      if (iy < 0 || iy >= HI) continue;
      #pragma unroll
      for (int dx = 0; dx < 2; ++dx) {
        int ix = ixa - dx, kx = kxa + 2*dx;
        if (ix < 0 || ix >= WI) continue;
        acc += Dl[((iy - rows_lo)*WI + ix)*DP + (ky*4 + kx)];
      }
    }
    outp[(size_t)n*HO*WO + y*WO + x] = 1.f/(1.f + __expf(-acc));
  }
}

extern "C" void kernel_launch(void* const* d_in, const int* in_sizes, int n_in,
                              void* d_out, int out_size, void* d_ws, size_t ws_size,
                              hipStream_t stream) {
  const float* z_content = (const float*)d_in[0];
  const float* z_motion  = (const float*)d_in[1];
  const float* W_h  = (const float*)d_in[2];
  const float* b_h  = (const float*)d_in[3];
  const float* W_c  = (const float*)d_in[4];
  const float* b_c  = (const float*)d_in[5];
  const float* W_ih = (const float*)d_in[6];
  const float* W_hh = (const float*)d_in[7];
  const float* b_ih = (const float*)d_in[8];
  const float* b_hh = (const float*)d_in[9];
  const float* W_f  = (const float*)d_in[10];
  const float* b_f  = (const float*)d_in[11];
  const float* init_in = (const float*)d_in[12];
  const float* fc_W = (const float*)d_in[13];
  const float* fc_b = (const float*)d_in[14];
  const float* w0 = (const float*)d_in[15];
  const float* g0 = (const float*)d_in[16];
  const float* be0 = (const float*)d_in[17];
  const float* w1 = (const float*)d_in[18];
  const float* g1 = (const float*)d_in[19];
  const float* be1 = (const float*)d_in[20];
  const float* w2 = (const float*)d_in[21];
  const float* g2 = (const float*)d_in[22];
  const float* be2 = (const float*)d_in[23];
  const float* wf = (const float*)d_in[24];
  const float* bf_ = (const float*)d_in[25];

  const size_t P_BYTES = 10631168;
  const size_t X_OFF   = P_BYTES;
  const size_t X_BYTES = 83886080;
  const size_t Y_OFF   = X_OFF + X_BYTES;
  const size_t NEED    = Y_OFF + 41943040;
  if (ws_size < NEED) return;

  float* ws = (float*)d_ws;
  char*  wsb = (char*)d_ws;
  float* sum0 = ws + 0;        float* sq0 = ws + 128;
  float* sum1 = ws + 256;      float* sq1 = ws + 320;
  float* sum2 = ws + 384;      float* sq2 = ws + 416;
  float4* xg4   = (float4*)(ws + 1024);
  float4* bias4 = (float4*)(ws + 2048);
  float* h    = ws + 3072;
  float* c    = ws + 19456;
  ushort* outsb = (ushort*)(ws + 35840);
  float* WhT  = ws + 199680;
  float* WcT  = ws + 265216;
  uint4* Whq8 = (uint4*)(ws + 330752);
  uint4* Wsq8 = (uint4*)(ws + 592896);
  ushort* wp0 = (ushort*)(ws + 855040);
  ushort* wp1 = (ushort*)(ws + 1117184);
  ushort* wp2 = (ushort*)(ws + 1182720);
  ushort* wfb = (ushort*)(ws + 1199104);
  ushort* wpff = (ushort*)(ws + 1199616);
  ushort* featb = (ushort*)(ws + 1265152);

  ushort* wpfc = (ushort*)(wsb + X_OFF);
  ushort* out0 = (ushort*)(wsb + X_OFF);
  ushort* out2 = (ushort*)(wsb + X_OFF);
  ushort* h1   = (ushort*)(wsb + Y_OFF);
  ushort* out1 = (ushort*)(wsb + Y_OFF);

  // ---- all independent prep in ONE launch
  k_prep<<<13890, 256, 0, stream>>>(
      W_h, W_c, WhT, WcT, fc_W, wpfc, W_f, wpff,
      W_ih, W_hh, Whq8, Wsq8, ws, b_ih, b_hh, init_in, xg4, bias4,
      w0, wp0, w1, wp1, w2, wp2, wf, wfb);
  k_h0c0<<<64, 256, 0, stream>>>(z_content, z_motion, WhT, WcT, b_h, b_c, h, c);

  // ---- whole LSTM in one launch (fp8 weights)
  k_lstm_all<<<64, 1024, 0, stream>>>(Whq8, Wsq8, xg4, bias4, h, c, outsb);

  // ---- ff (MFMA, + fused zc concat) + fc (MFMA)
  k_ff_m<<<dim3(8, 10), 256, 0, stream>>>(outsb, wpff, b_f, z_content, featb);
  k_gemm_fc_m<<<dim3(64, 10), 256, 0, stream>>>(featb, wpfc, fc_b, h1);

  // ---- deconv pipeline (all deconv kernels: waves_per_eu-capped + reg-dbuf)
  k_dcv<256,128,4><<<dim3(160,4,2), 256, 0, stream>>>(h1, wp0, out0, sum0, sq0);
  k_dcvim<128,64,8><<<1280, 512, 0, stream>>>(out0, wp1, sum0, sq0, g0, be0, 1.f/81920.f, out1, sum1, sq1);
  k_dcvim<64,32,16><<<1280, 512, 0, stream>>>(out1, wp2, sum1, sq1, g1, be1, 1.f/327680.f, out2, sum2, sq2);
  k_final<<<5120, 256, 0, stream>>>(out2, wfb, sum2, sq2, g2, be2, 1.f/1310720.f, bf_, (float*)d_out);
}